// Round 9
// baseline (1863.299 us; speedup 1.0000x reference)
//
#include <hip/hip_runtime.h>
#include <math.h>

#define EPS 1e-6f

constexpr int BSZ = 16;    // batch * S
constexpr int DD  = 512;   // channels / S
constexpr int NN  = 4096;  // H*W
constexpr int RR  = 64;
constexpr int STEPS = 7;
constexpr int NS_B  = 8;   // BtB d-split blocks
constexpr int NS_C  = 32;  // CtC n-split blocks
constexpr int NS_N2 = 8;   // numer2 n-split partials

typedef __attribute__((ext_vector_type(8))) short short8;
typedef __attribute__((ext_vector_type(8))) unsigned short ushort8;
typedef __attribute__((ext_vector_type(4))) float f32x4;

__device__ __forceinline__ void fma4s(float4& a, const float4& b, float s) {
  a.x = fmaf(b.x, s, a.x); a.y = fmaf(b.y, s, a.y);
  a.z = fmaf(b.z, s, a.z); a.w = fmaf(b.w, s, a.w);
}
__device__ __forceinline__ void add4(float4& a, const float4& b) {
  a.x += b.x; a.y += b.y; a.z += b.z; a.w += b.w;
}
__device__ __forceinline__ unsigned short f2bf(float f) {
  unsigned u = __float_as_uint(f);
  return (unsigned short)((u + 0x7FFFu + ((u >> 16) & 1u)) >> 16);
}
__device__ __forceinline__ float bf2f(unsigned short h) {
  return __uint_as_float(((unsigned)h) << 16);
}
__device__ __forceinline__ f32x4 mfma16(short8 a, short8 b, f32x4 c) {
  return __builtin_amdgcn_mfma_f32_16x16x32_bf16(a, b, c, 0, 0, 0);
}

// async global->LDS, 16B per lane (fp32 fallback path)
__device__ __forceinline__ void gload16(const float* g, float* l) {
  __builtin_amdgcn_global_load_lds(
      (const __attribute__((address_space(1))) void*)g,
      (__attribute__((address_space(3))) void*)l, 16, 0, 0);
}

// ================= transpose + fp32->bf16 convert (hi, optional lo residual)
template <bool LO>
__global__ void __launch_bounds__(256) tcvt_kernel(const float* __restrict__ src,
                                                   unsigned short* __restrict__ dh,
                                                   unsigned short* __restrict__ dl,
                                                   int R, int C) {
  __shared__ float tileT[64 * 65];   // [src_col][src_row], stride 65
  const int b = blockIdx.z, c0 = blockIdx.x << 6, r0 = blockIdx.y << 6;
  const float* sp = src + (long long)b * R * C;
  const int t = threadIdx.x;
  #pragma unroll
  for (int i = 0; i < 4; ++i) {
    const int idx = t + (i << 8);
    const int row = idx >> 4, c4 = (idx & 15) << 2;
    const float4 v = *(const float4*)&sp[(long long)(r0 + row) * C + c0 + c4];
    tileT[(c4 + 0) * 65 + row] = v.x;
    tileT[(c4 + 1) * 65 + row] = v.y;
    tileT[(c4 + 2) * 65 + row] = v.z;
    tileT[(c4 + 3) * 65 + row] = v.w;
  }
  __syncthreads();
  const int orow = t >> 2, och = (t & 3) << 4;
  ushort8 h0, h1, l0, l1;
  #pragma unroll
  for (int j = 0; j < 8; ++j) {
    const float v = tileT[orow * 65 + och + j];
    const unsigned short h = f2bf(v);
    h0[j] = h;
    if (LO) l0[j] = f2bf(v - bf2f(h));
  }
  #pragma unroll
  for (int j = 0; j < 8; ++j) {
    const float v = tileT[orow * 65 + och + 8 + j];
    const unsigned short h = f2bf(v);
    h1[j] = h;
    if (LO) l1[j] = f2bf(v - bf2f(h));
  }
  const long long ob = ((long long)b * C + c0 + orow) * R + r0 + och;
  *(ushort8*)&dh[ob] = h0;
  *(ushort8*)&dh[ob + 8] = h1;
  if (LO) { *(ushort8*)&dl[ob] = l0; *(ushort8*)&dl[ob + 8] = l1; }
}

// ================= flat fp32 -> bf16 hi/lo cast (no transpose)
__global__ void __launch_bounds__(256) casthl_kernel(const float* __restrict__ src,
                                                     unsigned short* __restrict__ dh,
                                                     unsigned short* __restrict__ dl,
                                                     long long n) {
  const long long i = ((long long)blockIdx.x * 256 + threadIdx.x) * 8;
  if (i >= n) return;
  const float4 a = *(const float4*)&src[i];
  const float4 c = *(const float4*)&src[i + 4];
  const float e[8] = {a.x, a.y, a.z, a.w, c.x, c.y, c.z, c.w};
  ushort8 h, lo;
  #pragma unroll
  for (int j = 0; j < 8; ++j) {
    h[j] = f2bf(e[j]);
    lo[j] = f2bf(e[j] - bf2f(h[j]));
  }
  *(ushort8*)&dh[i] = h;
  *(ushort8*)&dl[i] = lo;
}

// ================= sum BtB partials -> bf16 hi/lo G (once per iteration)
__global__ void __launch_bounds__(256) gsum_kernel(const float* __restrict__ btbp,
                                                   unsigned short* __restrict__ Gh,
                                                   unsigned short* __restrict__ Gl) {
  const int b = blockIdx.x;
  for (int i = threadIdx.x; i < 1024; i += 256) {
    float4 s = make_float4(0.f, 0.f, 0.f, 0.f);
    #pragma unroll
    for (int sp = 0; sp < NS_B; ++sp)
      add4(s, ((const float4*)(btbp + ((long long)sp * BSZ + b) * 4096))[i]);
    const float se[4] = {s.x, s.y, s.z, s.w};
    const long long base = (long long)b * 4096 + (long long)i * 4;
    #pragma unroll
    for (int e = 0; e < 4; ++e) {
      const unsigned short h = f2bf(se[e]);
      Gh[base + e] = h;
      Gl[base + e] = f2bf(se[e] - bf2f(h));
    }
  }
}

// ================= sum CtC partials (fp32, once per iteration)
__global__ void __launch_bounds__(256) csum_kernel(const float* __restrict__ src,
                                                   float* __restrict__ dst, int nsp) {
  const int b = blockIdx.x;
  for (int i = threadIdx.x; i < 1024; i += 256) {
    float4 s = make_float4(0.f, 0.f, 0.f, 0.f);
    for (int sp = 0; sp < nsp; ++sp)
      add4(s, ((const float4*)(src + ((long long)sp * BSZ + b) * 4096))[i]);
    ((float4*)(dst + (long long)b * 4096))[i] = s;
  }
}

// ================= MFMA fused numer + {softmax | coef update}
// MODE0: coef = softmax(numer).  MODE1: coef *= numer/(cold@G+eps), also emits
// cbT (bf16 [r][n]).  MODE2 (final): emits only cNh/cNl (bf16 hi/lo [n][r]).
// 128 thr = 2 waves; block = 32 n-rows x 64 r; wave owns 16 rows. No LDS.
template <int MODE>
__global__ void __launch_bounds__(128) fused_mfma_kernel(const unsigned short* __restrict__ xbTh,
                                                         const unsigned short* __restrict__ xbTl,
                                                         const unsigned short* __restrict__ BbT,
                                                         const unsigned short* __restrict__ Gh,
                                                         const unsigned short* __restrict__ Gl,
                                                         float* __restrict__ coef,
                                                         unsigned short* __restrict__ cbT,
                                                         unsigned short* __restrict__ cNh,
                                                         unsigned short* __restrict__ cNl) {
  const int b  = blockIdx.y;
  const int n0 = blockIdx.x << 5;
  const int t  = threadIdx.x;
  const int w  = t >> 6;
  const int l  = t & 63;
  const int row16 = l & 15;
  const int koff  = (l >> 4) << 3;
  const int nrb   = n0 + (w << 4);          // wave's 16 rows

  const unsigned short* aph = xbTh + ((long long)b * NN + nrb + row16) * DD + koff;
  const unsigned short* apl = xbTl + ((long long)b * NN + nrb + row16) * DD + koff;
  const unsigned short* bpt = BbT  + ((long long)b * RR + row16) * DD + koff;

  f32x4 acc[4];
  #pragma unroll
  for (int rs = 0; rs < 4; ++rs) acc[rs] = (f32x4){0.f, 0.f, 0.f, 0.f};

  #pragma unroll
  for (int kt = 0; kt < 16; ++kt) {
    const int ko = kt << 5;
    const short8 ah = *(const short8*)&aph[ko];
    const short8 al = *(const short8*)&apl[ko];
    short8 bf[4];
    #pragma unroll
    for (int rs = 0; rs < 4; ++rs) bf[rs] = *(const short8*)&bpt[rs * 16 * DD + ko];
    #pragma unroll
    for (int rs = 0; rs < 4; ++rs) {
      acc[rs] = mfma16(ah, bf[rs], acc[rs]);
      acc[rs] = mfma16(al, bf[rs], acc[rs]);
    }
  }

  if constexpr (MODE == 0) {
    #pragma unroll
    for (int j = 0; j < 4; ++j) {
      float m = fmaxf(fmaxf(acc[0][j], acc[1][j]), fmaxf(acc[2][j], acc[3][j]));
      m = fmaxf(m, __shfl_xor(m, 1));
      m = fmaxf(m, __shfl_xor(m, 2));
      m = fmaxf(m, __shfl_xor(m, 4));
      m = fmaxf(m, __shfl_xor(m, 8));
      float s = 0.f;
      #pragma unroll
      for (int rs = 0; rs < 4; ++rs) { acc[rs][j] = __expf(acc[rs][j] - m); s += acc[rs][j]; }
      s += __shfl_xor(s, 1); s += __shfl_xor(s, 2);
      s += __shfl_xor(s, 4); s += __shfl_xor(s, 8);
      const float inv = 1.f / s;
      #pragma unroll
      for (int rs = 0; rs < 4; ++rs) acc[rs][j] *= inv;
    }
    #pragma unroll
    for (int rs = 0; rs < 4; ++rs)
      #pragma unroll
      for (int j = 0; j < 4; ++j)
        coef[((long long)b * NN + nrb + ((l >> 4) << 2) + j) * RR + (rs << 4) + row16] = acc[rs][j];
  } else {
    // ---- denom = cold @ G via MFMA; G rows read from global (bf16 hi/lo)
    const float* crow = coef + ((long long)b * NN + nrb + row16) * RR;
    const unsigned short* ghb = Gh + (long long)b * 4096;
    const unsigned short* glb = Gl + (long long)b * 4096;
    f32x4 dn[4];
    #pragma unroll
    for (int rs = 0; rs < 4; ++rs) dn[rs] = (f32x4){0.f, 0.f, 0.f, 0.f};
    #pragma unroll
    for (int kt = 0; kt < 2; ++kt) {
      const int ko = (kt << 5) + koff;
      const float4 c0 = *(const float4*)&crow[ko];
      const float4 c1 = *(const float4*)&crow[ko + 4];
      const float ce[8] = {c0.x, c0.y, c0.z, c0.w, c1.x, c1.y, c1.z, c1.w};
      short8 ch, cl;
      #pragma unroll
      for (int j = 0; j < 8; ++j) {
        const unsigned short h = f2bf(ce[j]);
        ch[j] = (short)h;
        cl[j] = (short)f2bf(ce[j] - bf2f(h));
      }
      #pragma unroll
      for (int rs = 0; rs < 4; ++rs) {
        const short8 gh = *(const short8*)&ghb[((rs << 4) + row16) * 64 + ko];
        const short8 gl = *(const short8*)&glb[((rs << 4) + row16) * 64 + ko];
        dn[rs] = mfma16(ch, gh, dn[rs]);
        dn[rs] = mfma16(cl, gh, dn[rs]);
        dn[rs] = mfma16(ch, gl, dn[rs]);
      }
    }
    // ---- multiplicative update in D-frag positions (element-owner unique)
    #pragma unroll
    for (int rs = 0; rs < 4; ++rs)
      #pragma unroll
      for (int j = 0; j < 4; ++j) {
        const int r = (rs << 4) + row16;
        const long long n = (long long)nrb + ((l >> 4) << 2) + j;
        const long long idx = ((long long)b * NN + n) * RR + r;
        const float co = coef[idx];
        const float v  = co * acc[rs][j] / (dn[rs][j] + EPS);
        if constexpr (MODE == 1) {
          coef[idx] = v;
          cbT[((long long)b * RR + r) * NN + n] = f2bf(v);
        } else {
          const unsigned short h = f2bf(v);
          cNh[idx] = h;
          cNl[idx] = f2bf(v - bf2f(h));
        }
      }
  }
}

// ================= MFMA numer2 partials: n2p[s][b][d][r] = sum_n x[d][n]*c~[n][r]
__global__ void __launch_bounds__(128) numer2_mfma_kernel(const float* __restrict__ X,
                                                          const unsigned short* __restrict__ cbT,
                                                          float* __restrict__ n2p) {
  const int b  = blockIdx.z;
  const int s  = blockIdx.y;
  const int d0 = blockIdx.x << 6;
  const int t  = threadIdx.x;
  const int w  = t >> 6;
  const int l  = t & 63;
  const int row16 = l & 15;
  const int koff  = (l >> 4) << 3;
  const int nbeg  = s * (NN / NS_N2);

  const float* xp = X + ((long long)b * DD + d0 + w * 32 + row16) * NN + nbeg + koff;
  const unsigned short* cp = cbT + ((long long)b * RR + row16) * NN + nbeg + koff;

  f32x4 acc[2][4];
  #pragma unroll
  for (int ds = 0; ds < 2; ++ds)
    #pragma unroll
    for (int rs = 0; rs < 4; ++rs) acc[ds][rs] = (f32x4){0.f, 0.f, 0.f, 0.f};

  #pragma unroll
  for (int kt = 0; kt < 16; ++kt) {
    const int ko = kt << 5;
    short8 ah[2], al[2], bf[4];
    #pragma unroll
    for (int ds = 0; ds < 2; ++ds) {
      const float4 v0 = *(const float4*)&xp[(long long)ds * 16 * NN + ko];
      const float4 v1 = *(const float4*)&xp[(long long)ds * 16 * NN + ko + 4];
      const float ve[8] = {v0.x, v0.y, v0.z, v0.w, v1.x, v1.y, v1.z, v1.w};
      #pragma unroll
      for (int j = 0; j < 8; ++j) {
        const unsigned short h = f2bf(ve[j]);
        ah[ds][j] = (short)h;
        al[ds][j] = (short)f2bf(ve[j] - bf2f(h));
      }
    }
    #pragma unroll
    for (int rs = 0; rs < 4; ++rs) bf[rs] = *(const short8*)&cp[(long long)rs * 16 * NN + ko];
    #pragma unroll
    for (int ds = 0; ds < 2; ++ds)
      #pragma unroll
      for (int rs = 0; rs < 4; ++rs) {
        acc[ds][rs] = mfma16(ah[ds], bf[rs], acc[ds][rs]);
        acc[ds][rs] = mfma16(al[ds], bf[rs], acc[ds][rs]);
      }
  }
  float* op = n2p + (((long long)s * BSZ + b) * DD + d0 + w * 32) * RR;
  #pragma unroll
  for (int ds = 0; ds < 2; ++ds)
    #pragma unroll
    for (int rs = 0; rs < 4; ++rs)
      #pragma unroll
      for (int j = 0; j < 4; ++j)
        op[(long long)(ds * 16 + ((l >> 4) << 2) + j) * RR + (rs << 4) + row16] = acc[ds][rs][j];
}

// ================= MFMA out: out[d][n] = sum_r B[d][r]*coef[n][r]
// LDS-staged epilogue -> coalesced float4 row stores (256B segments).
__global__ void __launch_bounds__(256) out_mfma_kernel(const unsigned short* __restrict__ bDh,
                                                       const unsigned short* __restrict__ bDl,
                                                       const unsigned short* __restrict__ cNh,
                                                       const unsigned short* __restrict__ cNl,
                                                       float* __restrict__ out) {
  __shared__ float ot[64 * 68];
  const int n0 = blockIdx.x << 6;
  const int d0 = blockIdx.y << 6;
  const int b  = blockIdx.z;
  const int t  = threadIdx.x;
  const int w  = t >> 6;
  const int l  = t & 63;
  const int row16 = l & 15;
  const int koff  = (l >> 4) << 3;

  const unsigned short* aph = bDh + ((long long)b * DD + d0 + (w << 4) + row16) * RR + koff;
  const unsigned short* apl = bDl + ((long long)b * DD + d0 + (w << 4) + row16) * RR + koff;
  const unsigned short* bph = cNh + ((long long)b * NN + n0 + row16) * RR + koff;
  const unsigned short* bpl = cNl + ((long long)b * NN + n0 + row16) * RR + koff;

  f32x4 acc[4];
  #pragma unroll
  for (int ns = 0; ns < 4; ++ns) acc[ns] = (f32x4){0.f, 0.f, 0.f, 0.f};

  #pragma unroll
  for (int kt = 0; kt < 2; ++kt) {
    const int ko = kt << 5;
    const short8 ah = *(const short8*)&aph[ko];
    const short8 al = *(const short8*)&apl[ko];
    #pragma unroll
    for (int ns = 0; ns < 4; ++ns) {
      const short8 bh = *(const short8*)&bph[(long long)ns * 16 * RR + ko];
      const short8 bl = *(const short8*)&bpl[(long long)ns * 16 * RR + ko];
      acc[ns] = mfma16(ah, bh, acc[ns]);
      acc[ns] = mfma16(al, bh, acc[ns]);
      acc[ns] = mfma16(ah, bl, acc[ns]);
    }
  }
  #pragma unroll
  for (int ns = 0; ns < 4; ++ns)
    #pragma unroll
    for (int j = 0; j < 4; ++j)
      ot[((w << 4) + ((l >> 4) << 2) + j) * 68 + (ns << 4) + row16] = acc[ns][j];
  __syncthreads();
  #pragma unroll
  for (int k = 0; k < 4; ++k) {
    const int idx = t + (k << 8);
    const int row = idx >> 4, c4 = (idx & 15) << 2;
    const float4 v = *(const float4*)&ot[row * 68 + c4];
    *(float4*)&out[((long long)b * DD + d0 + row) * NN + n0 + c4] = v;
  }
}

// ================= Gram partials
__global__ void __launch_bounds__(256) gram_kernel(const float* __restrict__ M,
                                                   float* __restrict__ outp,
                                                   int rowsPerWave,
                                                   long long batchStride) {
  __shared__ float red[RR * RR];
  const int lane = threadIdx.x & 63;
  const int wid  = threadIdx.x >> 6;
  const int b    = blockIdx.y;
  const long long rowbase = (long long)(blockIdx.x * 4 + wid) * rowsPerWave;
  const float* Mp = M + (long long)b * batchStride + rowbase * RR;
  float acc[RR];
  #pragma unroll
  for (int k = 0; k < RR; ++k) acc[k] = 0.f;
  #pragma unroll 2
  for (int rr = 0; rr < rowsPerWave; ++rr) {
    const float v = Mp[(long long)rr * RR + lane];
    #pragma unroll
    for (int k = 0; k < RR; ++k) acc[k] = fmaf(__shfl(v, k), v, acc[k]);
  }
  for (int w = 0; w < 4; ++w) {
    if (wid == w) {
      if (w == 0) {
        #pragma unroll
        for (int k = 0; k < RR; ++k) red[k * RR + lane] = acc[k];
      } else {
        #pragma unroll
        for (int k = 0; k < RR; ++k) red[k * RR + lane] += acc[k];
      }
    }
    __syncthreads();
  }
  float* op = outp + ((long long)blockIdx.x * BSZ + b) * (RR * RR);
  for (int i = threadIdx.x; i < RR * RR; i += 256) op[i] = red[i];
}

// ================= numer2-partial-sum + bases update (ctc pre-summed)
__global__ void __launch_bounds__(256) bupdate_kernel(float* __restrict__ Bw,
                                                      const float* __restrict__ n2p,
                                                      const float* __restrict__ ctcs,
                                                      int ns2) {
  __shared__ float ct[4096];
  const int b  = blockIdx.y;
  const int d0 = blockIdx.x << 6;
  #pragma unroll
  for (int i = 0; i < 4; ++i) {
    const int w = threadIdx.x + (i << 8);
    ((float4*)ct)[w] = ((const float4*)(ctcs + (long long)b * 4096))[w];
  }
  __syncthreads();
  const int d  = d0 + (threadIdx.x >> 2);
  const int rq = (threadIdx.x & 3) << 4;

  float4 ns[4];
  #pragma unroll
  for (int j = 0; j < 4; ++j) ns[j] = make_float4(0.f, 0.f, 0.f, 0.f);
  for (int s = 0; s < ns2; ++s) {
    const float4* p = (const float4*)&n2p[(((long long)s * BSZ + b) * DD + d) * RR + rq];
    #pragma unroll
    for (int j = 0; j < 4; ++j) add4(ns[j], p[j]);
  }
  const float4* brow = (const float4*)&Bw[((long long)b * DD + d) * RR];
  float4 dn[4];
  #pragma unroll
  for (int j = 0; j < 4; ++j) dn[j] = make_float4(0.f, 0.f, 0.f, 0.f);
  for (int q = 0; q < 16; ++q) {
    const float4 b4 = brow[q];
    const float4* c0 = (const float4*)&ct[(4 * q + 0) * 64 + rq];
    const float4* c1 = (const float4*)&ct[(4 * q + 1) * 64 + rq];
    const float4* c2 = (const float4*)&ct[(4 * q + 2) * 64 + rq];
    const float4* c3 = (const float4*)&ct[(4 * q + 3) * 64 + rq];
    #pragma unroll
    for (int j = 0; j < 4; ++j) {
      fma4s(dn[j], c0[j], b4.x); fma4s(dn[j], c1[j], b4.y);
      fma4s(dn[j], c2[j], b4.z); fma4s(dn[j], c3[j], b4.w);
    }
  }
  float4* bp = (float4*)&Bw[((long long)b * DD + d) * RR + rq];
  float4 bo[4];
  #pragma unroll
  for (int j = 0; j < 4; ++j) bo[j] = bp[j];
  __syncthreads();
  #pragma unroll
  for (int j = 0; j < 4; ++j) {
    float4 o;
    o.x = bo[j].x * ns[j].x / (dn[j].x + EPS);
    o.y = bo[j].y * ns[j].y / (dn[j].y + EPS);
    o.z = bo[j].z * ns[j].z / (dn[j].z + EPS);
    o.w = bo[j].w * ns[j].w / (dn[j].w + EPS);
    bp[j] = o;
  }
}

// ================= fp32 fallback kernels (round-6 path) =================

template <int MODE>
__global__ void __launch_bounds__(128) fused_coef_kernel(const float* __restrict__ X,
                                                         const float* __restrict__ Bw,
                                                         const float* __restrict__ btbp,
                                                         float* __restrict__ coef) {
  __shared__ float lds[8192];
  const int b    = blockIdx.y;
  const int n0   = blockIdx.x << 6;
  const int t    = threadIdx.x;
  const int wid  = t >> 6;
  const int lane = t & 63;
  const int rgrp = t & 7;
  const int ngrp = t >> 3;
  const int nl   = ngrp << 2;
  const int r0   = rgrp << 3;
  const float* Xp = X  + (long long)b * DD * NN + n0;
  const float* Bp = Bw + (long long)b * DD * RR;

  float4 acc[4][2];
  #pragma unroll
  for (int i = 0; i < 4; ++i) { acc[i][0] = make_float4(0,0,0,0); acc[i][1] = make_float4(0,0,0,0); }

  auto stage = [&](int buf, int d0) {
    float* xd = lds + (buf << 11);
    float* bd = lds + 4096 + (buf << 11);
    const int rsub = lane >> 4;
    const int c4   = (lane & 15) << 2;
    #pragma unroll
    for (int j = 0; j < 4; ++j) {
      const int q   = (wid << 2) + j;
      const int row = (q << 2) + rsub;
      gload16(&Xp[(long long)(d0 + row) * NN + c4], xd + (q << 8));
      gload16(&Bp[(long long)(d0 + row) * RR + c4], bd + (q << 8));
    }
  };

  stage(0, 0);
  __syncthreads();
  for (int kt = 0; kt < 16; ++kt) {
    const int cur = kt & 1;
    if (kt + 1 < 16) stage(cur ^ 1, (kt + 1) << 5);
    const float* xs = lds + (cur << 11);
    const float* bs = lds + 4096 + (cur << 11);
    #pragma unroll 8
    for (int dd = 0; dd < 32; ++dd) {
      const float4 xv  = *(const float4*)&xs[(dd << 6) + nl];
      const float4 bv0 = *(const float4*)&bs[(dd << 6) + r0];
      const float4 bv1 = *(const float4*)&bs[(dd << 6) + r0 + 4];
      fma4s(acc[0][0], bv0, xv.x); fma4s(acc[0][1], bv1, xv.x);
      fma4s(acc[1][0], bv0, xv.y); fma4s(acc[1][1], bv1, xv.y);
      fma4s(acc[2][0], bv0, xv.z); fma4s(acc[2][1], bv1, xv.z);
      fma4s(acc[3][0], bv0, xv.w); fma4s(acc[3][1], bv1, xv.w);
    }
    __syncthreads();
  }

  if constexpr (MODE == 0) {
    #pragma unroll
    for (int i = 0; i < 4; ++i) {
      float4 a0 = acc[i][0], a1 = acc[i][1];
      float m = fmaxf(fmaxf(fmaxf(a0.x, a0.y), fmaxf(a0.z, a0.w)),
                      fmaxf(fmaxf(a1.x, a1.y), fmaxf(a1.z, a1.w)));
      m = fmaxf(m, __shfl_xor(m, 1));
      m = fmaxf(m, __shfl_xor(m, 2));
      m = fmaxf(m, __shfl_xor(m, 4));
      a0.x = __expf(a0.x - m); a0.y = __expf(a0.y - m);
      a0.z = __expf(a0.z - m); a0.w = __expf(a0.w - m);
      a1.x = __expf(a1.x - m); a1.y = __expf(a1.y - m);
      a1.z = __expf(a1.z - m); a1.w = __expf(a1.w - m);
      float s = a0.x + a0.y + a0.z + a0.w + a1.x + a1.y + a1.z + a1.w;
      s += __shfl_xor(s, 1); s += __shfl_xor(s, 2); s += __shfl_xor(s, 4);
      const float inv = 1.f / s;
      a0.x *= inv; a0.y *= inv; a0.z *= inv; a0.w *= inv;
      a1.x *= inv; a1.y *= inv; a1.z *= inv; a1.w *= inv;
      float* cp = coef + ((long long)b * NN + n0 + nl + i) * RR + r0;
      *(float4*)&cp[0] = a0;
      *(float4*)&cp[4] = a1;
    }
  } else {
    float4* G4  = (float4*)lds;
    float4* CO4 = (float4*)(lds + 4096);
    #pragma unroll
    for (int j = 0; j < 8; ++j) {
      const int wi = t + (j << 7);
      float4 ssum = make_float4(0,0,0,0);
      #pragma unroll
      for (int sp = 0; sp < NS_B; ++sp)
        add4(ssum, ((const float4*)(btbp + ((long long)sp * BSZ + b) * 4096))[wi]);
      G4[wi] = ssum;
    }
    const float4* cof4 = (const float4*)(coef + ((long long)b * NN + n0) * RR);
    #pragma unroll
    for (int j = 0; j < 8; ++j) {
      const int wi = t + (j << 7);
      const int row = wi >> 4, c4 = wi & 15;
      CO4[(row << 4) + (c4 ^ ((row >> 2) & 7))] = cof4[wi];
    }
    __syncthreads();
    const int g = ngrp & 7;
    float4 dn[4][2];
    #pragma unroll
    for (int i = 0; i < 4; ++i) { dn[i][0] = make_float4(0,0,0,0); dn[i][1] = make_float4(0,0,0,0); }
    #pragma unroll 4
    for (int kq = 0; kq < 16; ++kq) {
      float4 g0[4], g1[4];
      #pragma unroll
      for (int jj = 0; jj < 4; ++jj) {
        g0[jj] = G4[(((kq << 2) + jj) << 4) + (rgrp << 1)];
        g1[jj] = G4[(((kq << 2) + jj) << 4) + (rgrp << 1) + 1];
      }
      #pragma unroll
      for (int i = 0; i < 4; ++i) {
        const float4 cv = CO4[((nl + i) << 4) + (kq ^ g)];
        fma4s(dn[i][0], g0[0], cv.x); fma4s(dn[i][1], g1[0], cv.x);
        fma4s(dn[i][0], g0[1], cv.y); fma4s(dn[i][1], g1[1], cv.y);
        fma4s(dn[i][0], g0[2], cv.z); fma4s(dn[i][1], g1[2], cv.z);
        fma4s(dn[i][0], g0[3], cv.w); fma4s(dn[i][1], g1[3], cv.w);
      }
    }
    #pragma unroll
    for (int i = 0; i < 4; ++i) {
      const int row = nl + i;
      const float4 c0 = CO4[(row << 4) + ((rgrp << 1) ^ g)];
      const float4 c1 = CO4[(row << 4) + (((rgrp << 1) + 1) ^ g)];
      float4 o0, o1;
      o0.x = c0.x * acc[i][0].x / (dn[i][0].x + EPS);
      o0.y = c0.y * acc[i][0].y / (dn[i][0].y + EPS);
      o0.z = c0.z * acc[i][0].z / (dn[i][0].z + EPS);
      o0.w = c0.w * acc[i][0].w / (dn[i][0].w + EPS);
      o1.x = c1.x * acc[i][1].x / (dn[i][1].x + EPS);
      o1.y = c1.y * acc[i][1].y / (dn[i][1].y + EPS);
      o1.z = c1.z * acc[i][1].z / (dn[i][1].z + EPS);
      o1.w = c1.w * acc[i][1].w / (dn[i][1].w + EPS);
      float* cp = coef + ((long long)b * NN + n0 + row) * RR + r0;
      *(float4*)&cp[0] = o0;
      *(float4*)&cp[4] = o1;
    }
  }
}

__global__ void __launch_bounds__(128) numer2_kernel(const float* __restrict__ X,
                                                     const float* __restrict__ coef,
                                                     float* __restrict__ n2p) {
  __shared__ float lds[8192];
  const int b    = blockIdx.z;
  const int s    = blockIdx.y;
  const int d0   = blockIdx.x << 6;
  const int t    = threadIdx.x;
  const int wid  = t >> 6;
  const int lane = t & 63;
  const int rgrp = t & 7;
  const int dgrp = t >> 3;
  const int dl   = dgrp << 2;
  const int r0   = rgrp << 3;
  const int nbeg = s * (NN / NS_N2);
  const float* Xp = X + (long long)b * DD * NN + (long long)d0 * NN;
  const float* Cp = coef + (long long)b * NN * RR;

  float4 acc[4][2];
  #pragma unroll
  for (int i = 0; i < 4; ++i) { acc[i][0] = make_float4(0,0,0,0); acc[i][1] = make_float4(0,0,0,0); }

  auto stage = [&](int buf, int nb) {
    float* xd = lds + (buf << 11);
    float* cd = lds + 4096 + (buf << 11);
    {
      const int rsub = lane >> 3, c4 = lane & 7;
      #pragma unroll
      for (int j = 0; j < 4; ++j) {
        const int q   = (wid << 2) + j;
        const int row = (q << 3) + rsub;
        const int sc  = (c4 ^ ((row >> 2) & 7)) << 2;
        gload16(&Xp[(long long)row * NN + nb + sc], xd + (q << 8));
      }
    }
    {
      const int rsub = lane >> 4, c4 = (lane & 15) << 2;
      #pragma unroll
      for (int j = 0; j < 4; ++j) {
        const int q   = (wid << 2) + j;
        const int row = (q << 2) + rsub;
        gload16(&Cp[(long long)(nb + row) * RR + c4], cd + (q << 8));
      }
    }
  };

  stage(0, nbeg);
  __syncthreads();
  const int g = dgrp & 7;
  for (int kt = 0; kt < (NN / NS_N2) / 32; ++kt) {
    const int cur = kt & 1;
    if (kt + 1 < (NN / NS_N2) / 32) stage(cur ^ 1, nbeg + ((kt + 1) << 5));
    const float* xs = lds + (cur << 11);
    const float* cs = lds + 4096 + (cur << 11);
    #pragma unroll 8
    for (int nn = 0; nn < 32; ++nn) {
      const int col = ((((nn >> 2) ^ g) << 2) + (nn & 3));
      float xe[4];
      #pragma unroll
      for (int i = 0; i < 4; ++i) xe[i] = xs[((dl + i) << 5) + col];
      const float4 cv0 = *(const float4*)&cs[(nn << 6) + r0];
      const float4 cv1 = *(const float4*)&cs[(nn << 6) + r0 + 4];
      #pragma unroll
      for (int i = 0; i < 4; ++i) {
        fma4s(acc[i][0], cv0, xe[i]);
        fma4s(acc[i][1], cv1, xe[i]);
      }
    }
    __syncthreads();
  }
  #pragma unroll
  for (int i = 0; i < 4; ++i) {
    float* op = n2p + (((long long)s * BSZ + b) * DD + d0 + dl + i) * RR + r0;
    *(float4*)&op[0] = acc[i][0];
    *(float4*)&op[4] = acc[i][1];
  }
}

__global__ void __launch_bounds__(256) bupdate_fb_kernel(float* __restrict__ Bw,
                                                         const float* __restrict__ n2p,
                                                         const float* __restrict__ ctcp,
                                                         int ns2) {
  __shared__ float ct[4096];
  const int b  = blockIdx.y;
  const int d0 = blockIdx.x << 6;
  #pragma unroll
  for (int i = 0; i < 4; ++i) {
    const int w = threadIdx.x + (i << 8);
    float4 s = make_float4(0.f, 0.f, 0.f, 0.f);
    for (int sp = 0; sp < NS_C; ++sp)
      add4(s, ((const float4*)(ctcp + ((long long)sp * BSZ + b) * 4096))[w]);
    ((float4*)ct)[w] = s;
  }
  __syncthreads();
  const int d  = d0 + (threadIdx.x >> 2);
  const int rq = (threadIdx.x & 3) << 4;

  float4 ns[4];
  #pragma unroll
  for (int j = 0; j < 4; ++j) ns[j] = make_float4(0.f, 0.f, 0.f, 0.f);
  for (int s = 0; s < ns2; ++s) {
    const float4* p = (const float4*)&n2p[(((long long)s * BSZ + b) * DD + d) * RR + rq];
    #pragma unroll
    for (int j = 0; j < 4; ++j) add4(ns[j], p[j]);
  }
  const float4* brow = (const float4*)&Bw[((long long)b * DD + d) * RR];
  float4 dn[4];
  #pragma unroll
  for (int j = 0; j < 4; ++j) dn[j] = make_float4(0.f, 0.f, 0.f, 0.f);
  for (int q = 0; q < 16; ++q) {
    const float4 b4 = brow[q];
    const float4* c0 = (const float4*)&ct[(4 * q + 0) * 64 + rq];
    const float4* c1 = (const float4*)&ct[(4 * q + 1) * 64 + rq];
    const float4* c2 = (const float4*)&ct[(4 * q + 2) * 64 + rq];
    const float4* c3 = (const float4*)&ct[(4 * q + 3) * 64 + rq];
    #pragma unroll
    for (int j = 0; j < 4; ++j) {
      fma4s(dn[j], c0[j], b4.x); fma4s(dn[j], c1[j], b4.y);
      fma4s(dn[j], c2[j], b4.z); fma4s(dn[j], c3[j], b4.w);
    }
  }
  float4* bp = (float4*)&Bw[((long long)b * DD + d) * RR + rq];
  float4 bo[4];
  #pragma unroll
  for (int j = 0; j < 4; ++j) bo[j] = bp[j];
  __syncthreads();
  #pragma unroll
  for (int j = 0; j < 4; ++j) {
    float4 o;
    o.x = bo[j].x * ns[j].x / (dn[j].x + EPS);
    o.y = bo[j].y * ns[j].y / (dn[j].y + EPS);
    o.z = bo[j].z * ns[j].z / (dn[j].z + EPS);
    o.w = bo[j].w * ns[j].w / (dn[j].w + EPS);
    bp[j] = o;
  }
}

__global__ void __launch_bounds__(256) out_kernel(const float* __restrict__ Bw,
                                                  const float* __restrict__ coef,
                                                  float* __restrict__ out) {
  __shared__ float bt [64 * 68];
  __shared__ float ctl[64 * 68];
  const int n0 = blockIdx.x << 6;
  const int d0 = blockIdx.y << 6;
  const int b  = blockIdx.z;
  const int tx = threadIdx.x & 15;
  const int ty = threadIdx.x >> 4;
  for (int t = threadIdx.x; t < 1024; t += 256) {
    const int row = t >> 4, c4 = (t & 15) << 2;
    const float4 v = *(const float4*)&Bw[((long long)b * DD + d0 + row) * RR + c4];
    bt[(c4 + 0) * 68 + row] = v.x; bt[(c4 + 1) * 68 + row] = v.y;
    bt[(c4 + 2) * 68 + row] = v.z; bt[(c4 + 3) * 68 + row] = v.w;
  }
  for (int t = threadIdx.x; t < 1024; t += 256) {
    const int row = t >> 4, c4 = (t & 15) << 2;
    const float4 v = *(const float4*)&coef[((long long)b * NN + n0 + row) * RR + c4];
    ctl[(c4 + 0) * 68 + row] = v.x; ctl[(c4 + 1) * 68 + row] = v.y;
    ctl[(c4 + 2) * 68 + row] = v.z; ctl[(c4 + 3) * 68 + row] = v.w;
  }
  __syncthreads();
  float4 ai[4];
  #pragma unroll
  for (int i = 0; i < 4; ++i) ai[i] = make_float4(0.f, 0.f, 0.f, 0.f);
  #pragma unroll 8
  for (int r = 0; r < 64; ++r) {
    const float4 bv = *(const float4*)&bt [r * 68 + (ty << 2)];
    const float4 cv = *(const float4*)&ctl[r * 68 + (tx << 2)];
    fma4s(ai[0], cv, bv.x); fma4s(ai[1], cv, bv.y);
    fma4s(ai[2], cv, bv.z); fma4s(ai[3], cv, bv.w);
  }
  #pragma unroll
  for (int i = 0; i < 4; ++i)
    *(float4*)&out[((long long)b * DD + d0 + (ty << 2) + i) * NN + n0 + (tx << 2)] = ai[i];
}

extern "C" void kernel_launch(void* const* d_in, const int* in_sizes, int n_in,
                              void* d_out, int out_size, void* d_ws, size_t ws_size,
                              hipStream_t stream) {
  const float* x        = (const float*)d_in[0];
  const float* bases_in = (const float*)d_in[1];
  float* out = (float*)d_out;
  float* ws  = (float*)d_ws;

  float* coef    = ws;
  float* bases_w = coef + (long long)BSZ * NN * RR;
  float* btbp    = bases_w + (long long)BSZ * DD * RR;
  float* ctcp    = btbp + (long long)NS_B * BSZ * 4096;
  float* n2p     = ctcp + (long long)NS_C * BSZ * 4096;
  unsigned short* xbTh = (unsigned short*)(n2p + (long long)NS_N2 * BSZ * DD * RR);
  unsigned short* xbTl = xbTh + (long long)BSZ * NN * DD;
  unsigned short* BbT  = xbTl + (long long)BSZ * NN * DD;
  unsigned short* cbT  = BbT + (long long)BSZ * RR * DD;
  unsigned short* Gh   = cbT + (long long)BSZ * RR * NN;
  unsigned short* Gl   = Gh + (long long)BSZ * 4096;
  float* ctcs          = (float*)(Gl + (long long)BSZ * 4096);
  const long long need = (long long)((char*)(ctcs + (long long)BSZ * 4096) - (char*)d_ws);

  // aliases, live only after the loop (ctcp/n2p dead by then)
  unsigned short* cNh = (unsigned short*)ctcp;                 // 8 MB
  unsigned short* cNl = (unsigned short*)n2p;                  // 8 of 16 MB
  unsigned short* bDh = cNl + (long long)BSZ * NN * RR;        // 1 MB
  unsigned short* bDl = bDh + (long long)BSZ * DD * RR;        // 1 MB

  const dim3 blk256(256);
  const dim3 blk128(128);

  hipMemcpyAsync(bases_w, bases_in, sizeof(float) * BSZ * DD * RR,
                 hipMemcpyDeviceToDevice, stream);

  if ((long long)ws_size >= need) {
    // ---------- bf16-MFMA path ----------
    tcvt_kernel<true><<<dim3(NN / 64, DD / 64, BSZ), blk256, 0, stream>>>(x, xbTh, xbTl, DD, NN);
    tcvt_kernel<false><<<dim3(1, DD / 64, BSZ), blk256, 0, stream>>>(bases_w, BbT, nullptr, DD, RR);
    fused_mfma_kernel<0><<<dim3(NN / 32, BSZ), blk128, 0, stream>>>(
        xbTh, xbTl, BbT, nullptr, nullptr, coef, nullptr, nullptr, nullptr);

    for (int it = 0; it < STEPS; ++it) {
      tcvt_kernel<false><<<dim3(1, DD / 64, BSZ), blk256, 0, stream>>>(bases_w, BbT, nullptr, DD, RR);
      gram_kernel<<<dim3(NS_B, BSZ), blk256, 0, stream>>>(bases_w, btbp, DD / (NS_B * 4),
                                                          (long long)DD * RR);
      gsum_kernel<<<dim3(BSZ), blk256, 0, stream>>>(btbp, Gh, Gl);
      fused_mfma_kernel<1><<<dim3(NN / 32, BSZ), blk128, 0, stream>>>(
          xbTh, xbTl, BbT, Gh, Gl, coef, cbT, nullptr, nullptr);
      gram_kernel<<<dim3(NS_C, BSZ), blk256, 0, stream>>>(coef, ctcp, NN / (NS_C * 4),
                                                          (long long)NN * RR);
      csum_kernel<<<dim3(BSZ), blk256, 0, stream>>>(ctcp, ctcs, NS_C);
      numer2_mfma_kernel<<<dim3(DD / 64, NS_N2, BSZ), blk128, 0, stream>>>(x, cbT, n2p);
      bupdate_kernel<<<dim3(DD / 64, BSZ), blk256, 0, stream>>>(bases_w, n2p, ctcs, NS_N2);
    }
    // compute_coef: final update emits bf16 coef layouts directly
    tcvt_kernel<false><<<dim3(1, DD / 64, BSZ), blk256, 0, stream>>>(bases_w, BbT, nullptr, DD, RR);
    gram_kernel<<<dim3(NS_B, BSZ), blk256, 0, stream>>>(bases_w, btbp, DD / (NS_B * 4),
                                                        (long long)DD * RR);
    gsum_kernel<<<dim3(BSZ), blk256, 0, stream>>>(btbp, Gh, Gl);
    fused_mfma_kernel<2><<<dim3(NN / 32, BSZ), blk128, 0, stream>>>(
        xbTh, xbTl, BbT, Gh, Gl, coef, nullptr, cNh, cNl);
    casthl_kernel<<<dim3(256), blk256, 0, stream>>>(bases_w, bDh, bDl, (long long)BSZ * DD * RR);
    out_mfma_kernel<<<dim3(NN / 64, DD / 64, BSZ), blk256, 0, stream>>>(bDh, bDl, cNh, cNl, out);
  } else {
    // ---------- fp32 fallback (round-6 path) ----------
    fused_coef_kernel<0><<<dim3(NN / 64, BSZ), blk128, 0, stream>>>(x, bases_w, nullptr, coef);
    for (int it = 0; it < STEPS; ++it) {
      gram_kernel<<<dim3(NS_B, BSZ), blk256, 0, stream>>>(bases_w, btbp, DD / (NS_B * 4),
                                                          (long long)DD * RR);
      fused_coef_kernel<1><<<dim3(NN / 64, BSZ), blk128, 0, stream>>>(x, bases_w, btbp, coef);
      gram_kernel<<<dim3(NS_C, BSZ), blk256, 0, stream>>>(coef, ctcp, NN / (NS_C * 4),
                                                          (long long)NN * RR);
      numer2_kernel<<<dim3(DD / 64, NS_N2, BSZ), blk128, 0, stream>>>(x, coef, n2p);
      bupdate_fb_kernel<<<dim3(DD / 64, BSZ), blk256, 0, stream>>>(bases_w, n2p, ctcp, NS_N2);
    }
    gram_kernel<<<dim3(NS_B, BSZ), blk256, 0, stream>>>(bases_w, btbp, DD / (NS_B * 4),
                                                        (long long)DD * RR);
    fused_coef_kernel<1><<<dim3(NN / 64, BSZ), blk128, 0, stream>>>(x, bases_w, btbp, coef);
    out_kernel<<<dim3(NN / 64, DD / 64, BSZ), blk256, 0, stream>>>(bases_w, coef, out);
  }
}

// Round 10
// 1265.037 us; speedup vs baseline: 1.4729x; 1.4729x over previous
//
#include <hip/hip_runtime.h>
#include <math.h>

#define EPS 1e-6f

constexpr int BSZ = 16;    // batch * S
constexpr int DD  = 512;   // channels / S
constexpr int NN  = 4096;  // H*W
constexpr int RR  = 64;
constexpr int STEPS = 7;
constexpr int NS_B  = 8;   // BtB d-split blocks
constexpr int NS_C  = 32;  // CtC partial slots (8 blocks x 4 waves)
constexpr int NS_N2 = 8;   // numer2 n-split partials

typedef _Float16 half_t;
typedef __attribute__((ext_vector_type(8))) _Float16 half8;
typedef __attribute__((ext_vector_type(4))) _Float16 half4;
typedef __attribute__((ext_vector_type(4))) float f32x4;

__device__ __forceinline__ void fma4s(float4& a, const float4& b, float s) {
  a.x = fmaf(b.x, s, a.x); a.y = fmaf(b.y, s, a.y);
  a.z = fmaf(b.z, s, a.z); a.w = fmaf(b.w, s, a.w);
}
__device__ __forceinline__ void add4(float4& a, const float4& b) {
  a.x += b.x; a.y += b.y; a.z += b.z; a.w += b.w;
}
__device__ __forceinline__ f32x4 mfmah(half8 a, half8 b, f32x4 c) {
  return __builtin_amdgcn_mfma_f32_16x16x32_f16(a, b, c, 0, 0, 0);
}

// async global->LDS, 16B per lane (fp32 fallback path)
__device__ __forceinline__ void gload16(const float* g, float* l) {
  __builtin_amdgcn_global_load_lds(
      (const __attribute__((address_space(1))) void*)g,
      (__attribute__((address_space(3))) void*)l, 16, 0, 0);
}

// ================= transpose + fp32->fp16: src [b][R][C] -> dst [b][C][R]
__global__ void __launch_bounds__(256) tcvt16_kernel(const float* __restrict__ src,
                                                     half_t* __restrict__ dh,
                                                     int R, int C) {
  __shared__ float tileT[64 * 65];   // [src_col][src_row]
  const int b = blockIdx.z, c0 = blockIdx.x << 6, r0 = blockIdx.y << 6;
  const float* sp = src + (long long)b * R * C;
  const int t = threadIdx.x;
  #pragma unroll
  for (int i = 0; i < 4; ++i) {
    const int idx = t + (i << 8);
    const int row = idx >> 4, c4 = (idx & 15) << 2;
    const float4 v = *(const float4*)&sp[(long long)(r0 + row) * C + c0 + c4];
    tileT[(c4 + 0) * 65 + row] = v.x;
    tileT[(c4 + 1) * 65 + row] = v.y;
    tileT[(c4 + 2) * 65 + row] = v.z;
    tileT[(c4 + 3) * 65 + row] = v.w;
  }
  __syncthreads();
  const int orow = t >> 2, och = (t & 3) << 4;
  half8 h0, h1;
  #pragma unroll
  for (int j = 0; j < 8; ++j) h0[j] = (half_t)tileT[orow * 65 + och + j];
  #pragma unroll
  for (int j = 0; j < 8; ++j) h1[j] = (half_t)tileT[orow * 65 + och + 8 + j];
  const long long ob = ((long long)b * C + c0 + orow) * R + r0 + och;
  *(half8*)&dh[ob] = h0;
  *(half8*)&dh[ob + 8] = h1;
}

// ================= flat fp32 -> fp16 cast
__global__ void __launch_bounds__(256) cast16_kernel(const float* __restrict__ src,
                                                     half_t* __restrict__ dst,
                                                     long long n) {
  const long long i = ((long long)blockIdx.x * 256 + threadIdx.x) * 8;
  if (i >= n) return;
  const float4 a = *(const float4*)&src[i];
  const float4 c = *(const float4*)&src[i + 4];
  half8 h;
  h[0] = (half_t)a.x; h[1] = (half_t)a.y; h[2] = (half_t)a.z; h[3] = (half_t)a.w;
  h[4] = (half_t)c.x; h[5] = (half_t)c.y; h[6] = (half_t)c.z; h[7] = (half_t)c.w;
  *(half8*)&dst[i] = h;
}

// ================= sum BtB partials -> fp16 G (once per iteration)
__global__ void __launch_bounds__(256) gsum16_kernel(const float* __restrict__ btbp,
                                                     half_t* __restrict__ Gh) {
  const int b = blockIdx.x;
  for (int i = threadIdx.x; i < 1024; i += 256) {
    float4 s = make_float4(0.f, 0.f, 0.f, 0.f);
    #pragma unroll
    for (int sp = 0; sp < NS_B; ++sp)
      add4(s, ((const float4*)(btbp + ((long long)sp * BSZ + b) * 4096))[i]);
    half4 h;
    h[0] = (half_t)s.x; h[1] = (half_t)s.y; h[2] = (half_t)s.z; h[3] = (half_t)s.w;
    *(half4*)&Gh[(long long)b * 4096 + (long long)i * 4] = h;
  }
}

// ================= sum CtC partials (fp32)
__global__ void __launch_bounds__(256) csum_kernel(const float* __restrict__ src,
                                                   float* __restrict__ dst, int nsp) {
  const int b = blockIdx.x;
  for (int i = threadIdx.x; i < 1024; i += 256) {
    float4 s = make_float4(0.f, 0.f, 0.f, 0.f);
    for (int sp = 0; sp < nsp; ++sp)
      add4(s, ((const float4*)(src + ((long long)sp * BSZ + b) * 4096))[i]);
    ((float4*)(dst + (long long)b * 4096))[i] = s;
  }
}

// ================= fp16-MFMA fused numer + {softmax | coef update}
// MODE0: coef = softmax(numer).  MODE1: coef *= numer/(cold@G+eps); emits cbT
// via LDS transpose (coalesced).  MODE2 (final): emits cN fp16 [n][r] only.
// 128 thr = 2 waves; block = 32 n-rows x 64 r; wave owns 16 rows.
template <int MODE>
__global__ void __launch_bounds__(128) fused16_kernel(const half_t* __restrict__ xT,
                                                      const half_t* __restrict__ BT,
                                                      const half_t* __restrict__ Gh,
                                                      float* __restrict__ coef,
                                                      half_t* __restrict__ cbT,
                                                      half_t* __restrict__ cN) {
  __shared__ half_t ctile[(MODE == 1) ? 64 * 40 : 8];
  const int b  = blockIdx.y;
  const int n0 = blockIdx.x << 5;
  const int t  = threadIdx.x;
  const int w  = t >> 6;
  const int l  = t & 63;
  const int row16 = l & 15;
  const int koff  = (l >> 4) << 3;
  const int nrb   = n0 + (w << 4);

  const half_t* ap = xT + ((long long)b * NN + nrb + row16) * DD + koff;
  const half_t* bp = BT + ((long long)b * RR + row16) * DD + koff;

  f32x4 acc[4];
  #pragma unroll
  for (int rs = 0; rs < 4; ++rs) acc[rs] = (f32x4){0.f, 0.f, 0.f, 0.f};

  #pragma unroll
  for (int kt = 0; kt < 16; ++kt) {
    const int ko = kt << 5;
    const half8 av = *(const half8*)&ap[ko];
    #pragma unroll
    for (int rs = 0; rs < 4; ++rs) {
      const half8 bv = *(const half8*)&bp[rs * 16 * DD + ko];
      acc[rs] = mfmah(av, bv, acc[rs]);
    }
  }

  if constexpr (MODE == 0) {
    #pragma unroll
    for (int j = 0; j < 4; ++j) {
      float m = fmaxf(fmaxf(acc[0][j], acc[1][j]), fmaxf(acc[2][j], acc[3][j]));
      m = fmaxf(m, __shfl_xor(m, 1));
      m = fmaxf(m, __shfl_xor(m, 2));
      m = fmaxf(m, __shfl_xor(m, 4));
      m = fmaxf(m, __shfl_xor(m, 8));
      float s = 0.f;
      #pragma unroll
      for (int rs = 0; rs < 4; ++rs) { acc[rs][j] = __expf(acc[rs][j] - m); s += acc[rs][j]; }
      s += __shfl_xor(s, 1); s += __shfl_xor(s, 2);
      s += __shfl_xor(s, 4); s += __shfl_xor(s, 8);
      const float inv = 1.f / s;
      #pragma unroll
      for (int rs = 0; rs < 4; ++rs) acc[rs][j] *= inv;
    }
    #pragma unroll
    for (int rs = 0; rs < 4; ++rs)
      #pragma unroll
      for (int j = 0; j < 4; ++j)
        coef[((long long)b * NN + nrb + ((l >> 4) << 2) + j) * RR + (rs << 4) + row16] = acc[rs][j];
  } else {
    // denom = cold @ G via fp16 MFMA (G symmetric -> rows are k-contiguous)
    const float* crow = coef + ((long long)b * NN + nrb + row16) * RR;
    const half_t* ghb = Gh + (long long)b * 4096;
    f32x4 dn[4];
    #pragma unroll
    for (int rs = 0; rs < 4; ++rs) dn[rs] = (f32x4){0.f, 0.f, 0.f, 0.f};
    #pragma unroll
    for (int kt = 0; kt < 2; ++kt) {
      const int ko = (kt << 5) + koff;
      const float4 c0 = *(const float4*)&crow[ko];
      const float4 c1 = *(const float4*)&crow[ko + 4];
      half8 ch;
      ch[0] = (half_t)c0.x; ch[1] = (half_t)c0.y; ch[2] = (half_t)c0.z; ch[3] = (half_t)c0.w;
      ch[4] = (half_t)c1.x; ch[5] = (half_t)c1.y; ch[6] = (half_t)c1.z; ch[7] = (half_t)c1.w;
      #pragma unroll
      for (int rs = 0; rs < 4; ++rs) {
        const half8 gh = *(const half8*)&ghb[((rs << 4) + row16) * 64 + ko];
        dn[rs] = mfmah(ch, gh, dn[rs]);
      }
    }
    // multiplicative update (element-owner unique in D-frag positions)
    #pragma unroll
    for (int rs = 0; rs < 4; ++rs)
      #pragma unroll
      for (int j = 0; j < 4; ++j) {
        const int r = (rs << 4) + row16;
        const int nl = ((w << 4) + ((l >> 4) << 2) + j);   // n - n0
        const long long idx = ((long long)b * NN + n0 + nl) * RR + r;
        const float co = coef[idx];
        const float v  = co * acc[rs][j] / (dn[rs][j] + EPS);
        if constexpr (MODE == 1) {
          coef[idx] = v;
          ctile[r * 40 + nl] = (half_t)v;
        } else {
          cN[idx] = (half_t)v;
        }
      }
    if constexpr (MODE == 1) {
      __syncthreads();
      if (t < 64) {   // row r = t: write 32 contiguous fp16 (64 B) to cbT
        half_t* dst = cbT + ((long long)b * RR + t) * NN + n0;
        *(half8*)&dst[0]  = *(const half8*)&ctile[t * 40 + 0];
        *(half8*)&dst[8]  = *(const half8*)&ctile[t * 40 + 8];
        *(half8*)&dst[16] = *(const half8*)&ctile[t * 40 + 16];
        *(half8*)&dst[24] = *(const half8*)&ctile[t * 40 + 24];
      }
    }
  }
}

// ================= CtC partials via fp16 MFMA: ctcp[sp2][b][r1][r2]
// grid (8, BSZ) x 256 thr; wave w covers n-slice (sp*4+w)*128..+128.
__global__ void __launch_bounds__(256) ctc16_kernel(const half_t* __restrict__ cbT,
                                                    float* __restrict__ ctcp) {
  const int b  = blockIdx.y;
  const int t  = threadIdx.x;
  const int w  = t >> 6;
  const int l  = t & 63;
  const int row16 = l & 15;
  const int koff  = (l >> 4) << 3;
  const int sp2   = blockIdx.x * 4 + w;
  const int nbeg  = sp2 * 128;

  const half_t* ap = cbT + ((long long)b * RR + row16) * NN + nbeg + koff;

  f32x4 acc[4][4];
  #pragma unroll
  for (int i = 0; i < 4; ++i)
    #pragma unroll
    for (int j = 0; j < 4; ++j) acc[i][j] = (f32x4){0.f, 0.f, 0.f, 0.f};

  #pragma unroll
  for (int kt = 0; kt < 4; ++kt) {
    const int ko = kt << 5;
    half8 af[4];
    #pragma unroll
    for (int rs = 0; rs < 4; ++rs) af[rs] = *(const half8*)&ap[(long long)rs * 16 * NN + ko];
    #pragma unroll
    for (int r1 = 0; r1 < 4; ++r1)
      #pragma unroll
      for (int r2 = 0; r2 < 4; ++r2)
        acc[r1][r2] = mfmah(af[r1], af[r2], acc[r1][r2]);
  }
  float* op = ctcp + ((long long)sp2 * BSZ + b) * 4096;
  #pragma unroll
  for (int r1 = 0; r1 < 4; ++r1)
    #pragma unroll
    for (int r2 = 0; r2 < 4; ++r2)
      #pragma unroll
      for (int j = 0; j < 4; ++j)
        op[((r1 << 4) + ((l >> 4) << 2) + j) * 64 + (r2 << 4) + row16] = acc[r1][r2][j];
}

// ================= numer2 partials via fp16 MFMA
__global__ void __launch_bounds__(128) numer2_16_kernel(const half_t* __restrict__ xh,
                                                        const half_t* __restrict__ cbT,
                                                        float* __restrict__ n2p) {
  const int b  = blockIdx.z;
  const int s  = blockIdx.y;
  const int d0 = blockIdx.x << 6;
  const int t  = threadIdx.x;
  const int w  = t >> 6;
  const int l  = t & 63;
  const int row16 = l & 15;
  const int koff  = (l >> 4) << 3;
  const int nbeg  = s * (NN / NS_N2);

  const half_t* ap = xh + ((long long)b * DD + d0 + w * 32 + row16) * NN + nbeg + koff;
  const half_t* cp = cbT + ((long long)b * RR + row16) * NN + nbeg + koff;

  f32x4 acc[2][4];
  #pragma unroll
  for (int ds = 0; ds < 2; ++ds)
    #pragma unroll
    for (int rs = 0; rs < 4; ++rs) acc[ds][rs] = (f32x4){0.f, 0.f, 0.f, 0.f};

  #pragma unroll
  for (int kt = 0; kt < 16; ++kt) {
    const int ko = kt << 5;
    half8 av[2], bf[4];
    #pragma unroll
    for (int ds = 0; ds < 2; ++ds) av[ds] = *(const half8*)&ap[(long long)ds * 16 * NN + ko];
    #pragma unroll
    for (int rs = 0; rs < 4; ++rs) bf[rs] = *(const half8*)&cp[(long long)rs * 16 * NN + ko];
    #pragma unroll
    for (int ds = 0; ds < 2; ++ds)
      #pragma unroll
      for (int rs = 0; rs < 4; ++rs)
        acc[ds][rs] = mfmah(av[ds], bf[rs], acc[ds][rs]);
  }
  float* op = n2p + (((long long)s * BSZ + b) * DD + d0 + w * 32) * RR;
  #pragma unroll
  for (int ds = 0; ds < 2; ++ds)
    #pragma unroll
    for (int rs = 0; rs < 4; ++rs)
      #pragma unroll
      for (int j = 0; j < 4; ++j)
        op[(long long)(ds * 16 + ((l >> 4) << 2) + j) * RR + (rs << 4) + row16] = acc[ds][rs][j];
}

// ================= out via fp16 MFMA, LDS-staged coalesced stores
__global__ void __launch_bounds__(256) out16_kernel(const half_t* __restrict__ bD,
                                                    const half_t* __restrict__ cN,
                                                    float* __restrict__ out) {
  __shared__ float ot[64 * 68];
  const int n0 = blockIdx.x << 6;
  const int d0 = blockIdx.y << 6;
  const int b  = blockIdx.z;
  const int t  = threadIdx.x;
  const int w  = t >> 6;
  const int l  = t & 63;
  const int row16 = l & 15;
  const int koff  = (l >> 4) << 3;

  const half_t* ap = bD + ((long long)b * DD + d0 + (w << 4) + row16) * RR + koff;
  const half_t* bp = cN + ((long long)b * NN + n0 + row16) * RR + koff;

  f32x4 acc[4];
  #pragma unroll
  for (int ns = 0; ns < 4; ++ns) acc[ns] = (f32x4){0.f, 0.f, 0.f, 0.f};

  #pragma unroll
  for (int kt = 0; kt < 2; ++kt) {
    const int ko = kt << 5;
    const half8 av = *(const half8*)&ap[ko];
    #pragma unroll
    for (int ns = 0; ns < 4; ++ns) {
      const half8 bv = *(const half8*)&bp[(long long)ns * 16 * RR + ko];
      acc[ns] = mfmah(av, bv, acc[ns]);
    }
  }
  #pragma unroll
  for (int ns = 0; ns < 4; ++ns)
    #pragma unroll
    for (int j = 0; j < 4; ++j)
      ot[((w << 4) + ((l >> 4) << 2) + j) * 68 + (ns << 4) + row16] = acc[ns][j];
  __syncthreads();
  #pragma unroll
  for (int k = 0; k < 4; ++k) {
    const int idx = t + (k << 8);
    const int row = idx >> 4, c4 = (idx & 15) << 2;
    const float4 v = *(const float4*)&ot[row * 68 + c4];
    *(float4*)&out[((long long)b * DD + d0 + row) * NN + n0 + c4] = v;
  }
}

// ================= Gram partials (fp32, for BtB)
__global__ void __launch_bounds__(256) gram_kernel(const float* __restrict__ M,
                                                   float* __restrict__ outp,
                                                   int rowsPerWave,
                                                   long long batchStride) {
  __shared__ float red[RR * RR];
  const int lane = threadIdx.x & 63;
  const int wid  = threadIdx.x >> 6;
  const int b    = blockIdx.y;
  const long long rowbase = (long long)(blockIdx.x * 4 + wid) * rowsPerWave;
  const float* Mp = M + (long long)b * batchStride + rowbase * RR;
  float acc[RR];
  #pragma unroll
  for (int k = 0; k < RR; ++k) acc[k] = 0.f;
  #pragma unroll 2
  for (int rr = 0; rr < rowsPerWave; ++rr) {
    const float v = Mp[(long long)rr * RR + lane];
    #pragma unroll
    for (int k = 0; k < RR; ++k) acc[k] = fmaf(__shfl(v, k), v, acc[k]);
  }
  for (int w = 0; w < 4; ++w) {
    if (wid == w) {
      if (w == 0) {
        #pragma unroll
        for (int k = 0; k < RR; ++k) red[k * RR + lane] = acc[k];
      } else {
        #pragma unroll
        for (int k = 0; k < RR; ++k) red[k * RR + lane] += acc[k];
      }
    }
    __syncthreads();
  }
  float* op = outp + ((long long)blockIdx.x * BSZ + b) * (RR * RR);
  for (int i = threadIdx.x; i < RR * RR; i += 256) op[i] = red[i];
}

// ================= numer2-partial-sum + bases update (ctc pre-summed)
__global__ void __launch_bounds__(256) bupdate_kernel(float* __restrict__ Bw,
                                                      const float* __restrict__ n2p,
                                                      const float* __restrict__ ctcs,
                                                      int ns2) {
  __shared__ float ct[4096];
  const int b  = blockIdx.y;
  const int d0 = blockIdx.x << 6;
  #pragma unroll
  for (int i = 0; i < 4; ++i) {
    const int w = threadIdx.x + (i << 8);
    ((float4*)ct)[w] = ((const float4*)(ctcs + (long long)b * 4096))[w];
  }
  __syncthreads();
  const int d  = d0 + (threadIdx.x >> 2);
  const int rq = (threadIdx.x & 3) << 4;

  float4 ns[4];
  #pragma unroll
  for (int j = 0; j < 4; ++j) ns[j] = make_float4(0.f, 0.f, 0.f, 0.f);
  for (int s = 0; s < ns2; ++s) {
    const float4* p = (const float4*)&n2p[(((long long)s * BSZ + b) * DD + d) * RR + rq];
    #pragma unroll
    for (int j = 0; j < 4; ++j) add4(ns[j], p[j]);
  }
  const float4* brow = (const float4*)&Bw[((long long)b * DD + d) * RR];
  float4 dn[4];
  #pragma unroll
  for (int j = 0; j < 4; ++j) dn[j] = make_float4(0.f, 0.f, 0.f, 0.f);
  for (int q = 0; q < 16; ++q) {
    const float4 b4 = brow[q];
    const float4* c0 = (const float4*)&ct[(4 * q + 0) * 64 + rq];
    const float4* c1 = (const float4*)&ct[(4 * q + 1) * 64 + rq];
    const float4* c2 = (const float4*)&ct[(4 * q + 2) * 64 + rq];
    const float4* c3 = (const float4*)&ct[(4 * q + 3) * 64 + rq];
    #pragma unroll
    for (int j = 0; j < 4; ++j) {
      fma4s(dn[j], c0[j], b4.x); fma4s(dn[j], c1[j], b4.y);
      fma4s(dn[j], c2[j], b4.z); fma4s(dn[j], c3[j], b4.w);
    }
  }
  float4* bp = (float4*)&Bw[((long long)b * DD + d) * RR + rq];
  float4 bo[4];
  #pragma unroll
  for (int j = 0; j < 4; ++j) bo[j] = bp[j];
  __syncthreads();
  #pragma unroll
  for (int j = 0; j < 4; ++j) {
    float4 o;
    o.x = bo[j].x * ns[j].x / (dn[j].x + EPS);
    o.y = bo[j].y * ns[j].y / (dn[j].y + EPS);
    o.z = bo[j].z * ns[j].z / (dn[j].z + EPS);
    o.w = bo[j].w * ns[j].w / (dn[j].w + EPS);
    bp[j] = o;
  }
}

// ================= fp32 fallback kernels (round-6 path) =================

template <int MODE>
__global__ void __launch_bounds__(128) fused_coef_kernel(const float* __restrict__ X,
                                                         const float* __restrict__ Bw,
                                                         const float* __restrict__ btbp,
                                                         float* __restrict__ coef) {
  __shared__ float lds[8192];
  const int b    = blockIdx.y;
  const int n0   = blockIdx.x << 6;
  const int t    = threadIdx.x;
  const int wid  = t >> 6;
  const int lane = t & 63;
  const int rgrp = t & 7;
  const int ngrp = t >> 3;
  const int nl   = ngrp << 2;
  const int r0   = rgrp << 3;
  const float* Xp = X  + (long long)b * DD * NN + n0;
  const float* Bp = Bw + (long long)b * DD * RR;

  float4 acc[4][2];
  #pragma unroll
  for (int i = 0; i < 4; ++i) { acc[i][0] = make_float4(0,0,0,0); acc[i][1] = make_float4(0,0,0,0); }

  auto stage = [&](int buf, int d0) {
    float* xd = lds + (buf << 11);
    float* bd = lds + 4096 + (buf << 11);
    const int rsub = lane >> 4;
    const int c4   = (lane & 15) << 2;
    #pragma unroll
    for (int j = 0; j < 4; ++j) {
      const int q   = (wid << 2) + j;
      const int row = (q << 2) + rsub;
      gload16(&Xp[(long long)(d0 + row) * NN + c4], xd + (q << 8));
      gload16(&Bp[(long long)(d0 + row) * RR + c4], bd + (q << 8));
    }
  };

  stage(0, 0);
  __syncthreads();
  for (int kt = 0; kt < 16; ++kt) {
    const int cur = kt & 1;
    if (kt + 1 < 16) stage(cur ^ 1, (kt + 1) << 5);
    const float* xs = lds + (cur << 11);
    const float* bs = lds + 4096 + (cur << 11);
    #pragma unroll 8
    for (int dd = 0; dd < 32; ++dd) {
      const float4 xv  = *(const float4*)&xs[(dd << 6) + nl];
      const float4 bv0 = *(const float4*)&bs[(dd << 6) + r0];
      const float4 bv1 = *(const float4*)&bs[(dd << 6) + r0 + 4];
      fma4s(acc[0][0], bv0, xv.x); fma4s(acc[0][1], bv1, xv.x);
      fma4s(acc[1][0], bv0, xv.y); fma4s(acc[1][1], bv1, xv.y);
      fma4s(acc[2][0], bv0, xv.z); fma4s(acc[2][1], bv1, xv.z);
      fma4s(acc[3][0], bv0, xv.w); fma4s(acc[3][1], bv1, xv.w);
    }
    __syncthreads();
  }

  if constexpr (MODE == 0) {
    #pragma unroll
    for (int i = 0; i < 4; ++i) {
      float4 a0 = acc[i][0], a1 = acc[i][1];
      float m = fmaxf(fmaxf(fmaxf(a0.x, a0.y), fmaxf(a0.z, a0.w)),
                      fmaxf(fmaxf(a1.x, a1.y), fmaxf(a1.z, a1.w)));
      m = fmaxf(m, __shfl_xor(m, 1));
      m = fmaxf(m, __shfl_xor(m, 2));
      m = fmaxf(m, __shfl_xor(m, 4));
      a0.x = __expf(a0.x - m); a0.y = __expf(a0.y - m);
      a0.z = __expf(a0.z - m); a0.w = __expf(a0.w - m);
      a1.x = __expf(a1.x - m); a1.y = __expf(a1.y - m);
      a1.z = __expf(a1.z - m); a1.w = __expf(a1.w - m);
      float s = a0.x + a0.y + a0.z + a0.w + a1.x + a1.y + a1.z + a1.w;
      s += __shfl_xor(s, 1); s += __shfl_xor(s, 2); s += __shfl_xor(s, 4);
      const float inv = 1.f / s;
      a0.x *= inv; a0.y *= inv; a0.z *= inv; a0.w *= inv;
      a1.x *= inv; a1.y *= inv; a1.z *= inv; a1.w *= inv;
      float* cp = coef + ((long long)b * NN + n0 + nl + i) * RR + r0;
      *(float4*)&cp[0] = a0;
      *(float4*)&cp[4] = a1;
    }
  } else {
    float4* G4  = (float4*)lds;
    float4* CO4 = (float4*)(lds + 4096);
    #pragma unroll
    for (int j = 0; j < 8; ++j) {
      const int wi = t + (j << 7);
      float4 ssum = make_float4(0,0,0,0);
      #pragma unroll
      for (int sp = 0; sp < NS_B; ++sp)
        add4(ssum, ((const float4*)(btbp + ((long long)sp * BSZ + b) * 4096))[wi]);
      G4[wi] = ssum;
    }
    const float4* cof4 = (const float4*)(coef + ((long long)b * NN + n0) * RR);
    #pragma unroll
    for (int j = 0; j < 8; ++j) {
      const int wi = t + (j << 7);
      const int row = wi >> 4, c4 = wi & 15;
      CO4[(row << 4) + (c4 ^ ((row >> 2) & 7))] = cof4[wi];
    }
    __syncthreads();
    const int g = ngrp & 7;
    float4 dn[4][2];
    #pragma unroll
    for (int i = 0; i < 4; ++i) { dn[i][0] = make_float4(0,0,0,0); dn[i][1] = make_float4(0,0,0,0); }
    #pragma unroll 4
    for (int kq = 0; kq < 16; ++kq) {
      float4 g0[4], g1[4];
      #pragma unroll
      for (int jj = 0; jj < 4; ++jj) {
        g0[jj] = G4[(((kq << 2) + jj) << 4) + (rgrp << 1)];
        g1[jj] = G4[(((kq << 2) + jj) << 4) + (rgrp << 1) + 1];
      }
      #pragma unroll
      for (int i = 0; i < 4; ++i) {
        const float4 cv = CO4[((nl + i) << 4) + (kq ^ g)];
        fma4s(dn[i][0], g0[0], cv.x); fma4s(dn[i][1], g1[0], cv.x);
        fma4s(dn[i][0], g0[1], cv.y); fma4s(dn[i][1], g1[1], cv.y);
        fma4s(dn[i][0], g0[2], cv.z); fma4s(dn[i][1], g1[2], cv.z);
        fma4s(dn[i][0], g0[3], cv.w); fma4s(dn[i][1], g1[3], cv.w);
      }
    }
    #pragma unroll
    for (int i = 0; i < 4; ++i) {
      const int row = nl + i;
      const float4 c0 = CO4[(row << 4) + ((rgrp << 1) ^ g)];
      const float4 c1 = CO4[(row << 4) + (((rgrp << 1) + 1) ^ g)];
      float4 o0, o1;
      o0.x = c0.x * acc[i][0].x / (dn[i][0].x + EPS);
      o0.y = c0.y * acc[i][0].y / (dn[i][0].y + EPS);
      o0.z = c0.z * acc[i][0].z / (dn[i][0].z + EPS);
      o0.w = c0.w * acc[i][0].w / (dn[i][0].w + EPS);
      o1.x = c1.x * acc[i][1].x / (dn[i][1].x + EPS);
      o1.y = c1.y * acc[i][1].y / (dn[i][1].y + EPS);
      o1.z = c1.z * acc[i][1].z / (dn[i][1].z + EPS);
      o1.w = c1.w * acc[i][1].w / (dn[i][1].w + EPS);
      float* cp = coef + ((long long)b * NN + n0 + row) * RR + r0;
      *(float4*)&cp[0] = o0;
      *(float4*)&cp[4] = o1;
    }
  }
}

__global__ void __launch_bounds__(128) numer2_kernel(const float* __restrict__ X,
                                                     const float* __restrict__ coef,
                                                     float* __restrict__ n2p) {
  __shared__ float lds[8192];
  const int b    = blockIdx.z;
  const int s    = blockIdx.y;
  const int d0   = blockIdx.x << 6;
  const int t    = threadIdx.x;
  const int wid  = t >> 6;
  const int lane = t & 63;
  const int rgrp = t & 7;
  const int dgrp = t >> 3;
  const int dl   = dgrp << 2;
  const int r0   = rgrp << 3;
  const int nbeg = s * (NN / NS_N2);
  const float* Xp = X + (long long)b * DD * NN + (long long)d0 * NN;
  const float* Cp = coef + (long long)b * NN * RR;

  float4 acc[4][2];
  #pragma unroll
  for (int i = 0; i < 4; ++i) { acc[i][0] = make_float4(0,0,0,0); acc[i][1] = make_float4(0,0,0,0); }

  auto stage = [&](int buf, int nb) {
    float* xd = lds + (buf << 11);
    float* cd = lds + 4096 + (buf << 11);
    {
      const int rsub = lane >> 3, c4 = lane & 7;
      #pragma unroll
      for (int j = 0; j < 4; ++j) {
        const int q   = (wid << 2) + j;
        const int row = (q << 3) + rsub;
        const int sc  = (c4 ^ ((row >> 2) & 7)) << 2;
        gload16(&Xp[(long long)row * NN + nb + sc], xd + (q << 8));
      }
    }
    {
      const int rsub = lane >> 4, c4 = (lane & 15) << 2;
      #pragma unroll
      for (int j = 0; j < 4; ++j) {
        const int q   = (wid << 2) + j;
        const int row = (q << 2) + rsub;
        gload16(&Cp[(long long)(nb + row) * RR + c4], cd + (q << 8));
      }
    }
  };

  stage(0, nbeg);
  __syncthreads();
  const int g = dgrp & 7;
  for (int kt = 0; kt < (NN / NS_N2) / 32; ++kt) {
    const int cur = kt & 1;
    if (kt + 1 < (NN / NS_N2) / 32) stage(cur ^ 1, nbeg + ((kt + 1) << 5));
    const float* xs = lds + (cur << 11);
    const float* cs = lds + 4096 + (cur << 11);
    #pragma unroll 8
    for (int nn = 0; nn < 32; ++nn) {
      const int col = ((((nn >> 2) ^ g) << 2) + (nn & 3));
      float xe[4];
      #pragma unroll
      for (int i = 0; i < 4; ++i) xe[i] = xs[((dl + i) << 5) + col];
      const float4 cv0 = *(const float4*)&cs[(nn << 6) + r0];
      const float4 cv1 = *(const float4*)&cs[(nn << 6) + r0 + 4];
      #pragma unroll
      for (int i = 0; i < 4; ++i) {
        fma4s(acc[i][0], cv0, xe[i]);
        fma4s(acc[i][1], cv1, xe[i]);
      }
    }
    __syncthreads();
  }
  #pragma unroll
  for (int i = 0; i < 4; ++i) {
    float* op = n2p + (((long long)s * BSZ + b) * DD + d0 + dl + i) * RR + r0;
    *(float4*)&op[0] = acc[i][0];
    *(float4*)&op[4] = acc[i][1];
  }
}

__global__ void __launch_bounds__(256) bupdate_fb_kernel(float* __restrict__ Bw,
                                                         const float* __restrict__ n2p,
                                                         const float* __restrict__ ctcp,
                                                         int ns2) {
  __shared__ float ct[4096];
  const int b  = blockIdx.y;
  const int d0 = blockIdx.x << 6;
  #pragma unroll
  for (int i = 0; i < 4; ++i) {
    const int w = threadIdx.x + (i << 8);
    float4 s = make_float4(0.f, 0.f, 0.f, 0.f);
    for (int sp = 0; sp < NS_C; ++sp)
      add4(s, ((const float4*)(ctcp + ((long long)sp * BSZ + b) * 4096))[w]);
    ((float4*)ct)[w] = s;
  }
  __syncthreads();
  const int d  = d0 + (threadIdx.x >> 2);
  const int rq = (threadIdx.x & 3) << 4;

  float4 ns[4];
  #pragma unroll
  for (int j = 0; j < 4; ++j) ns[j] = make_float4(0.f, 0.f, 0.f, 0.f);
  for (int s = 0; s < ns2; ++s) {
    const float4* p = (const float4*)&n2p[(((long long)s * BSZ + b) * DD + d) * RR + rq];
    #pragma unroll
    for (int j = 0; j < 4; ++j) add4(ns[j], p[j]);
  }
  const float4* brow = (const float4*)&Bw[((long long)b * DD + d) * RR];
  float4 dn[4];
  #pragma unroll
  for (int j = 0; j < 4; ++j) dn[j] = make_float4(0.f, 0.f, 0.f, 0.f);
  for (int q = 0; q < 16; ++q) {
    const float4 b4 = brow[q];
    const float4* c0 = (const float4*)&ct[(4 * q + 0) * 64 + rq];
    const float4* c1 = (const float4*)&ct[(4 * q + 1) * 64 + rq];
    const float4* c2 = (const float4*)&ct[(4 * q + 2) * 64 + rq];
    const float4* c3 = (const float4*)&ct[(4 * q + 3) * 64 + rq];
    #pragma unroll
    for (int j = 0; j < 4; ++j) {
      fma4s(dn[j], c0[j], b4.x); fma4s(dn[j], c1[j], b4.y);
      fma4s(dn[j], c2[j], b4.z); fma4s(dn[j], c3[j], b4.w);
    }
  }
  float4* bp = (float4*)&Bw[((long long)b * DD + d) * RR + rq];
  float4 bo[4];
  #pragma unroll
  for (int j = 0; j < 4; ++j) bo[j] = bp[j];
  __syncthreads();
  #pragma unroll
  for (int j = 0; j < 4; ++j) {
    float4 o;
    o.x = bo[j].x * ns[j].x / (dn[j].x + EPS);
    o.y = bo[j].y * ns[j].y / (dn[j].y + EPS);
    o.z = bo[j].z * ns[j].z / (dn[j].z + EPS);
    o.w = bo[j].w * ns[j].w / (dn[j].w + EPS);
    bp[j] = o;
  }
}

__global__ void __launch_bounds__(256) out_kernel(const float* __restrict__ Bw,
                                                  const float* __restrict__ coef,
                                                  float* __restrict__ out) {
  __shared__ float bt [64 * 68];
  __shared__ float ctl[64 * 68];
  const int n0 = blockIdx.x << 6;
  const int d0 = blockIdx.y << 6;
  const int b  = blockIdx.z;
  const int tx = threadIdx.x & 15;
  const int ty = threadIdx.x >> 4;
  for (int t = threadIdx.x; t < 1024; t += 256) {
    const int row = t >> 4, c4 = (t & 15) << 2;
    const float4 v = *(const float4*)&Bw[((long long)b * DD + d0 + row) * RR + c4];
    bt[(c4 + 0) * 68 + row] = v.x; bt[(c4 + 1) * 68 + row] = v.y;
    bt[(c4 + 2) * 68 + row] = v.z; bt[(c4 + 3) * 68 + row] = v.w;
  }
  for (int t = threadIdx.x; t < 1024; t += 256) {
    const int row = t >> 4, c4 = (t & 15) << 2;
    const float4 v = *(const float4*)&coef[((long long)b * NN + n0 + row) * RR + c4];
    ctl[(c4 + 0) * 68 + row] = v.x; ctl[(c4 + 1) * 68 + row] = v.y;
    ctl[(c4 + 2) * 68 + row] = v.z; ctl[(c4 + 3) * 68 + row] = v.w;
  }
  __syncthreads();
  float4 ai[4];
  #pragma unroll
  for (int i = 0; i < 4; ++i) ai[i] = make_float4(0.f, 0.f, 0.f, 0.f);
  #pragma unroll 8
  for (int r = 0; r < 64; ++r) {
    const float4 bv = *(const float4*)&bt [r * 68 + (ty << 2)];
    const float4 cv = *(const float4*)&ctl[r * 68 + (tx << 2)];
    fma4s(ai[0], cv, bv.x); fma4s(ai[1], cv, bv.y);
    fma4s(ai[2], cv, bv.z); fma4s(ai[3], cv, bv.w);
  }
  #pragma unroll
  for (int i = 0; i < 4; ++i)
    *(float4*)&out[((long long)b * DD + d0 + (ty << 2) + i) * NN + n0 + (tx << 2)] = ai[i];
}

extern "C" void kernel_launch(void* const* d_in, const int* in_sizes, int n_in,
                              void* d_out, int out_size, void* d_ws, size_t ws_size,
                              hipStream_t stream) {
  const float* x        = (const float*)d_in[0];
  const float* bases_in = (const float*)d_in[1];
  float* out = (float*)d_out;
  float* ws  = (float*)d_ws;

  float* coef    = ws;                                   // 4M f32
  float* bases_w = coef + (long long)BSZ * NN * RR;      // 0.5M
  float* btbp    = bases_w + (long long)BSZ * DD * RR;   // 0.5M
  float* ctcp    = btbp + (long long)NS_B * BSZ * 4096;  // 2M
  float* n2p     = ctcp + (long long)NS_C * BSZ * 4096;  // 4M
  float* ctcs    = n2p + (long long)NS_N2 * BSZ * DD * RR;   // 64K
  half_t* xT16   = (half_t*)(ctcs + (long long)BSZ * 4096);  // 33.5M halfs
  half_t* xd16   = xT16 + (long long)BSZ * NN * DD;          // 33.5M halfs
  half_t* BbT16  = xd16 + (long long)BSZ * NN * DD;          // 0.5M halfs
  half_t* cbT16  = BbT16 + (long long)BSZ * RR * DD;         // 4M halfs
  half_t* Gh16   = cbT16 + (long long)BSZ * RR * NN;         // 64K halfs
  const long long need = (long long)((char*)(Gh16 + (long long)BSZ * 4096) - (char*)d_ws);

  // post-loop aliases (n2p dead after last bupdate)
  half_t* cN16 = (half_t*)n2p;                       // 8 MB
  half_t* bD16 = cN16 + (long long)BSZ * NN * RR;    // 1 MB

  const dim3 blk256(256);
  const dim3 blk128(128);

  hipMemcpyAsync(bases_w, bases_in, sizeof(float) * BSZ * DD * RR,
                 hipMemcpyDeviceToDevice, stream);

  if ((long long)ws_size >= need) {
    // ---------- fp16-MFMA path (all operands L3-resident) ----------
    cast16_kernel<<<dim3(16384), blk256, 0, stream>>>(x, xd16, (long long)BSZ * DD * NN);
    tcvt16_kernel<<<dim3(NN / 64, DD / 64, BSZ), blk256, 0, stream>>>(x, xT16, DD, NN);
    tcvt16_kernel<<<dim3(1, DD / 64, BSZ), blk256, 0, stream>>>(bases_w, BbT16, DD, RR);
    fused16_kernel<0><<<dim3(NN / 32, BSZ), blk128, 0, stream>>>(
        xT16, BbT16, nullptr, coef, nullptr, nullptr);

    for (int it = 0; it < STEPS; ++it) {
      tcvt16_kernel<<<dim3(1, DD / 64, BSZ), blk256, 0, stream>>>(bases_w, BbT16, DD, RR);
      gram_kernel<<<dim3(NS_B, BSZ), blk256, 0, stream>>>(bases_w, btbp, DD / (NS_B * 4),
                                                          (long long)DD * RR);
      gsum16_kernel<<<dim3(BSZ), blk256, 0, stream>>>(btbp, Gh16);
      fused16_kernel<1><<<dim3(NN / 32, BSZ), blk128, 0, stream>>>(
          xT16, BbT16, Gh16, coef, cbT16, nullptr);
      ctc16_kernel<<<dim3(8, BSZ), blk256, 0, stream>>>(cbT16, ctcp);
      csum_kernel<<<dim3(BSZ), blk256, 0, stream>>>(ctcp, ctcs, NS_C);
      numer2_16_kernel<<<dim3(DD / 64, NS_N2, BSZ), blk128, 0, stream>>>(xd16, cbT16, n2p);
      bupdate_kernel<<<dim3(DD / 64, BSZ), blk256, 0, stream>>>(bases_w, n2p, ctcs, NS_N2);
    }
    // compute_coef: final update emits fp16 coef [n][r] directly
    tcvt16_kernel<<<dim3(1, DD / 64, BSZ), blk256, 0, stream>>>(bases_w, BbT16, DD, RR);
    gram_kernel<<<dim3(NS_B, BSZ), blk256, 0, stream>>>(bases_w, btbp, DD / (NS_B * 4),
                                                        (long long)DD * RR);
    gsum16_kernel<<<dim3(BSZ), blk256, 0, stream>>>(btbp, Gh16);
    fused16_kernel<2><<<dim3(NN / 32, BSZ), blk128, 0, stream>>>(
        xT16, BbT16, Gh16, coef, nullptr, cN16);
    cast16_kernel<<<dim3(256), blk256, 0, stream>>>(bases_w, bD16, (long long)BSZ * DD * RR);
    out16_kernel<<<dim3(NN / 64, DD / 64, BSZ), blk256, 0, stream>>>(bD16, cN16, out);
  } else {
    // ---------- fp32 fallback (round-6 path) ----------
    fused_coef_kernel<0><<<dim3(NN / 64, BSZ), blk128, 0, stream>>>(x, bases_w, nullptr, coef);
    for (int it = 0; it < STEPS; ++it) {
      gram_kernel<<<dim3(NS_B, BSZ), blk256, 0, stream>>>(bases_w, btbp, DD / (NS_B * 4),
                                                          (long long)DD * RR);
      fused_coef_kernel<1><<<dim3(NN / 64, BSZ), blk128, 0, stream>>>(x, bases_w, btbp, coef);
      gram_kernel<<<dim3(NS_C, BSZ), blk256, 0, stream>>>(coef, ctcp, NN / (NS_C * 4),
                                                          (long long)NN * RR);
      numer2_kernel<<<dim3(DD / 64, NS_N2, BSZ), blk128, 0, stream>>>(x, coef, n2p);
      bupdate_fb_kernel<<<dim3(DD / 64, BSZ), blk256, 0, stream>>>(bases_w, n2p, ctcp, NS_N2);
    }
    gram_kernel<<<dim3(NS_B, BSZ), blk256, 0, stream>>>(bases_w, btbp, DD / (NS_B * 4),
                                                        (long long)DD * RR);
    fused_coef_kernel<1><<<dim3(NN / 64, BSZ), blk128, 0, stream>>>(x, bases_w, btbp, coef);
    out_kernel<<<dim3(NN / 64, DD / 64, BSZ), blk256, 0, stream>>>(bases_w, coef, out);
  }
}

// Round 11
// 997.150 us; speedup vs baseline: 1.8686x; 1.2687x over previous
//
#include <hip/hip_runtime.h>
#include <math.h>

#define EPS 1e-6f

constexpr int BSZ = 16;    // batch * S
constexpr int DD  = 512;   // channels / S
constexpr int NN  = 4096;  // H*W
constexpr int RR  = 64;
constexpr int STEPS = 7;
constexpr int NS_B  = 8;   // (fallback) BtB d-split blocks
constexpr int NS_C  = 32;  // CtC partial slots (8 blocks x 4 waves)
constexpr int NS_N2 = 8;   // numer2 n-split partials

typedef _Float16 half_t;
typedef __attribute__((ext_vector_type(8))) _Float16 half8;
typedef __attribute__((ext_vector_type(4))) float f32x4;

__device__ __forceinline__ void fma4s(float4& a, const float4& b, float s) {
  a.x = fmaf(b.x, s, a.x); a.y = fmaf(b.y, s, a.y);
  a.z = fmaf(b.z, s, a.z); a.w = fmaf(b.w, s, a.w);
}
__device__ __forceinline__ void add4(float4& a, const float4& b) {
  a.x += b.x; a.y += b.y; a.z += b.z; a.w += b.w;
}
__device__ __forceinline__ f32x4 mfmah(half8 a, half8 b, f32x4 c) {
  return __builtin_amdgcn_mfma_f32_16x16x32_f16(a, b, c, 0, 0, 0);
}

// async global->LDS, 16B per lane (fp32 fallback path)
__device__ __forceinline__ void gload16(const float* g, float* l) {
  __builtin_amdgcn_global_load_lds(
      (const __attribute__((address_space(1))) void*)g,
      (__attribute__((address_space(3))) void*)l, 16, 0, 0);
}

// ================= transpose + fp32->fp16: src [b][R][C] -> dst [b][C][R]
__global__ void __launch_bounds__(256) tcvt16_kernel(const float* __restrict__ src,
                                                     half_t* __restrict__ dh,
                                                     int R, int C) {
  __shared__ float tileT[64 * 65];   // [src_col][src_row]
  const int b = blockIdx.z, c0 = blockIdx.x << 6, r0 = blockIdx.y << 6;
  const float* sp = src + (long long)b * R * C;
  const int t = threadIdx.x;
  #pragma unroll
  for (int i = 0; i < 4; ++i) {
    const int idx = t + (i << 8);
    const int row = idx >> 4, c4 = (idx & 15) << 2;
    const float4 v = *(const float4*)&sp[(long long)(r0 + row) * C + c0 + c4];
    tileT[(c4 + 0) * 65 + row] = v.x;
    tileT[(c4 + 1) * 65 + row] = v.y;
    tileT[(c4 + 2) * 65 + row] = v.z;
    tileT[(c4 + 3) * 65 + row] = v.w;
  }
  __syncthreads();
  const int orow = t >> 2, och = (t & 3) << 4;
  half8 h0, h1;
  #pragma unroll
  for (int j = 0; j < 8; ++j) h0[j] = (half_t)tileT[orow * 65 + och + j];
  #pragma unroll
  for (int j = 0; j < 8; ++j) h1[j] = (half_t)tileT[orow * 65 + och + 8 + j];
  const long long ob = ((long long)b * C + c0 + orow) * R + r0 + och;
  *(half8*)&dh[ob] = h0;
  *(half8*)&dh[ob + 8] = h1;
}

// ================= flat fp32 -> fp16 cast
__global__ void __launch_bounds__(256) cast16_kernel(const float* __restrict__ src,
                                                     half_t* __restrict__ dst,
                                                     long long n) {
  const long long i = ((long long)blockIdx.x * 256 + threadIdx.x) * 8;
  if (i >= n) return;
  const float4 a = *(const float4*)&src[i];
  const float4 c = *(const float4*)&src[i + 4];
  half8 h;
  h[0] = (half_t)a.x; h[1] = (half_t)a.y; h[2] = (half_t)a.z; h[3] = (half_t)a.w;
  h[4] = (half_t)c.x; h[5] = (half_t)c.y; h[6] = (half_t)c.z; h[7] = (half_t)c.w;
  *(half8*)&dst[i] = h;
}

// ================= G = B~^T B~ via fp16 MFMA, one block per batch.
// Wave w covers k-slice w*128..+128 of DD; partials LDS-reduced; Gh fp16 out.
__global__ void __launch_bounds__(256) btb16_kernel(const half_t* __restrict__ BT,
                                                    half_t* __restrict__ Gh) {
  __shared__ float red[64 * 64];
  const int b = blockIdx.x;
  const int t = threadIdx.x;
  const int w = t >> 6;
  const int l = t & 63;
  const int row16 = l & 15;
  const int koff  = (l >> 4) << 3;

  const half_t* ap = BT + ((long long)b * RR + row16) * DD + (w << 7) + koff;

  f32x4 acc[4][4];
  #pragma unroll
  for (int i = 0; i < 4; ++i)
    #pragma unroll
    for (int j = 0; j < 4; ++j) acc[i][j] = (f32x4){0.f, 0.f, 0.f, 0.f};

  #pragma unroll
  for (int kt = 0; kt < 4; ++kt) {
    const int ko = kt << 5;
    half8 af[4];
    #pragma unroll
    for (int rs = 0; rs < 4; ++rs) af[rs] = *(const half8*)&ap[(long long)rs * 16 * DD + ko];
    #pragma unroll
    for (int r1 = 0; r1 < 4; ++r1)
      #pragma unroll
      for (int r2 = 0; r2 < 4; ++r2)
        acc[r1][r2] = mfmah(af[r1], af[r2], acc[r1][r2]);
  }
  for (int ww = 0; ww < 4; ++ww) {
    if (w == ww) {
      #pragma unroll
      for (int r1 = 0; r1 < 4; ++r1)
        #pragma unroll
        for (int r2 = 0; r2 < 4; ++r2)
          #pragma unroll
          for (int j = 0; j < 4; ++j) {
            const int row = (r1 << 4) + ((l >> 4) << 2) + j;
            const int col = (r2 << 4) + row16;
            if (ww == 0) red[row * 64 + col] = acc[r1][r2][j];
            else         red[row * 64 + col] += acc[r1][r2][j];
          }
    }
    __syncthreads();
  }
  for (int i = t; i < 512; i += 256) {
    half8 h;
    #pragma unroll
    for (int j = 0; j < 8; ++j) h[j] = (half_t)red[(i << 3) + j];
    *(half8*)&Gh[(long long)b * 4096 + (i << 3)] = h;
  }
}

// ================= fp16-MFMA fused numer + {softmax | coef update}
// MODE0: coef = softmax(numer).  MODE1: coef *= numer/(cold@G+eps); emits cbT
// via LDS transpose (coalesced).  MODE2 (final): emits cN fp16 [n][r] only.
template <int MODE>
__global__ void __launch_bounds__(128) fused16_kernel(const half_t* __restrict__ xT,
                                                      const half_t* __restrict__ BT,
                                                      const half_t* __restrict__ Gh,
                                                      float* __restrict__ coef,
                                                      half_t* __restrict__ cbT,
                                                      half_t* __restrict__ cN) {
  __shared__ half_t ctile[(MODE == 1) ? 64 * 40 : 8];
  const int b  = blockIdx.y;
  const int n0 = blockIdx.x << 5;
  const int t  = threadIdx.x;
  const int w  = t >> 6;
  const int l  = t & 63;
  const int row16 = l & 15;
  const int koff  = (l >> 4) << 3;
  const int nrb   = n0 + (w << 4);

  const half_t* ap = xT + ((long long)b * NN + nrb + row16) * DD + koff;
  const half_t* bp = BT + ((long long)b * RR + row16) * DD + koff;

  f32x4 acc[4];
  #pragma unroll
  for (int rs = 0; rs < 4; ++rs) acc[rs] = (f32x4){0.f, 0.f, 0.f, 0.f};

  #pragma unroll
  for (int kt = 0; kt < 16; ++kt) {
    const int ko = kt << 5;
    const half8 av = *(const half8*)&ap[ko];
    #pragma unroll
    for (int rs = 0; rs < 4; ++rs) {
      const half8 bv = *(const half8*)&bp[rs * 16 * DD + ko];
      acc[rs] = mfmah(av, bv, acc[rs]);
    }
  }

  if constexpr (MODE == 0) {
    #pragma unroll
    for (int j = 0; j < 4; ++j) {
      float m = fmaxf(fmaxf(acc[0][j], acc[1][j]), fmaxf(acc[2][j], acc[3][j]));
      m = fmaxf(m, __shfl_xor(m, 1));
      m = fmaxf(m, __shfl_xor(m, 2));
      m = fmaxf(m, __shfl_xor(m, 4));
      m = fmaxf(m, __shfl_xor(m, 8));
      float s = 0.f;
      #pragma unroll
      for (int rs = 0; rs < 4; ++rs) { acc[rs][j] = __expf(acc[rs][j] - m); s += acc[rs][j]; }
      s += __shfl_xor(s, 1); s += __shfl_xor(s, 2);
      s += __shfl_xor(s, 4); s += __shfl_xor(s, 8);
      const float inv = 1.f / s;
      #pragma unroll
      for (int rs = 0; rs < 4; ++rs) acc[rs][j] *= inv;
    }
    #pragma unroll
    for (int rs = 0; rs < 4; ++rs)
      #pragma unroll
      for (int j = 0; j < 4; ++j)
        coef[((long long)b * NN + nrb + ((l >> 4) << 2) + j) * RR + (rs << 4) + row16] = acc[rs][j];
  } else {
    // denom = cold @ G via fp16 MFMA (G symmetric -> rows are k-contiguous)
    const float* crow = coef + ((long long)b * NN + nrb + row16) * RR;
    const half_t* ghb = Gh + (long long)b * 4096;
    f32x4 dn[4];
    #pragma unroll
    for (int rs = 0; rs < 4; ++rs) dn[rs] = (f32x4){0.f, 0.f, 0.f, 0.f};
    #pragma unroll
    for (int kt = 0; kt < 2; ++kt) {
      const int ko = (kt << 5) + koff;
      const float4 c0 = *(const float4*)&crow[ko];
      const float4 c1 = *(const float4*)&crow[ko + 4];
      half8 ch;
      ch[0] = (half_t)c0.x; ch[1] = (half_t)c0.y; ch[2] = (half_t)c0.z; ch[3] = (half_t)c0.w;
      ch[4] = (half_t)c1.x; ch[5] = (half_t)c1.y; ch[6] = (half_t)c1.z; ch[7] = (half_t)c1.w;
      #pragma unroll
      for (int rs = 0; rs < 4; ++rs) {
        const half8 gh = *(const half8*)&ghb[((rs << 4) + row16) * 64 + ko];
        dn[rs] = mfmah(ch, gh, dn[rs]);
      }
    }
    // multiplicative update (element-owner unique in D-frag positions)
    #pragma unroll
    for (int rs = 0; rs < 4; ++rs)
      #pragma unroll
      for (int j = 0; j < 4; ++j) {
        const int r = (rs << 4) + row16;
        const int nl = ((w << 4) + ((l >> 4) << 2) + j);   // n - n0
        const long long idx = ((long long)b * NN + n0 + nl) * RR + r;
        const float co = coef[idx];
        const float v  = co * acc[rs][j] / (dn[rs][j] + EPS);
        if constexpr (MODE == 1) {
          coef[idx] = v;
          ctile[r * 40 + nl] = (half_t)v;
        } else {
          cN[idx] = (half_t)v;
        }
      }
    if constexpr (MODE == 1) {
      __syncthreads();
      if (t < 64) {   // row r = t: write 32 contiguous fp16 (64 B) to cbT
        half_t* dst = cbT + ((long long)b * RR + t) * NN + n0;
        *(half8*)&dst[0]  = *(const half8*)&ctile[t * 40 + 0];
        *(half8*)&dst[8]  = *(const half8*)&ctile[t * 40 + 8];
        *(half8*)&dst[16] = *(const half8*)&ctile[t * 40 + 16];
        *(half8*)&dst[24] = *(const half8*)&ctile[t * 40 + 24];
      }
    }
  }
}

// ================= CtC partials via fp16 MFMA: ctcp[sp2][b][r1][r2]
__global__ void __launch_bounds__(256) ctc16_kernel(const half_t* __restrict__ cbT,
                                                    float* __restrict__ ctcp) {
  const int b  = blockIdx.y;
  const int t  = threadIdx.x;
  const int w  = t >> 6;
  const int l  = t & 63;
  const int row16 = l & 15;
  const int koff  = (l >> 4) << 3;
  const int sp2   = blockIdx.x * 4 + w;
  const int nbeg  = sp2 * 128;

  const half_t* ap = cbT + ((long long)b * RR + row16) * NN + nbeg + koff;

  f32x4 acc[4][4];
  #pragma unroll
  for (int i = 0; i < 4; ++i)
    #pragma unroll
    for (int j = 0; j < 4; ++j) acc[i][j] = (f32x4){0.f, 0.f, 0.f, 0.f};

  #pragma unroll
  for (int kt = 0; kt < 4; ++kt) {
    const int ko = kt << 5;
    half8 af[4];
    #pragma unroll
    for (int rs = 0; rs < 4; ++rs) af[rs] = *(const half8*)&ap[(long long)rs * 16 * NN + ko];
    #pragma unroll
    for (int r1 = 0; r1 < 4; ++r1)
      #pragma unroll
      for (int r2 = 0; r2 < 4; ++r2)
        acc[r1][r2] = mfmah(af[r1], af[r2], acc[r1][r2]);
  }
  float* op = ctcp + ((long long)sp2 * BSZ + b) * 4096;
  #pragma unroll
  for (int r1 = 0; r1 < 4; ++r1)
    #pragma unroll
    for (int r2 = 0; r2 < 4; ++r2)
      #pragma unroll
      for (int j = 0; j < 4; ++j)
        op[((r1 << 4) + ((l >> 4) << 2) + j) * 64 + (r2 << 4) + row16] = acc[r1][r2][j];
}

// ================= numer2 partials via fp16 MFMA
__global__ void __launch_bounds__(128) numer2_16_kernel(const half_t* __restrict__ xh,
                                                        const half_t* __restrict__ cbT,
                                                        float* __restrict__ n2p) {
  const int b  = blockIdx.z;
  const int s  = blockIdx.y;
  const int d0 = blockIdx.x << 6;
  const int t  = threadIdx.x;
  const int w  = t >> 6;
  const int l  = t & 63;
  const int row16 = l & 15;
  const int koff  = (l >> 4) << 3;
  const int nbeg  = s * (NN / NS_N2);

  const half_t* ap = xh + ((long long)b * DD + d0 + w * 32 + row16) * NN + nbeg + koff;
  const half_t* cp = cbT + ((long long)b * RR + row16) * NN + nbeg + koff;

  f32x4 acc[2][4];
  #pragma unroll
  for (int ds = 0; ds < 2; ++ds)
    #pragma unroll
    for (int rs = 0; rs < 4; ++rs) acc[ds][rs] = (f32x4){0.f, 0.f, 0.f, 0.f};

  #pragma unroll
  for (int kt = 0; kt < 16; ++kt) {
    const int ko = kt << 5;
    half8 av[2], bf[4];
    #pragma unroll
    for (int ds = 0; ds < 2; ++ds) av[ds] = *(const half8*)&ap[(long long)ds * 16 * NN + ko];
    #pragma unroll
    for (int rs = 0; rs < 4; ++rs) bf[rs] = *(const half8*)&cp[(long long)rs * 16 * NN + ko];
    #pragma unroll
    for (int ds = 0; ds < 2; ++ds)
      #pragma unroll
      for (int rs = 0; rs < 4; ++rs)
        acc[ds][rs] = mfmah(av[ds], bf[rs], acc[ds][rs]);
  }
  float* op = n2p + (((long long)s * BSZ + b) * DD + d0 + w * 32) * RR;
  #pragma unroll
  for (int ds = 0; ds < 2; ++ds)
    #pragma unroll
    for (int rs = 0; rs < 4; ++rs)
      #pragma unroll
      for (int j = 0; j < 4; ++j)
        op[(long long)(ds * 16 + ((l >> 4) << 2) + j) * RR + (rs << 4) + row16] = acc[ds][rs][j];
}

// ================= out via fp16 MFMA, 16d x 256n tiles -> 1KB row stores
__global__ void __launch_bounds__(256) out16_kernel(const half_t* __restrict__ bD,
                                                    const half_t* __restrict__ cN,
                                                    float* __restrict__ out) {
  __shared__ float ot[16 * 264];
  const int n0 = blockIdx.x << 8;   // 256 n
  const int d0 = blockIdx.y << 4;   // 16 d
  const int b  = blockIdx.z;
  const int t  = threadIdx.x;
  const int w  = t >> 6;
  const int l  = t & 63;
  const int row16 = l & 15;
  const int koff  = (l >> 4) << 3;

  const half_t* ap = bD + ((long long)b * DD + d0 + row16) * RR + koff;
  const half_t* bp = cN + ((long long)b * NN + n0 + (w << 6) + row16) * RR + koff;

  f32x4 acc[4];
  #pragma unroll
  for (int ns = 0; ns < 4; ++ns) acc[ns] = (f32x4){0.f, 0.f, 0.f, 0.f};

  #pragma unroll
  for (int kt = 0; kt < 2; ++kt) {
    const int ko = kt << 5;
    const half8 av = *(const half8*)&ap[ko];
    #pragma unroll
    for (int ns = 0; ns < 4; ++ns) {
      const half8 bv = *(const half8*)&bp[(long long)ns * 16 * RR + ko];
      acc[ns] = mfmah(av, bv, acc[ns]);
    }
  }
  #pragma unroll
  for (int ns = 0; ns < 4; ++ns)
    #pragma unroll
    for (int j = 0; j < 4; ++j)
      ot[(((l >> 4) << 2) + j) * 264 + (w << 6) + (ns << 4) + row16] = acc[ns][j];
  __syncthreads();
  #pragma unroll
  for (int k = 0; k < 4; ++k) {
    const int idx = t + (k << 8);
    const int row = idx >> 6, c4 = (idx & 63) << 2;
    const float4 v = *(const float4*)&ot[row * 264 + c4];
    *(float4*)&out[((long long)b * DD + d0 + row) * NN + n0 + c4] = v;
  }
}

// ================= numer2-partial-sum + inline-CtC-sum + bases update
__global__ void __launch_bounds__(256) bupdate_fb_kernel(float* __restrict__ Bw,
                                                         const float* __restrict__ n2p,
                                                         const float* __restrict__ ctcp,
                                                         int ns2) {
  __shared__ float ct[4096];
  const int b  = blockIdx.y;
  const int d0 = blockIdx.x << 6;
  #pragma unroll
  for (int i = 0; i < 4; ++i) {
    const int w = threadIdx.x + (i << 8);
    float4 s = make_float4(0.f, 0.f, 0.f, 0.f);
    for (int sp = 0; sp < NS_C; ++sp)
      add4(s, ((const float4*)(ctcp + ((long long)sp * BSZ + b) * 4096))[w]);
    ((float4*)ct)[w] = s;
  }
  __syncthreads();
  const int d  = d0 + (threadIdx.x >> 2);
  const int rq = (threadIdx.x & 3) << 4;

  float4 ns[4];
  #pragma unroll
  for (int j = 0; j < 4; ++j) ns[j] = make_float4(0.f, 0.f, 0.f, 0.f);
  for (int s = 0; s < ns2; ++s) {
    const float4* p = (const float4*)&n2p[(((long long)s * BSZ + b) * DD + d) * RR + rq];
    #pragma unroll
    for (int j = 0; j < 4; ++j) add4(ns[j], p[j]);
  }
  const float4* brow = (const float4*)&Bw[((long long)b * DD + d) * RR];
  float4 dn[4];
  #pragma unroll
  for (int j = 0; j < 4; ++j) dn[j] = make_float4(0.f, 0.f, 0.f, 0.f);
  for (int q = 0; q < 16; ++q) {
    const float4 b4 = brow[q];
    const float4* c0 = (const float4*)&ct[(4 * q + 0) * 64 + rq];
    const float4* c1 = (const float4*)&ct[(4 * q + 1) * 64 + rq];
    const float4* c2 = (const float4*)&ct[(4 * q + 2) * 64 + rq];
    const float4* c3 = (const float4*)&ct[(4 * q + 3) * 64 + rq];
    #pragma unroll
    for (int j = 0; j < 4; ++j) {
      fma4s(dn[j], c0[j], b4.x); fma4s(dn[j], c1[j], b4.y);
      fma4s(dn[j], c2[j], b4.z); fma4s(dn[j], c3[j], b4.w);
    }
  }
  float4* bp = (float4*)&Bw[((long long)b * DD + d) * RR + rq];
  float4 bo[4];
  #pragma unroll
  for (int j = 0; j < 4; ++j) bo[j] = bp[j];
  __syncthreads();
  #pragma unroll
  for (int j = 0; j < 4; ++j) {
    float4 o;
    o.x = bo[j].x * ns[j].x / (dn[j].x + EPS);
    o.y = bo[j].y * ns[j].y / (dn[j].y + EPS);
    o.z = bo[j].z * ns[j].z / (dn[j].z + EPS);
    o.w = bo[j].w * ns[j].w / (dn[j].w + EPS);
    bp[j] = o;
  }
}

// ================= Gram partials (fp32, fallback only)
__global__ void __launch_bounds__(256) gram_kernel(const float* __restrict__ M,
                                                   float* __restrict__ outp,
                                                   int rowsPerWave,
                                                   long long batchStride) {
  __shared__ float red[RR * RR];
  const int lane = threadIdx.x & 63;
  const int wid  = threadIdx.x >> 6;
  const int b    = blockIdx.y;
  const long long rowbase = (long long)(blockIdx.x * 4 + wid) * rowsPerWave;
  const float* Mp = M + (long long)b * batchStride + rowbase * RR;
  float acc[RR];
  #pragma unroll
  for (int k = 0; k < RR; ++k) acc[k] = 0.f;
  #pragma unroll 2
  for (int rr = 0; rr < rowsPerWave; ++rr) {
    const float v = Mp[(long long)rr * RR + lane];
    #pragma unroll
    for (int k = 0; k < RR; ++k) acc[k] = fmaf(__shfl(v, k), v, acc[k]);
  }
  for (int w = 0; w < 4; ++w) {
    if (wid == w) {
      if (w == 0) {
        #pragma unroll
        for (int k = 0; k < RR; ++k) red[k * RR + lane] = acc[k];
      } else {
        #pragma unroll
        for (int k = 0; k < RR; ++k) red[k * RR + lane] += acc[k];
      }
    }
    __syncthreads();
  }
  float* op = outp + ((long long)blockIdx.x * BSZ + b) * (RR * RR);
  for (int i = threadIdx.x; i < RR * RR; i += 256) op[i] = red[i];
}

// ================= fp32 fallback kernels (round-6 path) =================

template <int MODE>
__global__ void __launch_bounds__(128) fused_coef_kernel(const float* __restrict__ X,
                                                         const float* __restrict__ Bw,
                                                         const float* __restrict__ btbp,
                                                         float* __restrict__ coef) {
  __shared__ float lds[8192];
  const int b    = blockIdx.y;
  const int n0   = blockIdx.x << 6;
  const int t    = threadIdx.x;
  const int wid  = t >> 6;
  const int lane = t & 63;
  const int rgrp = t & 7;
  const int ngrp = t >> 3;
  const int nl   = ngrp << 2;
  const int r0   = rgrp << 3;
  const float* Xp = X  + (long long)b * DD * NN + n0;
  const float* Bp = Bw + (long long)b * DD * RR;

  float4 acc[4][2];
  #pragma unroll
  for (int i = 0; i < 4; ++i) { acc[i][0] = make_float4(0,0,0,0); acc[i][1] = make_float4(0,0,0,0); }

  auto stage = [&](int buf, int d0) {
    float* xd = lds + (buf << 11);
    float* bd = lds + 4096 + (buf << 11);
    const int rsub = lane >> 4;
    const int c4   = (lane & 15) << 2;
    #pragma unroll
    for (int j = 0; j < 4; ++j) {
      const int q   = (wid << 2) + j;
      const int row = (q << 2) + rsub;
      gload16(&Xp[(long long)(d0 + row) * NN + c4], xd + (q << 8));
      gload16(&Bp[(long long)(d0 + row) * RR + c4], bd + (q << 8));
    }
  };

  stage(0, 0);
  __syncthreads();
  for (int kt = 0; kt < 16; ++kt) {
    const int cur = kt & 1;
    if (kt + 1 < 16) stage(cur ^ 1, (kt + 1) << 5);
    const float* xs = lds + (cur << 11);
    const float* bs = lds + 4096 + (cur << 11);
    #pragma unroll 8
    for (int dd = 0; dd < 32; ++dd) {
      const float4 xv  = *(const float4*)&xs[(dd << 6) + nl];
      const float4 bv0 = *(const float4*)&bs[(dd << 6) + r0];
      const float4 bv1 = *(const float4*)&bs[(dd << 6) + r0 + 4];
      fma4s(acc[0][0], bv0, xv.x); fma4s(acc[0][1], bv1, xv.x);
      fma4s(acc[1][0], bv0, xv.y); fma4s(acc[1][1], bv1, xv.y);
      fma4s(acc[2][0], bv0, xv.z); fma4s(acc[2][1], bv1, xv.z);
      fma4s(acc[3][0], bv0, xv.w); fma4s(acc[3][1], bv1, xv.w);
    }
    __syncthreads();
  }

  if constexpr (MODE == 0) {
    #pragma unroll
    for (int i = 0; i < 4; ++i) {
      float4 a0 = acc[i][0], a1 = acc[i][1];
      float m = fmaxf(fmaxf(fmaxf(a0.x, a0.y), fmaxf(a0.z, a0.w)),
                      fmaxf(fmaxf(a1.x, a1.y), fmaxf(a1.z, a1.w)));
      m = fmaxf(m, __shfl_xor(m, 1));
      m = fmaxf(m, __shfl_xor(m, 2));
      m = fmaxf(m, __shfl_xor(m, 4));
      a0.x = __expf(a0.x - m); a0.y = __expf(a0.y - m);
      a0.z = __expf(a0.z - m); a0.w = __expf(a0.w - m);
      a1.x = __expf(a1.x - m); a1.y = __expf(a1.y - m);
      a1.z = __expf(a1.z - m); a1.w = __expf(a1.w - m);
      float s = a0.x + a0.y + a0.z + a0.w + a1.x + a1.y + a1.z + a1.w;
      s += __shfl_xor(s, 1); s += __shfl_xor(s, 2); s += __shfl_xor(s, 4);
      const float inv = 1.f / s;
      a0.x *= inv; a0.y *= inv; a0.z *= inv; a0.w *= inv;
      a1.x *= inv; a1.y *= inv; a1.z *= inv; a1.w *= inv;
      float* cp = coef + ((long long)b * NN + n0 + nl + i) * RR + r0;
      *(float4*)&cp[0] = a0;
      *(float4*)&cp[4] = a1;
    }
  } else {
    float4* G4  = (float4*)lds;
    float4* CO4 = (float4*)(lds + 4096);
    #pragma unroll
    for (int j = 0; j < 8; ++j) {
      const int wi = t + (j << 7);
      float4 ssum = make_float4(0,0,0,0);
      #pragma unroll
      for (int sp = 0; sp < NS_B; ++sp)
        add4(ssum, ((const float4*)(btbp + ((long long)sp * BSZ + b) * 4096))[wi]);
      G4[wi] = ssum;
    }
    const float4* cof4 = (const float4*)(coef + ((long long)b * NN + n0) * RR);
    #pragma unroll
    for (int j = 0; j < 8; ++j) {
      const int wi = t + (j << 7);
      const int row = wi >> 4, c4 = wi & 15;
      CO4[(row << 4) + (c4 ^ ((row >> 2) & 7))] = cof4[wi];
    }
    __syncthreads();
    const int g = ngrp & 7;
    float4 dn[4][2];
    #pragma unroll
    for (int i = 0; i < 4; ++i) { dn[i][0] = make_float4(0,0,0,0); dn[i][1] = make_float4(0,0,0,0); }
    #pragma unroll 4
    for (int kq = 0; kq < 16; ++kq) {
      float4 g0[4], g1[4];
      #pragma unroll
      for (int jj = 0; jj < 4; ++jj) {
        g0[jj] = G4[(((kq << 2) + jj) << 4) + (rgrp << 1)];
        g1[jj] = G4[(((kq << 2) + jj) << 4) + (rgrp << 1) + 1];
      }
      #pragma unroll
      for (int i = 0; i < 4; ++i) {
        const float4 cv = CO4[((nl + i) << 4) + (kq ^ g)];
        fma4s(dn[i][0], g0[0], cv.x); fma4s(dn[i][1], g1[0], cv.x);
        fma4s(dn[i][0], g0[1], cv.y); fma4s(dn[i][1], g1[1], cv.y);
        fma4s(dn[i][0], g0[2], cv.z); fma4s(dn[i][1], g1[2], cv.z);
        fma4s(dn[i][0], g0[3], cv.w); fma4s(dn[i][1], g1[3], cv.w);
      }
    }
    #pragma unroll
    for (int i = 0; i < 4; ++i) {
      const int row = nl + i;
      const float4 c0 = CO4[(row << 4) + ((rgrp << 1) ^ g)];
      const float4 c1 = CO4[(row << 4) + (((rgrp << 1) + 1) ^ g)];
      float4 o0, o1;
      o0.x = c0.x * acc[i][0].x / (dn[i][0].x + EPS);
      o0.y = c0.y * acc[i][0].y / (dn[i][0].y + EPS);
      o0.z = c0.z * acc[i][0].z / (dn[i][0].z + EPS);
      o0.w = c0.w * acc[i][0].w / (dn[i][0].w + EPS);
      o1.x = c1.x * acc[i][1].x / (dn[i][1].x + EPS);
      o1.y = c1.y * acc[i][1].y / (dn[i][1].y + EPS);
      o1.z = c1.z * acc[i][1].z / (dn[i][1].z + EPS);
      o1.w = c1.w * acc[i][1].w / (dn[i][1].w + EPS);
      float* cp = coef + ((long long)b * NN + n0 + row) * RR + r0;
      *(float4*)&cp[0] = o0;
      *(float4*)&cp[4] = o1;
    }
  }
}

__global__ void __launch_bounds__(128) numer2_kernel(const float* __restrict__ X,
                                                     const float* __restrict__ coef,
                                                     float* __restrict__ n2p) {
  __shared__ float lds[8192];
  const int b    = blockIdx.z;
  const int s    = blockIdx.y;
  const int d0   = blockIdx.x << 6;
  const int t    = threadIdx.x;
  const int wid  = t >> 6;
  const int lane = t & 63;
  const int rgrp = t & 7;
  const int dgrp = t >> 3;
  const int dl   = dgrp << 2;
  const int r0   = rgrp << 3;
  const int nbeg = s * (NN / NS_N2);
  const float* Xp = X + (long long)b * DD * NN + (long long)d0 * NN;
  const float* Cp = coef + (long long)b * NN * RR;

  float4 acc[4][2];
  #pragma unroll
  for (int i = 0; i < 4; ++i) { acc[i][0] = make_float4(0,0,0,0); acc[i][1] = make_float4(0,0,0,0); }

  auto stage = [&](int buf, int nb) {
    float* xd = lds + (buf << 11);
    float* cd = lds + 4096 + (buf << 11);
    {
      const int rsub = lane >> 3, c4 = lane & 7;
      #pragma unroll
      for (int j = 0; j < 4; ++j) {
        const int q   = (wid << 2) + j;
        const int row = (q << 3) + rsub;
        const int sc  = (c4 ^ ((row >> 2) & 7)) << 2;
        gload16(&Xp[(long long)row * NN + nb + sc], xd + (q << 8));
      }
    }
    {
      const int rsub = lane >> 4, c4 = (lane & 15) << 2;
      #pragma unroll
      for (int j = 0; j < 4; ++j) {
        const int q   = (wid << 2) + j;
        const int row = (q << 2) + rsub;
        gload16(&Cp[(long long)(nb + row) * RR + c4], cd + (q << 8));
      }
    }
  };

  stage(0, nbeg);
  __syncthreads();
  const int g = dgrp & 7;
  for (int kt = 0; kt < (NN / NS_N2) / 32; ++kt) {
    const int cur = kt & 1;
    if (kt + 1 < (NN / NS_N2) / 32) stage(cur ^ 1, nbeg + ((kt + 1) << 5));
    const float* xs = lds + (cur << 11);
    const float* cs = lds + 4096 + (cur << 11);
    #pragma unroll 8
    for (int nn = 0; nn < 32; ++nn) {
      const int col = ((((nn >> 2) ^ g) << 2) + (nn & 3));
      float xe[4];
      #pragma unroll
      for (int i = 0; i < 4; ++i) xe[i] = xs[((dl + i) << 5) + col];
      const float4 cv0 = *(const float4*)&cs[(nn << 6) + r0];
      const float4 cv1 = *(const float4*)&cs[(nn << 6) + r0 + 4];
      #pragma unroll
      for (int i = 0; i < 4; ++i) {
        fma4s(acc[i][0], cv0, xe[i]);
        fma4s(acc[i][1], cv1, xe[i]);
      }
    }
    __syncthreads();
  }
  #pragma unroll
  for (int i = 0; i < 4; ++i) {
    float* op = n2p + (((long long)s * BSZ + b) * DD + d0 + dl + i) * RR + r0;
    *(float4*)&op[0] = acc[i][0];
    *(float4*)&op[4] = acc[i][1];
  }
}

__global__ void __launch_bounds__(256) out_kernel(const float* __restrict__ Bw,
                                                  const float* __restrict__ coef,
                                                  float* __restrict__ out) {
  __shared__ float bt [64 * 68];
  __shared__ float ctl[64 * 68];
  const int n0 = blockIdx.x << 6;
  const int d0 = blockIdx.y << 6;
  const int b  = blockIdx.z;
  const int tx = threadIdx.x & 15;
  const int ty = threadIdx.x >> 4;
  for (int t = threadIdx.x; t < 1024; t += 256) {
    const int row = t >> 4, c4 = (t & 15) << 2;
    const float4 v = *(const float4*)&Bw[((long long)b * DD + d0 + row) * RR + c4];
    bt[(c4 + 0) * 68 + row] = v.x; bt[(c4 + 1) * 68 + row] = v.y;
    bt[(c4 + 2) * 68 + row] = v.z; bt[(c4 + 3) * 68 + row] = v.w;
  }
  for (int t = threadIdx.x; t < 1024; t += 256) {
    const int row = t >> 4, c4 = (t & 15) << 2;
    const float4 v = *(const float4*)&coef[((long long)b * NN + n0 + row) * RR + c4];
    ctl[(c4 + 0) * 68 + row] = v.x; ctl[(c4 + 1) * 68 + row] = v.y;
    ctl[(c4 + 2) * 68 + row] = v.z; ctl[(c4 + 3) * 68 + row] = v.w;
  }
  __syncthreads();
  float4 ai[4];
  #pragma unroll
  for (int i = 0; i < 4; ++i) ai[i] = make_float4(0.f, 0.f, 0.f, 0.f);
  #pragma unroll 8
  for (int r = 0; r < 64; ++r) {
    const float4 bv = *(const float4*)&bt [r * 68 + (ty << 2)];
    const float4 cv = *(const float4*)&ctl[r * 68 + (tx << 2)];
    fma4s(ai[0], cv, bv.x); fma4s(ai[1], cv, bv.y);
    fma4s(ai[2], cv, bv.z); fma4s(ai[3], cv, bv.w);
  }
  #pragma unroll
  for (int i = 0; i < 4; ++i)
    *(float4*)&out[((long long)b * DD + d0 + (ty << 2) + i) * NN + n0 + (tx << 2)] = ai[i];
}

extern "C" void kernel_launch(void* const* d_in, const int* in_sizes, int n_in,
                              void* d_out, int out_size, void* d_ws, size_t ws_size,
                              hipStream_t stream) {
  const float* x        = (const float*)d_in[0];
  const float* bases_in = (const float*)d_in[1];
  float* out = (float*)d_out;
  float* ws  = (float*)d_ws;

  float* coef    = ws;                                   // 4M f32
  float* bases_w = coef + (long long)BSZ * NN * RR;      // 0.5M
  float* btbp    = bases_w + (long long)BSZ * DD * RR;   // 0.5M (fallback)
  float* ctcp    = btbp + (long long)NS_B * BSZ * 4096;  // 2M
  float* n2p     = ctcp + (long long)NS_C * BSZ * 4096;  // 4M
  float* ctcs    = n2p + (long long)NS_N2 * BSZ * DD * RR;   // 64K (unused, layout keep)
  half_t* xT16   = (half_t*)(ctcs + (long long)BSZ * 4096);  // 33.5M halfs
  half_t* xd16   = xT16 + (long long)BSZ * NN * DD;          // 33.5M halfs
  half_t* BbT16  = xd16 + (long long)BSZ * NN * DD;          // 0.5M halfs
  half_t* cbT16  = BbT16 + (long long)BSZ * RR * DD;         // 4M halfs
  half_t* Gh16   = cbT16 + (long long)BSZ * RR * NN;         // 64K halfs
  const long long need = (long long)((char*)(Gh16 + (long long)BSZ * 4096) - (char*)d_ws);

  // post-loop aliases (n2p dead after last bupdate)
  half_t* cN16 = (half_t*)n2p;                       // 8 MB
  half_t* bD16 = cN16 + (long long)BSZ * NN * RR;    // 1 MB

  const dim3 blk256(256);
  const dim3 blk128(128);

  hipMemcpyAsync(bases_w, bases_in, sizeof(float) * BSZ * DD * RR,
                 hipMemcpyDeviceToDevice, stream);

  if ((long long)ws_size >= need) {
    // ---------- fp16-MFMA path (all loop operands L3-resident) ----------
    cast16_kernel<<<dim3(16384), blk256, 0, stream>>>(x, xd16, (long long)BSZ * DD * NN);
    tcvt16_kernel<<<dim3(NN / 64, DD / 64, BSZ), blk256, 0, stream>>>(x, xT16, DD, NN);
    tcvt16_kernel<<<dim3(1, DD / 64, BSZ), blk256, 0, stream>>>(bases_w, BbT16, DD, RR);
    fused16_kernel<0><<<dim3(NN / 32, BSZ), blk128, 0, stream>>>(
        xT16, BbT16, nullptr, coef, nullptr, nullptr);

    for (int it = 0; it < STEPS; ++it) {
      tcvt16_kernel<<<dim3(1, DD / 64, BSZ), blk256, 0, stream>>>(bases_w, BbT16, DD, RR);
      btb16_kernel<<<dim3(BSZ), blk256, 0, stream>>>(BbT16, Gh16);
      fused16_kernel<1><<<dim3(NN / 32, BSZ), blk128, 0, stream>>>(
          xT16, BbT16, Gh16, coef, cbT16, nullptr);
      ctc16_kernel<<<dim3(8, BSZ), blk256, 0, stream>>>(cbT16, ctcp);
      numer2_16_kernel<<<dim3(DD / 64, NS_N2, BSZ), blk128, 0, stream>>>(xd16, cbT16, n2p);
      bupdate_fb_kernel<<<dim3(DD / 64, BSZ), blk256, 0, stream>>>(bases_w, n2p, ctcp, NS_N2);
    }
    // compute_coef: final update emits fp16 coef [n][r] directly
    tcvt16_kernel<<<dim3(1, DD / 64, BSZ), blk256, 0, stream>>>(bases_w, BbT16, DD, RR);
    btb16_kernel<<<dim3(BSZ), blk256, 0, stream>>>(BbT16, Gh16);
    fused16_kernel<2><<<dim3(NN / 32, BSZ), blk128, 0, stream>>>(
        xT16, BbT16, Gh16, coef, nullptr, cN16);
    cast16_kernel<<<dim3(256), blk256, 0, stream>>>(bases_w, bD16, (long long)BSZ * DD * RR);
    out16_kernel<<<dim3(NN / 256, DD / 16, BSZ), blk256, 0, stream>>>(bD16, cN16, out);
  } else {
    // ---------- fp32 fallback (round-6 path) ----------
    fused_coef_kernel<0><<<dim3(NN / 64, BSZ), blk128, 0, stream>>>(x, bases_w, nullptr, coef);
    for (int it = 0; it < STEPS; ++it) {
      gram_kernel<<<dim3(NS_B, BSZ), blk256, 0, stream>>>(bases_w, btbp, DD / (NS_B * 4),
                                                          (long long)DD * RR);
      fused_coef_kernel<1><<<dim3(NN / 64, BSZ), blk128, 0, stream>>>(x, bases_w, btbp, coef);
      gram_kernel<<<dim3(NS_C, BSZ), blk256, 0, stream>>>(coef, ctcp, NN / (NS_C * 4),
                                                          (long long)NN * RR);
      numer2_kernel<<<dim3(DD / 64, NS_N2, BSZ), blk128, 0, stream>>>(x, coef, n2p);
      bupdate_fb_kernel<<<dim3(DD / 64, BSZ), blk256, 0, stream>>>(bases_w, n2p, ctcp, NS_N2);
    }
    gram_kernel<<<dim3(NS_B, BSZ), blk256, 0, stream>>>(bases_w, btbp, DD / (NS_B * 4),
                                                        (long long)DD * RR);
    fused_coef_kernel<1><<<dim3(NN / 64, BSZ), blk128, 0, stream>>>(x, bases_w, btbp, coef);
    out_kernel<<<dim3(NN / 64, DD / 64, BSZ), blk256, 0, stream>>>(bases_w, coef, out);
  }
}

// Round 12
// 923.470 us; speedup vs baseline: 2.0177x; 1.0798x over previous
//
#include <hip/hip_runtime.h>
#include <math.h>

#define EPS 1e-6f

constexpr int BSZ = 16;    // batch * S
constexpr int DD  = 512;   // channels / S
constexpr int NN  = 4096;  // H*W
constexpr int RR  = 64;
constexpr int STEPS = 7;
constexpr int NS_B  = 8;   // (fallback) BtB d-split blocks
constexpr int NS_C  = 32;  // (fallback) CtC partial slots
constexpr int NS_N2 = 8;   // numer2 / CtC n-split partials

typedef _Float16 half_t;
typedef __attribute__((ext_vector_type(8))) _Float16 half8;
typedef __attribute__((ext_vector_type(4))) float f32x4;

__device__ __forceinline__ void fma4s(float4& a, const float4& b, float s) {
  a.x = fmaf(b.x, s, a.x); a.y = fmaf(b.y, s, a.y);
  a.z = fmaf(b.z, s, a.z); a.w = fmaf(b.w, s, a.w);
}
__device__ __forceinline__ void add4(float4& a, const float4& b) {
  a.x += b.x; a.y += b.y; a.z += b.z; a.w += b.w;
}
__device__ __forceinline__ f32x4 mfmah(half8 a, half8 b, f32x4 c) {
  return __builtin_amdgcn_mfma_f32_16x16x32_f16(a, b, c, 0, 0, 0);
}

// async global->LDS, 16B per lane (fp32 fallback path)
__device__ __forceinline__ void gload16(const float* g, float* l) {
  __builtin_amdgcn_global_load_lds(
      (const __attribute__((address_space(1))) void*)g,
      (__attribute__((address_space(3))) void*)l, 16, 0, 0);
}

// ================= transpose + fp32->fp16: src [b][R][C] -> dst [b][C][R]
__global__ void __launch_bounds__(256) tcvt16_kernel(const float* __restrict__ src,
                                                     half_t* __restrict__ dh,
                                                     int R, int C) {
  __shared__ float tileT[64 * 65];   // [src_col][src_row]
  const int b = blockIdx.z, c0 = blockIdx.x << 6, r0 = blockIdx.y << 6;
  const float* sp = src + (long long)b * R * C;
  const int t = threadIdx.x;
  #pragma unroll
  for (int i = 0; i < 4; ++i) {
    const int idx = t + (i << 8);
    const int row = idx >> 4, c4 = (idx & 15) << 2;
    const float4 v = *(const float4*)&sp[(long long)(r0 + row) * C + c0 + c4];
    tileT[(c4 + 0) * 65 + row] = v.x;
    tileT[(c4 + 1) * 65 + row] = v.y;
    tileT[(c4 + 2) * 65 + row] = v.z;
    tileT[(c4 + 3) * 65 + row] = v.w;
  }
  __syncthreads();
  const int orow = t >> 2, och = (t & 3) << 4;
  half8 h0, h1;
  #pragma unroll
  for (int j = 0; j < 8; ++j) h0[j] = (half_t)tileT[orow * 65 + och + j];
  #pragma unroll
  for (int j = 0; j < 8; ++j) h1[j] = (half_t)tileT[orow * 65 + och + 8 + j];
  const long long ob = ((long long)b * C + c0 + orow) * R + r0 + och;
  *(half8*)&dh[ob] = h0;
  *(half8*)&dh[ob + 8] = h1;
}

// ================= flat fp32 -> fp16 cast
__global__ void __launch_bounds__(256) cast16_kernel(const float* __restrict__ src,
                                                     half_t* __restrict__ dst,
                                                     long long n) {
  const long long i = ((long long)blockIdx.x * 256 + threadIdx.x) * 8;
  if (i >= n) return;
  const float4 a = *(const float4*)&src[i];
  const float4 c = *(const float4*)&src[i + 4];
  half8 h;
  h[0] = (half_t)a.x; h[1] = (half_t)a.y; h[2] = (half_t)a.z; h[3] = (half_t)a.w;
  h[4] = (half_t)c.x; h[5] = (half_t)c.y; h[6] = (half_t)c.z; h[7] = (half_t)c.w;
  *(half8*)&dst[i] = h;
}

// ================= G = B~^T B~ via fp16 MFMA, one block per batch
__global__ void __launch_bounds__(256) btb16_kernel(const half_t* __restrict__ BT,
                                                    half_t* __restrict__ Gh) {
  __shared__ float red[64 * 64];
  const int b = blockIdx.x;
  const int t = threadIdx.x;
  const int w = t >> 6;
  const int l = t & 63;
  const int row16 = l & 15;
  const int koff  = (l >> 4) << 3;

  const half_t* ap = BT + ((long long)b * RR + row16) * DD + (w << 7) + koff;

  f32x4 acc[4][4];
  #pragma unroll
  for (int i = 0; i < 4; ++i)
    #pragma unroll
    for (int j = 0; j < 4; ++j) acc[i][j] = (f32x4){0.f, 0.f, 0.f, 0.f};

  #pragma unroll
  for (int kt = 0; kt < 4; ++kt) {
    const int ko = kt << 5;
    half8 af[4];
    #pragma unroll
    for (int rs = 0; rs < 4; ++rs) af[rs] = *(const half8*)&ap[(long long)rs * 16 * DD + ko];
    #pragma unroll
    for (int r1 = 0; r1 < 4; ++r1)
      #pragma unroll
      for (int r2 = 0; r2 < 4; ++r2)
        acc[r1][r2] = mfmah(af[r1], af[r2], acc[r1][r2]);
  }
  for (int ww = 0; ww < 4; ++ww) {
    if (w == ww) {
      #pragma unroll
      for (int r1 = 0; r1 < 4; ++r1)
        #pragma unroll
        for (int r2 = 0; r2 < 4; ++r2)
          #pragma unroll
          for (int j = 0; j < 4; ++j) {
            const int row = (r1 << 4) + ((l >> 4) << 2) + j;
            const int col = (r2 << 4) + row16;
            if (ww == 0) red[row * 64 + col] = acc[r1][r2][j];
            else         red[row * 64 + col] += acc[r1][r2][j];
          }
    }
    __syncthreads();
  }
  for (int i = t; i < 512; i += 256) {
    half8 h;
    #pragma unroll
    for (int j = 0; j < 8; ++j) h[j] = (half_t)red[(i << 3) + j];
    *(half8*)&Gh[(long long)b * 4096 + (i << 3)] = h;
  }
}

// ================= fp16-MFMA fused numer + {softmax | coef update}
template <int MODE>
__global__ void __launch_bounds__(128) fused16_kernel(const half_t* __restrict__ xT,
                                                      const half_t* __restrict__ BT,
                                                      const half_t* __restrict__ Gh,
                                                      float* __restrict__ coef,
                                                      half_t* __restrict__ cbT,
                                                      half_t* __restrict__ cN) {
  __shared__ half_t ctile[(MODE == 1) ? 64 * 40 : 8];
  const int b  = blockIdx.y;
  const int n0 = blockIdx.x << 5;
  const int t  = threadIdx.x;
  const int w  = t >> 6;
  const int l  = t & 63;
  const int row16 = l & 15;
  const int koff  = (l >> 4) << 3;
  const int nrb   = n0 + (w << 4);

  const half_t* ap = xT + ((long long)b * NN + nrb + row16) * DD + koff;
  const half_t* bp = BT + ((long long)b * RR + row16) * DD + koff;

  f32x4 acc[4];
  #pragma unroll
  for (int rs = 0; rs < 4; ++rs) acc[rs] = (f32x4){0.f, 0.f, 0.f, 0.f};

  #pragma unroll
  for (int kt = 0; kt < 16; ++kt) {
    const int ko = kt << 5;
    const half8 av = *(const half8*)&ap[ko];
    #pragma unroll
    for (int rs = 0; rs < 4; ++rs) {
      const half8 bv = *(const half8*)&bp[rs * 16 * DD + ko];
      acc[rs] = mfmah(av, bv, acc[rs]);
    }
  }

  if constexpr (MODE == 0) {
    #pragma unroll
    for (int j = 0; j < 4; ++j) {
      float m = fmaxf(fmaxf(acc[0][j], acc[1][j]), fmaxf(acc[2][j], acc[3][j]));
      m = fmaxf(m, __shfl_xor(m, 1));
      m = fmaxf(m, __shfl_xor(m, 2));
      m = fmaxf(m, __shfl_xor(m, 4));
      m = fmaxf(m, __shfl_xor(m, 8));
      float s = 0.f;
      #pragma unroll
      for (int rs = 0; rs < 4; ++rs) { acc[rs][j] = __expf(acc[rs][j] - m); s += acc[rs][j]; }
      s += __shfl_xor(s, 1); s += __shfl_xor(s, 2);
      s += __shfl_xor(s, 4); s += __shfl_xor(s, 8);
      const float inv = 1.f / s;
      #pragma unroll
      for (int rs = 0; rs < 4; ++rs) acc[rs][j] *= inv;
    }
    #pragma unroll
    for (int rs = 0; rs < 4; ++rs)
      #pragma unroll
      for (int j = 0; j < 4; ++j)
        coef[((long long)b * NN + nrb + ((l >> 4) << 2) + j) * RR + (rs << 4) + row16] = acc[rs][j];
  } else {
    // denom = cold @ G via fp16 MFMA (G symmetric -> rows are k-contiguous)
    const float* crow = coef + ((long long)b * NN + nrb + row16) * RR;
    const half_t* ghb = Gh + (long long)b * 4096;
    f32x4 dn[4];
    #pragma unroll
    for (int rs = 0; rs < 4; ++rs) dn[rs] = (f32x4){0.f, 0.f, 0.f, 0.f};
    #pragma unroll
    for (int kt = 0; kt < 2; ++kt) {
      const int ko = (kt << 5) + koff;
      const float4 c0 = *(const float4*)&crow[ko];
      const float4 c1 = *(const float4*)&crow[ko + 4];
      half8 ch;
      ch[0] = (half_t)c0.x; ch[1] = (half_t)c0.y; ch[2] = (half_t)c0.z; ch[3] = (half_t)c0.w;
      ch[4] = (half_t)c1.x; ch[5] = (half_t)c1.y; ch[6] = (half_t)c1.z; ch[7] = (half_t)c1.w;
      #pragma unroll
      for (int rs = 0; rs < 4; ++rs) {
        const half8 gh = *(const half8*)&ghb[((rs << 4) + row16) * 64 + ko];
        dn[rs] = mfmah(ch, gh, dn[rs]);
      }
    }
    // multiplicative update (element-owner unique in D-frag positions)
    #pragma unroll
    for (int rs = 0; rs < 4; ++rs)
      #pragma unroll
      for (int j = 0; j < 4; ++j) {
        const int r = (rs << 4) + row16;
        const int nl = ((w << 4) + ((l >> 4) << 2) + j);   // n - n0
        const long long idx = ((long long)b * NN + n0 + nl) * RR + r;
        const float co = coef[idx];
        const float v  = co * acc[rs][j] / (dn[rs][j] + EPS);
        if constexpr (MODE == 1) {
          coef[idx] = v;
          ctile[r * 40 + nl] = (half_t)v;
        } else {
          cN[idx] = (half_t)v;
        }
      }
    if constexpr (MODE == 1) {
      __syncthreads();
      if (t < 64) {   // row r = t: write 32 contiguous fp16 (64 B) to cbT
        half_t* dst = cbT + ((long long)b * RR + t) * NN + n0;
        *(half8*)&dst[0]  = *(const half8*)&ctile[t * 40 + 0];
        *(half8*)&dst[8]  = *(const half8*)&ctile[t * 40 + 8];
        *(half8*)&dst[16] = *(const half8*)&ctile[t * 40 + 16];
        *(half8*)&dst[24] = *(const half8*)&ctile[t * 40 + 24];
      }
    }
  }
}

// ================= merged numer2 partials + CtC partials (share cbT dependency)
// grid (DD/64 + 1, NS_N2, BSZ).  blockIdx.x < DD/64: numer2 path.
// blockIdx.x == DD/64: CtC partial for this (s,b) n-slice of 512 (2 waves x 256 n).
__global__ void __launch_bounds__(128) numer2ctc16_kernel(const half_t* __restrict__ xh,
                                                          const half_t* __restrict__ cbT,
                                                          float* __restrict__ n2p,
                                                          float* __restrict__ ctcp) {
  __shared__ float red[4096];
  const int b = blockIdx.z;
  const int s = blockIdx.y;
  const int t = threadIdx.x;
  const int w = t >> 6;
  const int l = t & 63;
  const int row16 = l & 15;
  const int koff  = (l >> 4) << 3;
  const int nbeg  = s * (NN / NS_N2);

  if (blockIdx.x == DD / 64) {
    const half_t* ap = cbT + ((long long)b * RR + row16) * NN + nbeg + (w << 8) + koff;
    f32x4 acc[4][4];
    #pragma unroll
    for (int i = 0; i < 4; ++i)
      #pragma unroll
      for (int j = 0; j < 4; ++j) acc[i][j] = (f32x4){0.f, 0.f, 0.f, 0.f};
    #pragma unroll
    for (int kt = 0; kt < 8; ++kt) {
      const int ko = kt << 5;
      half8 af[4];
      #pragma unroll
      for (int rs = 0; rs < 4; ++rs) af[rs] = *(const half8*)&ap[(long long)rs * 16 * NN + ko];
      #pragma unroll
      for (int r1 = 0; r1 < 4; ++r1)
        #pragma unroll
        for (int r2 = 0; r2 < 4; ++r2)
          acc[r1][r2] = mfmah(af[r1], af[r2], acc[r1][r2]);
    }
    if (w == 0) {
      #pragma unroll
      for (int r1 = 0; r1 < 4; ++r1)
        #pragma unroll
        for (int r2 = 0; r2 < 4; ++r2)
          #pragma unroll
          for (int j = 0; j < 4; ++j)
            red[((r1 << 4) + ((l >> 4) << 2) + j) * 64 + (r2 << 4) + row16] = acc[r1][r2][j];
    }
    __syncthreads();
    if (w == 1) {
      #pragma unroll
      for (int r1 = 0; r1 < 4; ++r1)
        #pragma unroll
        for (int r2 = 0; r2 < 4; ++r2)
          #pragma unroll
          for (int j = 0; j < 4; ++j)
            red[((r1 << 4) + ((l >> 4) << 2) + j) * 64 + (r2 << 4) + row16] += acc[r1][r2][j];
    }
    __syncthreads();
    float* op = ctcp + ((long long)s * BSZ + b) * 4096;
    for (int i = t; i < 1024; i += 128) ((float4*)op)[i] = ((const float4*)red)[i];
    return;
  }

  const int d0 = blockIdx.x << 6;
  const half_t* ap = xh + ((long long)b * DD + d0 + w * 32 + row16) * NN + nbeg + koff;
  const half_t* cp = cbT + ((long long)b * RR + row16) * NN + nbeg + koff;

  f32x4 acc[2][4];
  #pragma unroll
  for (int ds = 0; ds < 2; ++ds)
    #pragma unroll
    for (int rs = 0; rs < 4; ++rs) acc[ds][rs] = (f32x4){0.f, 0.f, 0.f, 0.f};

  #pragma unroll
  for (int kt = 0; kt < 16; ++kt) {
    const int ko = kt << 5;
    half8 av[2], bf[4];
    #pragma unroll
    for (int ds = 0; ds < 2; ++ds) av[ds] = *(const half8*)&ap[(long long)ds * 16 * NN + ko];
    #pragma unroll
    for (int rs = 0; rs < 4; ++rs) bf[rs] = *(const half8*)&cp[(long long)rs * 16 * NN + ko];
    #pragma unroll
    for (int ds = 0; ds < 2; ++ds)
      #pragma unroll
      for (int rs = 0; rs < 4; ++rs)
        acc[ds][rs] = mfmah(av[ds], bf[rs], acc[ds][rs]);
  }
  float* op = n2p + (((long long)s * BSZ + b) * DD + d0 + w * 32) * RR;
  #pragma unroll
  for (int ds = 0; ds < 2; ++ds)
    #pragma unroll
    for (int rs = 0; rs < 4; ++rs)
      #pragma unroll
      for (int j = 0; j < 4; ++j)
        op[(long long)(ds * 16 + ((l >> 4) << 2) + j) * RR + (rs << 4) + row16] = acc[ds][rs][j];
}

// ================= bases update; also emits BbT16 (transposed fp16) and
// optionally bD16 (fp16 [d][r], last iteration) directly from registers.
__global__ void __launch_bounds__(256) bupdate16_kernel(float* __restrict__ Bw,
                                                        const float* __restrict__ n2p,
                                                        const float* __restrict__ ctcp,
                                                        half_t* __restrict__ BbT,
                                                        half_t* __restrict__ bD) {
  __shared__ float ct[4096];
  const int b  = blockIdx.y;
  const int d0 = blockIdx.x << 6;
  const int t  = threadIdx.x;
  #pragma unroll
  for (int i = 0; i < 4; ++i) {
    const int w = t + (i << 8);
    float4 s4 = make_float4(0.f, 0.f, 0.f, 0.f);
    #pragma unroll
    for (int sp = 0; sp < NS_N2; ++sp)
      add4(s4, ((const float4*)(ctcp + ((long long)sp * BSZ + b) * 4096))[w]);
    ((float4*)ct)[w] = s4;
  }
  __syncthreads();
  const int dl = t >> 2;
  const int d  = d0 + dl;
  const int rq = (t & 3) << 4;

  float4 ns[4];
  #pragma unroll
  for (int j = 0; j < 4; ++j) ns[j] = make_float4(0.f, 0.f, 0.f, 0.f);
  for (int s = 0; s < NS_N2; ++s) {
    const float4* p = (const float4*)&n2p[(((long long)s * BSZ + b) * DD + d) * RR + rq];
    #pragma unroll
    for (int j = 0; j < 4; ++j) add4(ns[j], p[j]);
  }
  const float4* brow = (const float4*)&Bw[((long long)b * DD + d) * RR];
  float4 dn[4];
  #pragma unroll
  for (int j = 0; j < 4; ++j) dn[j] = make_float4(0.f, 0.f, 0.f, 0.f);
  for (int q = 0; q < 16; ++q) {
    const float4 b4 = brow[q];
    const float4* c0 = (const float4*)&ct[(4 * q + 0) * 64 + rq];
    const float4* c1 = (const float4*)&ct[(4 * q + 1) * 64 + rq];
    const float4* c2 = (const float4*)&ct[(4 * q + 2) * 64 + rq];
    const float4* c3 = (const float4*)&ct[(4 * q + 3) * 64 + rq];
    #pragma unroll
    for (int j = 0; j < 4; ++j) {
      fma4s(dn[j], c0[j], b4.x); fma4s(dn[j], c1[j], b4.y);
      fma4s(dn[j], c2[j], b4.z); fma4s(dn[j], c3[j], b4.w);
    }
  }
  float4* bp = (float4*)&Bw[((long long)b * DD + d) * RR + rq];
  float4 bo[4];
  #pragma unroll
  for (int j = 0; j < 4; ++j) bo[j] = bp[j];
  __syncthreads();   // all ct / Bw reads complete (block-wide)
  half_t* tile = (half_t*)ct;   // reuse: [r][dlocal] 64x64 fp16
  float4 ov[4];
  #pragma unroll
  for (int j = 0; j < 4; ++j) {
    ov[j].x = bo[j].x * ns[j].x / (dn[j].x + EPS);
    ov[j].y = bo[j].y * ns[j].y / (dn[j].y + EPS);
    ov[j].z = bo[j].z * ns[j].z / (dn[j].z + EPS);
    ov[j].w = bo[j].w * ns[j].w / (dn[j].w + EPS);
    bp[j] = ov[j];
    tile[(rq + (j << 2) + 0) * 64 + dl] = (half_t)ov[j].x;
    tile[(rq + (j << 2) + 1) * 64 + dl] = (half_t)ov[j].y;
    tile[(rq + (j << 2) + 2) * 64 + dl] = (half_t)ov[j].z;
    tile[(rq + (j << 2) + 3) * 64 + dl] = (half_t)ov[j].w;
  }
  if (bD) {
    half_t* dst = bD + ((long long)b * DD + d) * RR + rq;
    half8 h0, h1;
    #pragma unroll
    for (int e = 0; e < 4; ++e) {
      h0[e] = (half_t)ov[0].x, h0[e] = h0[e];  // placeholder avoided below
    }
    h0[0] = (half_t)ov[0].x; h0[1] = (half_t)ov[0].y; h0[2] = (half_t)ov[0].z; h0[3] = (half_t)ov[0].w;
    h0[4] = (half_t)ov[1].x; h0[5] = (half_t)ov[1].y; h0[6] = (half_t)ov[1].z; h0[7] = (half_t)ov[1].w;
    h1[0] = (half_t)ov[2].x; h1[1] = (half_t)ov[2].y; h1[2] = (half_t)ov[2].z; h1[3] = (half_t)ov[2].w;
    h1[4] = (half_t)ov[3].x; h1[5] = (half_t)ov[3].y; h1[6] = (half_t)ov[3].z; h1[7] = (half_t)ov[3].w;
    *(half8*)&dst[0] = h0;
    *(half8*)&dst[8] = h1;
  }
  __syncthreads();
  const int r = t >> 2, qc = t & 3;
  half_t* dstT = BbT + ((long long)b * RR + r) * DD + d0 + (qc << 4);
  *(half8*)&dstT[0] = *(const half8*)&tile[r * 64 + (qc << 4)];
  *(half8*)&dstT[8] = *(const half8*)&tile[r * 64 + (qc << 4) + 8];
}

// ================= out via fp16 MFMA, 16d x 256n tiles -> 1KB row stores
__global__ void __launch_bounds__(256) out16_kernel(const half_t* __restrict__ bD,
                                                    const half_t* __restrict__ cN,
                                                    float* __restrict__ out) {
  __shared__ float ot[16 * 264];
  const int n0 = blockIdx.x << 8;
  const int d0 = blockIdx.y << 4;
  const int b  = blockIdx.z;
  const int t  = threadIdx.x;
  const int w  = t >> 6;
  const int l  = t & 63;
  const int row16 = l & 15;
  const int koff  = (l >> 4) << 3;

  const half_t* ap = bD + ((long long)b * DD + d0 + row16) * RR + koff;
  const half_t* bp = cN + ((long long)b * NN + n0 + (w << 6) + row16) * RR + koff;

  f32x4 acc[4];
  #pragma unroll
  for (int ns = 0; ns < 4; ++ns) acc[ns] = (f32x4){0.f, 0.f, 0.f, 0.f};

  #pragma unroll
  for (int kt = 0; kt < 2; ++kt) {
    const int ko = kt << 5;
    const half8 av = *(const half8*)&ap[ko];
    #pragma unroll
    for (int ns = 0; ns < 4; ++ns) {
      const half8 bv = *(const half8*)&bp[(long long)ns * 16 * RR + ko];
      acc[ns] = mfmah(av, bv, acc[ns]);
    }
  }
  #pragma unroll
  for (int ns = 0; ns < 4; ++ns)
    #pragma unroll
    for (int j = 0; j < 4; ++j)
      ot[(((l >> 4) << 2) + j) * 264 + (w << 6) + (ns << 4) + row16] = acc[ns][j];
  __syncthreads();
  #pragma unroll
  for (int k = 0; k < 4; ++k) {
    const int idx = t + (k << 8);
    const int row = idx >> 6, c4 = (idx & 63) << 2;
    const float4 v = *(const float4*)&ot[row * 264 + c4];
    *(float4*)&out[((long long)b * DD + d0 + row) * NN + n0 + c4] = v;
  }
}

// ================= fp32 fallback kernels (round-6 path) =================

__global__ void __launch_bounds__(256) gram_kernel(const float* __restrict__ M,
                                                   float* __restrict__ outp,
                                                   int rowsPerWave,
                                                   long long batchStride) {
  __shared__ float red[RR * RR];
  const int lane = threadIdx.x & 63;
  const int wid  = threadIdx.x >> 6;
  const int b    = blockIdx.y;
  const long long rowbase = (long long)(blockIdx.x * 4 + wid) * rowsPerWave;
  const float* Mp = M + (long long)b * batchStride + rowbase * RR;
  float acc[RR];
  #pragma unroll
  for (int k = 0; k < RR; ++k) acc[k] = 0.f;
  #pragma unroll 2
  for (int rr = 0; rr < rowsPerWave; ++rr) {
    const float v = Mp[(long long)rr * RR + lane];
    #pragma unroll
    for (int k = 0; k < RR; ++k) acc[k] = fmaf(__shfl(v, k), v, acc[k]);
  }
  for (int w = 0; w < 4; ++w) {
    if (wid == w) {
      if (w == 0) {
        #pragma unroll
        for (int k = 0; k < RR; ++k) red[k * RR + lane] = acc[k];
      } else {
        #pragma unroll
        for (int k = 0; k < RR; ++k) red[k * RR + lane] += acc[k];
      }
    }
    __syncthreads();
  }
  float* op = outp + ((long long)blockIdx.x * BSZ + b) * (RR * RR);
  for (int i = threadIdx.x; i < RR * RR; i += 256) op[i] = red[i];
}

template <int MODE>
__global__ void __launch_bounds__(128) fused_coef_kernel(const float* __restrict__ X,
                                                         const float* __restrict__ Bw,
                                                         const float* __restrict__ btbp,
                                                         float* __restrict__ coef) {
  __shared__ float lds[8192];
  const int b    = blockIdx.y;
  const int n0   = blockIdx.x << 6;
  const int t    = threadIdx.x;
  const int wid  = t >> 6;
  const int lane = t & 63;
  const int rgrp = t & 7;
  const int ngrp = t >> 3;
  const int nl   = ngrp << 2;
  const int r0   = rgrp << 3;
  const float* Xp = X  + (long long)b * DD * NN + n0;
  const float* Bp = Bw + (long long)b * DD * RR;

  float4 acc[4][2];
  #pragma unroll
  for (int i = 0; i < 4; ++i) { acc[i][0] = make_float4(0,0,0,0); acc[i][1] = make_float4(0,0,0,0); }

  auto stage = [&](int buf, int d0) {
    float* xd = lds + (buf << 11);
    float* bd = lds + 4096 + (buf << 11);
    const int rsub = lane >> 4;
    const int c4   = (lane & 15) << 2;
    #pragma unroll
    for (int j = 0; j < 4; ++j) {
      const int q   = (wid << 2) + j;
      const int row = (q << 2) + rsub;
      gload16(&Xp[(long long)(d0 + row) * NN + c4], xd + (q << 8));
      gload16(&Bp[(long long)(d0 + row) * RR + c4], bd + (q << 8));
    }
  };

  stage(0, 0);
  __syncthreads();
  for (int kt = 0; kt < 16; ++kt) {
    const int cur = kt & 1;
    if (kt + 1 < 16) stage(cur ^ 1, (kt + 1) << 5);
    const float* xs = lds + (cur << 11);
    const float* bs = lds + 4096 + (cur << 11);
    #pragma unroll 8
    for (int dd = 0; dd < 32; ++dd) {
      const float4 xv  = *(const float4*)&xs[(dd << 6) + nl];
      const float4 bv0 = *(const float4*)&bs[(dd << 6) + r0];
      const float4 bv1 = *(const float4*)&bs[(dd << 6) + r0 + 4];
      fma4s(acc[0][0], bv0, xv.x); fma4s(acc[0][1], bv1, xv.x);
      fma4s(acc[1][0], bv0, xv.y); fma4s(acc[1][1], bv1, xv.y);
      fma4s(acc[2][0], bv0, xv.z); fma4s(acc[2][1], bv1, xv.z);
      fma4s(acc[3][0], bv0, xv.w); fma4s(acc[3][1], bv1, xv.w);
    }
    __syncthreads();
  }

  if constexpr (MODE == 0) {
    #pragma unroll
    for (int i = 0; i < 4; ++i) {
      float4 a0 = acc[i][0], a1 = acc[i][1];
      float m = fmaxf(fmaxf(fmaxf(a0.x, a0.y), fmaxf(a0.z, a0.w)),
                      fmaxf(fmaxf(a1.x, a1.y), fmaxf(a1.z, a1.w)));
      m = fmaxf(m, __shfl_xor(m, 1));
      m = fmaxf(m, __shfl_xor(m, 2));
      m = fmaxf(m, __shfl_xor(m, 4));
      a0.x = __expf(a0.x - m); a0.y = __expf(a0.y - m);
      a0.z = __expf(a0.z - m); a0.w = __expf(a0.w - m);
      a1.x = __expf(a1.x - m); a1.y = __expf(a1.y - m);
      a1.z = __expf(a1.z - m); a1.w = __expf(a1.w - m);
      float s = a0.x + a0.y + a0.z + a0.w + a1.x + a1.y + a1.z + a1.w;
      s += __shfl_xor(s, 1); s += __shfl_xor(s, 2); s += __shfl_xor(s, 4);
      const float inv = 1.f / s;
      a0.x *= inv; a0.y *= inv; a0.z *= inv; a0.w *= inv;
      a1.x *= inv; a1.y *= inv; a1.z *= inv; a1.w *= inv;
      float* cp = coef + ((long long)b * NN + n0 + nl + i) * RR + r0;
      *(float4*)&cp[0] = a0;
      *(float4*)&cp[4] = a1;
    }
  } else {
    float4* G4  = (float4*)lds;
    float4* CO4 = (float4*)(lds + 4096);
    #pragma unroll
    for (int j = 0; j < 8; ++j) {
      const int wi = t + (j << 7);
      float4 ssum = make_float4(0,0,0,0);
      #pragma unroll
      for (int sp = 0; sp < NS_B; ++sp)
        add4(ssum, ((const float4*)(btbp + ((long long)sp * BSZ + b) * 4096))[wi]);
      G4[wi] = ssum;
    }
    const float4* cof4 = (const float4*)(coef + ((long long)b * NN + n0) * RR);
    #pragma unroll
    for (int j = 0; j < 8; ++j) {
      const int wi = t + (j << 7);
      const int row = wi >> 4, c4 = wi & 15;
      CO4[(row << 4) + (c4 ^ ((row >> 2) & 7))] = cof4[wi];
    }
    __syncthreads();
    const int g = ngrp & 7;
    float4 dn[4][2];
    #pragma unroll
    for (int i = 0; i < 4; ++i) { dn[i][0] = make_float4(0,0,0,0); dn[i][1] = make_float4(0,0,0,0); }
    #pragma unroll 4
    for (int kq = 0; kq < 16; ++kq) {
      float4 g0[4], g1[4];
      #pragma unroll
      for (int jj = 0; jj < 4; ++jj) {
        g0[jj] = G4[(((kq << 2) + jj) << 4) + (rgrp << 1)];
        g1[jj] = G4[(((kq << 2) + jj) << 4) + (rgrp << 1) + 1];
      }
      #pragma unroll
      for (int i = 0; i < 4; ++i) {
        const float4 cv = CO4[((nl + i) << 4) + (kq ^ g)];
        fma4s(dn[i][0], g0[0], cv.x); fma4s(dn[i][1], g1[0], cv.x);
        fma4s(dn[i][0], g0[1], cv.y); fma4s(dn[i][1], g1[1], cv.y);
        fma4s(dn[i][0], g0[2], cv.z); fma4s(dn[i][1], g1[2], cv.z);
        fma4s(dn[i][0], g0[3], cv.w); fma4s(dn[i][1], g1[3], cv.w);
      }
    }
    #pragma unroll
    for (int i = 0; i < 4; ++i) {
      const int row = nl + i;
      const float4 c0 = CO4[(row << 4) + ((rgrp << 1) ^ g)];
      const float4 c1 = CO4[(row << 4) + (((rgrp << 1) + 1) ^ g)];
      float4 o0, o1;
      o0.x = c0.x * acc[i][0].x / (dn[i][0].x + EPS);
      o0.y = c0.y * acc[i][0].y / (dn[i][0].y + EPS);
      o0.z = c0.z * acc[i][0].z / (dn[i][0].z + EPS);
      o0.w = c0.w * acc[i][0].w / (dn[i][0].w + EPS);
      o1.x = c1.x * acc[i][1].x / (dn[i][1].x + EPS);
      o1.y = c1.y * acc[i][1].y / (dn[i][1].y + EPS);
      o1.z = c1.z * acc[i][1].z / (dn[i][1].z + EPS);
      o1.w = c1.w * acc[i][1].w / (dn[i][1].w + EPS);
      float* cp = coef + ((long long)b * NN + n0 + row) * RR + r0;
      *(float4*)&cp[0] = o0;
      *(float4*)&cp[4] = o1;
    }
  }
}

__global__ void __launch_bounds__(128) numer2_kernel(const float* __restrict__ X,
                                                     const float* __restrict__ coef,
                                                     float* __restrict__ n2p) {
  __shared__ float lds[8192];
  const int b    = blockIdx.z;
  const int s    = blockIdx.y;
  const int d0   = blockIdx.x << 6;
  const int t    = threadIdx.x;
  const int wid  = t >> 6;
  const int lane = t & 63;
  const int rgrp = t & 7;
  const int dgrp = t >> 3;
  const int dl   = dgrp << 2;
  const int r0   = rgrp << 3;
  const int nbeg = s * (NN / NS_N2);
  const float* Xp = X + (long long)b * DD * NN + (long long)d0 * NN;
  const float* Cp = coef + (long long)b * NN * RR;

  float4 acc[4][2];
  #pragma unroll
  for (int i = 0; i < 4; ++i) { acc[i][0] = make_float4(0,0,0,0); acc[i][1] = make_float4(0,0,0,0); }

  auto stage = [&](int buf, int nb) {
    float* xd = lds + (buf << 11);
    float* cd = lds + 4096 + (buf << 11);
    {
      const int rsub = lane >> 3, c4 = lane & 7;
      #pragma unroll
      for (int j = 0; j < 4; ++j) {
        const int q   = (wid << 2) + j;
        const int row = (q << 3) + rsub;
        const int sc  = (c4 ^ ((row >> 2) & 7)) << 2;
        gload16(&Xp[(long long)row * NN + nb + sc], xd + (q << 8));
      }
    }
    {
      const int rsub = lane >> 4, c4 = (lane & 15) << 2;
      #pragma unroll
      for (int j = 0; j < 4; ++j) {
        const int q   = (wid << 2) + j;
        const int row = (q << 2) + rsub;
        gload16(&Cp[(long long)(nb + row) * RR + c4], cd + (q << 8));
      }
    }
  };

  stage(0, nbeg);
  __syncthreads();
  const int g = dgrp & 7;
  for (int kt = 0; kt < (NN / NS_N2) / 32; ++kt) {
    const int cur = kt & 1;
    if (kt + 1 < (NN / NS_N2) / 32) stage(cur ^ 1, nbeg + ((kt + 1) << 5));
    const float* xs = lds + (cur << 11);
    const float* cs = lds + 4096 + (cur << 11);
    #pragma unroll 8
    for (int nn = 0; nn < 32; ++nn) {
      const int col = ((((nn >> 2) ^ g) << 2) + (nn & 3));
      float xe[4];
      #pragma unroll
      for (int i = 0; i < 4; ++i) xe[i] = xs[((dl + i) << 5) + col];
      const float4 cv0 = *(const float4*)&cs[(nn << 6) + r0];
      const float4 cv1 = *(const float4*)&cs[(nn << 6) + r0 + 4];
      #pragma unroll
      for (int i = 0; i < 4; ++i) {
        fma4s(acc[i][0], cv0, xe[i]);
        fma4s(acc[i][1], cv1, xe[i]);
      }
    }
    __syncthreads();
  }
  #pragma unroll
  for (int i = 0; i < 4; ++i) {
    float* op = n2p + (((long long)s * BSZ + b) * DD + d0 + dl + i) * RR + r0;
    *(float4*)&op[0] = acc[i][0];
    *(float4*)&op[4] = acc[i][1];
  }
}

__global__ void __launch_bounds__(256) bupdate_fb_kernel(float* __restrict__ Bw,
                                                         const float* __restrict__ n2p,
                                                         const float* __restrict__ ctcp,
                                                         int ns2) {
  __shared__ float ct[4096];
  const int b  = blockIdx.y;
  const int d0 = blockIdx.x << 6;
  #pragma unroll
  for (int i = 0; i < 4; ++i) {
    const int w = threadIdx.x + (i << 8);
    float4 s = make_float4(0.f, 0.f, 0.f, 0.f);
    for (int sp = 0; sp < NS_C; ++sp)
      add4(s, ((const float4*)(ctcp + ((long long)sp * BSZ + b) * 4096))[w]);
    ((float4*)ct)[w] = s;
  }
  __syncthreads();
  const int d  = d0 + (threadIdx.x >> 2);
  const int rq = (threadIdx.x & 3) << 4;

  float4 ns[4];
  #pragma unroll
  for (int j = 0; j < 4; ++j) ns[j] = make_float4(0.f, 0.f, 0.f, 0.f);
  for (int s = 0; s < ns2; ++s) {
    const float4* p = (const float4*)&n2p[(((long long)s * BSZ + b) * DD + d) * RR + rq];
    #pragma unroll
    for (int j = 0; j < 4; ++j) add4(ns[j], p[j]);
  }
  const float4* brow = (const float4*)&Bw[((long long)b * DD + d) * RR];
  float4 dn[4];
  #pragma unroll
  for (int j = 0; j < 4; ++j) dn[j] = make_float4(0.f, 0.f, 0.f, 0.f);
  for (int q = 0; q < 16; ++q) {
    const float4 b4 = brow[q];
    const float4* c0 = (const float4*)&ct[(4 * q + 0) * 64 + rq];
    const float4* c1 = (const float4*)&ct[(4 * q + 1) * 64 + rq];
    const float4* c2 = (const float4*)&ct[(4 * q + 2) * 64 + rq];
    const float4* c3 = (const float4*)&ct[(4 * q + 3) * 64 + rq];
    #pragma unroll
    for (int j = 0; j < 4; ++j) {
      fma4s(dn[j], c0[j], b4.x); fma4s(dn[j], c1[j], b4.y);
      fma4s(dn[j], c2[j], b4.z); fma4s(dn[j], c3[j], b4.w);
    }
  }
  float4* bp = (float4*)&Bw[((long long)b * DD + d) * RR + rq];
  float4 bo[4];
  #pragma unroll
  for (int j = 0; j < 4; ++j) bo[j] = bp[j];
  __syncthreads();
  #pragma unroll
  for (int j = 0; j < 4; ++j) {
    float4 o;
    o.x = bo[j].x * ns[j].x / (dn[j].x + EPS);
    o.y = bo[j].y * ns[j].y / (dn[j].y + EPS);
    o.z = bo[j].z * ns[j].z / (dn[j].z + EPS);
    o.w = bo[j].w * ns[j].w / (dn[j].w + EPS);
    bp[j] = o;
  }
}

__global__ void __launch_bounds__(256) out_kernel(const float* __restrict__ Bw,
                                                  const float* __restrict__ coef,
                                                  float* __restrict__ out) {
  __shared__ float bt [64 * 68];
  __shared__ float ctl[64 * 68];
  const int n0 = blockIdx.x << 6;
  const int d0 = blockIdx.y << 6;
  const int b  = blockIdx.z;
  const int tx = threadIdx.x & 15;
  const int ty = threadIdx.x >> 4;
  for (int t = threadIdx.x; t < 1024; t += 256) {
    const int row = t >> 4, c4 = (t & 15) << 2;
    const float4 v = *(const float4*)&Bw[((long long)b * DD + d0 + row) * RR + c4];
    bt[(c4 + 0) * 68 + row] = v.x; bt[(c4 + 1) * 68 + row] = v.y;
    bt[(c4 + 2) * 68 + row] = v.z; bt[(c4 + 3) * 68 + row] = v.w;
  }
  for (int t = threadIdx.x; t < 1024; t += 256) {
    const int row = t >> 4, c4 = (t & 15) << 2;
    const float4 v = *(const float4*)&coef[((long long)b * NN + n0 + row) * RR + c4];
    ctl[(c4 + 0) * 68 + row] = v.x; ctl[(c4 + 1) * 68 + row] = v.y;
    ctl[(c4 + 2) * 68 + row] = v.z; ctl[(c4 + 3) * 68 + row] = v.w;
  }
  __syncthreads();
  float4 ai[4];
  #pragma unroll
  for (int i = 0; i < 4; ++i) ai[i] = make_float4(0.f, 0.f, 0.f, 0.f);
  #pragma unroll 8
  for (int r = 0; r < 64; ++r) {
    const float4 bv = *(const float4*)&bt [r * 68 + (ty << 2)];
    const float4 cv = *(const float4*)&ctl[r * 68 + (tx << 2)];
    fma4s(ai[0], cv, bv.x); fma4s(ai[1], cv, bv.y);
    fma4s(ai[2], cv, bv.z); fma4s(ai[3], cv, bv.w);
  }
  #pragma unroll
  for (int i = 0; i < 4; ++i)
    *(float4*)&out[((long long)b * DD + d0 + (ty << 2) + i) * NN + n0 + (tx << 2)] = ai[i];
}

extern "C" void kernel_launch(void* const* d_in, const int* in_sizes, int n_in,
                              void* d_out, int out_size, void* d_ws, size_t ws_size,
                              hipStream_t stream) {
  const float* x        = (const float*)d_in[0];
  const float* bases_in = (const float*)d_in[1];
  float* out = (float*)d_out;
  float* ws  = (float*)d_ws;

  float* coef    = ws;                                   // 4M f32
  float* bases_w = coef + (long long)BSZ * NN * RR;      // 0.5M
  float* btbp    = bases_w + (long long)BSZ * DD * RR;   // 0.5M (fallback; fp16 path: bD16)
  float* ctcp    = btbp + (long long)NS_B * BSZ * 4096;  // 2M
  float* n2p     = ctcp + (long long)NS_C * BSZ * 4096;  // 4M
  float* ctcs    = n2p + (long long)NS_N2 * BSZ * DD * RR;   // 64K (layout keep)
  half_t* xT16   = (half_t*)(ctcs + (long long)BSZ * 4096);  // 33.5M halfs
  half_t* xd16   = xT16 + (long long)BSZ * NN * DD;          // 33.5M halfs
  half_t* BbT16  = xd16 + (long long)BSZ * NN * DD;          // 0.5M halfs
  half_t* cbT16  = BbT16 + (long long)BSZ * RR * DD;         // 4M halfs
  half_t* Gh16   = cbT16 + (long long)BSZ * RR * NN;         // 64K halfs
  const long long need = (long long)((char*)(Gh16 + (long long)BSZ * 4096) - (char*)d_ws);

  // fp16-path aliases: cN16 in n2p (dead after loop); bD16 in btbp (unused in fp16 path)
  half_t* cN16 = (half_t*)n2p;
  half_t* bD16 = (half_t*)btbp;

  const dim3 blk256(256);
  const dim3 blk128(128);

  hipMemcpyAsync(bases_w, bases_in, sizeof(float) * BSZ * DD * RR,
                 hipMemcpyDeviceToDevice, stream);

  if ((long long)ws_size >= need) {
    // ---------- fp16-MFMA path (all loop operands L3-resident) ----------
    cast16_kernel<<<dim3(16384), blk256, 0, stream>>>(x, xd16, (long long)BSZ * DD * NN);
    tcvt16_kernel<<<dim3(NN / 64, DD / 64, BSZ), blk256, 0, stream>>>(x, xT16, DD, NN);
    tcvt16_kernel<<<dim3(1, DD / 64, BSZ), blk256, 0, stream>>>(bases_w, BbT16, DD, RR);
    fused16_kernel<0><<<dim3(NN / 32, BSZ), blk128, 0, stream>>>(
        xT16, BbT16, nullptr, coef, nullptr, nullptr);

    for (int it = 0; it < STEPS; ++it) {
      btb16_kernel<<<dim3(BSZ), blk256, 0, stream>>>(BbT16, Gh16);
      fused16_kernel<1><<<dim3(NN / 32, BSZ), blk128, 0, stream>>>(
          xT16, BbT16, Gh16, coef, cbT16, nullptr);
      numer2ctc16_kernel<<<dim3(DD / 64 + 1, NS_N2, BSZ), blk128, 0, stream>>>(
          xd16, cbT16, n2p, ctcp);
      bupdate16_kernel<<<dim3(DD / 64, BSZ), blk256, 0, stream>>>(
          bases_w, n2p, ctcp, BbT16, (it == STEPS - 1) ? bD16 : nullptr);
    }
    // compute_coef: final update emits fp16 coef [n][r] directly
    btb16_kernel<<<dim3(BSZ), blk256, 0, stream>>>(BbT16, Gh16);
    fused16_kernel<2><<<dim3(NN / 32, BSZ), blk128, 0, stream>>>(
        xT16, BbT16, Gh16, coef, nullptr, cN16);
    out16_kernel<<<dim3(NN / 256, DD / 16, BSZ), blk256, 0, stream>>>(bD16, cN16, out);
  } else {
    // ---------- fp32 fallback (round-6 path) ----------
    fused_coef_kernel<0><<<dim3(NN / 64, BSZ), blk128, 0, stream>>>(x, bases_w, nullptr, coef);
    for (int it = 0; it < STEPS; ++it) {
      gram_kernel<<<dim3(NS_B, BSZ), blk256, 0, stream>>>(bases_w, btbp, DD / (NS_B * 4),
                                                          (long long)DD * RR);
      fused_coef_kernel<1><<<dim3(NN / 64, BSZ), blk128, 0, stream>>>(x, bases_w, btbp, coef);
      gram_kernel<<<dim3(NS_C, BSZ), blk256, 0, stream>>>(coef, ctcp, NN / (NS_C * 4),
                                                          (long long)NN * RR);
      numer2_kernel<<<dim3(DD / 64, NS_N2, BSZ), blk128, 0, stream>>>(x, coef, n2p);
      bupdate_fb_kernel<<<dim3(DD / 64, BSZ), blk256, 0, stream>>>(bases_w, n2p, ctcp, NS_N2);
    }
    gram_kernel<<<dim3(NS_B, BSZ), blk256, 0, stream>>>(bases_w, btbp, DD / (NS_B * 4),
                                                        (long long)DD * RR);
    fused_coef_kernel<1><<<dim3(NN / 64, BSZ), blk128, 0, stream>>>(x, bases_w, btbp, coef);
    out_kernel<<<dim3(NN / 64, DD / 64, BSZ), blk256, 0, stream>>>(bases_w, coef, out);
  }
}

// Round 13
// 880.731 us; speedup vs baseline: 2.1156x; 1.0485x over previous
//
#include <hip/hip_runtime.h>
#include <math.h>

#define EPS 1e-6f

constexpr int BSZ = 16;    // batch * S
constexpr int DD  = 512;   // channels / S
constexpr int NN  = 4096;  // H*W
constexpr int RR  = 64;
constexpr int STEPS = 7;
constexpr int NS_B  = 8;   // (fallback) BtB d-split blocks
constexpr int NS_C  = 32;  // (fallback) CtC partial slots
constexpr int NS_N2 = 8;   // numer2 / CtC n-split partials

typedef _Float16 half_t;
typedef __attribute__((ext_vector_type(8))) _Float16 half8;
typedef __attribute__((ext_vector_type(4))) _Float16 half4v;
typedef __attribute__((ext_vector_type(4))) float f32x4;

__device__ __forceinline__ void fma4s(float4& a, const float4& b, float s) {
  a.x = fmaf(b.x, s, a.x); a.y = fmaf(b.y, s, a.y);
  a.z = fmaf(b.z, s, a.z); a.w = fmaf(b.w, s, a.w);
}
__device__ __forceinline__ void add4(float4& a, const float4& b) {
  a.x += b.x; a.y += b.y; a.z += b.z; a.w += b.w;
}
__device__ __forceinline__ f32x4 mfmah(half8 a, half8 b, f32x4 c) {
  return __builtin_amdgcn_mfma_f32_16x16x32_f16(a, b, c, 0, 0, 0);
}

// async global->LDS, 16B per lane (fp32 fallback path)
__device__ __forceinline__ void gload16(const float* g, float* l) {
  __builtin_amdgcn_global_load_lds(
      (const __attribute__((address_space(1))) void*)g,
      (__attribute__((address_space(3))) void*)l, 16, 0, 0);
}

// ================= x -> fp16 straight (xd) AND transposed (xT) in one pass
__global__ void __launch_bounds__(256) xcvt16_kernel(const float* __restrict__ src,
                                                     half_t* __restrict__ xd,
                                                     half_t* __restrict__ xT) {
  __shared__ float tileT[64 * 65];   // [n_local][d_local]
  const int b = blockIdx.z, c0 = blockIdx.x << 6, r0 = blockIdx.y << 6;  // c=n, r=d
  const float* sp = src + (long long)b * DD * NN;
  const int t = threadIdx.x;
  #pragma unroll
  for (int i = 0; i < 4; ++i) {
    const int idx = t + (i << 8);
    const int row = idx >> 4, c4 = (idx & 15) << 2;
    const float4 v = *(const float4*)&sp[(long long)(r0 + row) * NN + c0 + c4];
    // straight fp16 write [d][n]
    half4v h;
    h[0] = (half_t)v.x; h[1] = (half_t)v.y; h[2] = (half_t)v.z; h[3] = (half_t)v.w;
    *(half4v*)&xd[((long long)b * DD + r0 + row) * NN + c0 + c4] = h;
    // transposed staging
    tileT[(c4 + 0) * 65 + row] = v.x;
    tileT[(c4 + 1) * 65 + row] = v.y;
    tileT[(c4 + 2) * 65 + row] = v.z;
    tileT[(c4 + 3) * 65 + row] = v.w;
  }
  __syncthreads();
  const int orow = t >> 2, och = (t & 3) << 4;
  half8 h0, h1;
  #pragma unroll
  for (int j = 0; j < 8; ++j) h0[j] = (half_t)tileT[orow * 65 + och + j];
  #pragma unroll
  for (int j = 0; j < 8; ++j) h1[j] = (half_t)tileT[orow * 65 + och + 8 + j];
  const long long ob = ((long long)b * NN + c0 + orow) * DD + r0 + och;
  *(half8*)&xT[ob] = h0;
  *(half8*)&xT[ob + 8] = h1;
}

// ================= transpose + fp32->fp16 (bases prologue): [b][R][C] -> [b][C][R]
__global__ void __launch_bounds__(256) tcvt16_kernel(const float* __restrict__ src,
                                                     half_t* __restrict__ dh,
                                                     int R, int C) {
  __shared__ float tileT[64 * 65];
  const int b = blockIdx.z, c0 = blockIdx.x << 6, r0 = blockIdx.y << 6;
  const float* sp = src + (long long)b * R * C;
  const int t = threadIdx.x;
  #pragma unroll
  for (int i = 0; i < 4; ++i) {
    const int idx = t + (i << 8);
    const int row = idx >> 4, c4 = (idx & 15) << 2;
    const float4 v = *(const float4*)&sp[(long long)(r0 + row) * C + c0 + c4];
    tileT[(c4 + 0) * 65 + row] = v.x;
    tileT[(c4 + 1) * 65 + row] = v.y;
    tileT[(c4 + 2) * 65 + row] = v.z;
    tileT[(c4 + 3) * 65 + row] = v.w;
  }
  __syncthreads();
  const int orow = t >> 2, och = (t & 3) << 4;
  half8 h0, h1;
  #pragma unroll
  for (int j = 0; j < 8; ++j) h0[j] = (half_t)tileT[orow * 65 + och + j];
  #pragma unroll
  for (int j = 0; j < 8; ++j) h1[j] = (half_t)tileT[orow * 65 + och + 8 + j];
  const long long ob = ((long long)b * C + c0 + orow) * R + r0 + och;
  *(half8*)&dh[ob] = h0;
  *(half8*)&dh[ob + 8] = h1;
}

// ================= prologue: Gf (fp32) = B~^T B~ via fp16 MFMA, one block/batch
__global__ void __launch_bounds__(256) btb16_kernel(const half_t* __restrict__ BT,
                                                    float* __restrict__ Gf) {
  __shared__ float red[64 * 64];
  const int b = blockIdx.x;
  const int t = threadIdx.x;
  const int w = t >> 6;
  const int l = t & 63;
  const int row16 = l & 15;
  const int koff  = (l >> 4) << 3;

  const half_t* ap = BT + ((long long)b * RR + row16) * DD + (w << 7) + koff;

  f32x4 acc[4][4];
  #pragma unroll
  for (int i = 0; i < 4; ++i)
    #pragma unroll
    for (int j = 0; j < 4; ++j) acc[i][j] = (f32x4){0.f, 0.f, 0.f, 0.f};

  #pragma unroll
  for (int kt = 0; kt < 4; ++kt) {
    const int ko = kt << 5;
    half8 af[4];
    #pragma unroll
    for (int rs = 0; rs < 4; ++rs) af[rs] = *(const half8*)&ap[(long long)rs * 16 * DD + ko];
    #pragma unroll
    for (int r1 = 0; r1 < 4; ++r1)
      #pragma unroll
      for (int r2 = 0; r2 < 4; ++r2)
        acc[r1][r2] = mfmah(af[r1], af[r2], acc[r1][r2]);
  }
  for (int ww = 0; ww < 4; ++ww) {
    if (w == ww) {
      #pragma unroll
      for (int r1 = 0; r1 < 4; ++r1)
        #pragma unroll
        for (int r2 = 0; r2 < 4; ++r2)
          #pragma unroll
          for (int j = 0; j < 4; ++j) {
            const int row = (r1 << 4) + ((l >> 4) << 2) + j;
            const int col = (r2 << 4) + row16;
            if (ww == 0) red[row * 64 + col] = acc[r1][r2][j];
            else         red[row * 64 + col] += acc[r1][r2][j];
          }
    }
    __syncthreads();
  }
  float* op = Gf + (long long)b * 4096;
  for (int i = t; i < 1024; i += 256) ((float4*)op)[i] = ((const float4*)red)[i];
}

// ================= fp16-MFMA fused numer + {softmax | coef update}
// G read as fp32 (Gf), converted per-thread.
template <int MODE>
__global__ void __launch_bounds__(128) fused16_kernel(const half_t* __restrict__ xT,
                                                      const half_t* __restrict__ BT,
                                                      const float* __restrict__ Gf,
                                                      float* __restrict__ coef,
                                                      half_t* __restrict__ cbT,
                                                      half_t* __restrict__ cN) {
  __shared__ half_t ctile[(MODE == 1) ? 64 * 40 : 8];
  const int b  = blockIdx.y;
  const int n0 = blockIdx.x << 5;
  const int t  = threadIdx.x;
  const int w  = t >> 6;
  const int l  = t & 63;
  const int row16 = l & 15;
  const int koff  = (l >> 4) << 3;
  const int nrb   = n0 + (w << 4);

  const half_t* ap = xT + ((long long)b * NN + nrb + row16) * DD + koff;
  const half_t* bp = BT + ((long long)b * RR + row16) * DD + koff;

  f32x4 acc[4];
  #pragma unroll
  for (int rs = 0; rs < 4; ++rs) acc[rs] = (f32x4){0.f, 0.f, 0.f, 0.f};

  #pragma unroll
  for (int kt = 0; kt < 16; ++kt) {
    const int ko = kt << 5;
    const half8 av = *(const half8*)&ap[ko];
    #pragma unroll
    for (int rs = 0; rs < 4; ++rs) {
      const half8 bv = *(const half8*)&bp[rs * 16 * DD + ko];
      acc[rs] = mfmah(av, bv, acc[rs]);
    }
  }

  if constexpr (MODE == 0) {
    #pragma unroll
    for (int j = 0; j < 4; ++j) {
      float m = fmaxf(fmaxf(acc[0][j], acc[1][j]), fmaxf(acc[2][j], acc[3][j]));
      m = fmaxf(m, __shfl_xor(m, 1));
      m = fmaxf(m, __shfl_xor(m, 2));
      m = fmaxf(m, __shfl_xor(m, 4));
      m = fmaxf(m, __shfl_xor(m, 8));
      float s = 0.f;
      #pragma unroll
      for (int rs = 0; rs < 4; ++rs) { acc[rs][j] = __expf(acc[rs][j] - m); s += acc[rs][j]; }
      s += __shfl_xor(s, 1); s += __shfl_xor(s, 2);
      s += __shfl_xor(s, 4); s += __shfl_xor(s, 8);
      const float inv = 1.f / s;
      #pragma unroll
      for (int rs = 0; rs < 4; ++rs) acc[rs][j] *= inv;
    }
    #pragma unroll
    for (int rs = 0; rs < 4; ++rs)
      #pragma unroll
      for (int j = 0; j < 4; ++j)
        coef[((long long)b * NN + nrb + ((l >> 4) << 2) + j) * RR + (rs << 4) + row16] = acc[rs][j];
  } else {
    // denom = cold @ G via fp16 MFMA (G symmetric; rows read fp32, cvt in-thread)
    const float* crow = coef + ((long long)b * NN + nrb + row16) * RR;
    const float* gfb  = Gf + (long long)b * 4096;
    f32x4 dn[4];
    #pragma unroll
    for (int rs = 0; rs < 4; ++rs) dn[rs] = (f32x4){0.f, 0.f, 0.f, 0.f};
    #pragma unroll
    for (int kt = 0; kt < 2; ++kt) {
      const int ko = (kt << 5) + koff;
      const float4 c0 = *(const float4*)&crow[ko];
      const float4 c1 = *(const float4*)&crow[ko + 4];
      half8 ch;
      ch[0] = (half_t)c0.x; ch[1] = (half_t)c0.y; ch[2] = (half_t)c0.z; ch[3] = (half_t)c0.w;
      ch[4] = (half_t)c1.x; ch[5] = (half_t)c1.y; ch[6] = (half_t)c1.z; ch[7] = (half_t)c1.w;
      #pragma unroll
      for (int rs = 0; rs < 4; ++rs) {
        const float4 g0 = *(const float4*)&gfb[((rs << 4) + row16) * 64 + ko];
        const float4 g1 = *(const float4*)&gfb[((rs << 4) + row16) * 64 + ko + 4];
        half8 gh;
        gh[0] = (half_t)g0.x; gh[1] = (half_t)g0.y; gh[2] = (half_t)g0.z; gh[3] = (half_t)g0.w;
        gh[4] = (half_t)g1.x; gh[5] = (half_t)g1.y; gh[6] = (half_t)g1.z; gh[7] = (half_t)g1.w;
        dn[rs] = mfmah(ch, gh, dn[rs]);
      }
    }
    // multiplicative update (element-owner unique in D-frag positions)
    #pragma unroll
    for (int rs = 0; rs < 4; ++rs)
      #pragma unroll
      for (int j = 0; j < 4; ++j) {
        const int r = (rs << 4) + row16;
        const int nl = ((w << 4) + ((l >> 4) << 2) + j);   // n - n0
        const long long idx = ((long long)b * NN + n0 + nl) * RR + r;
        const float co = coef[idx];
        const float v  = co * acc[rs][j] / (dn[rs][j] + EPS);
        if constexpr (MODE == 1) {
          coef[idx] = v;
          ctile[r * 40 + nl] = (half_t)v;
        } else {
          cN[idx] = (half_t)v;
        }
      }
    if constexpr (MODE == 1) {
      __syncthreads();
      if (t < 64) {   // row r = t: write 32 contiguous fp16 (64 B) to cbT
        half_t* dst = cbT + ((long long)b * RR + t) * NN + n0;
        *(half8*)&dst[0]  = *(const half8*)&ctile[t * 40 + 0];
        *(half8*)&dst[8]  = *(const half8*)&ctile[t * 40 + 8];
        *(half8*)&dst[16] = *(const half8*)&ctile[t * 40 + 16];
        *(half8*)&dst[24] = *(const half8*)&ctile[t * 40 + 24];
      }
    }
  }
}

// ================= merged numer2 partials + CtC partials (+ Gf zeroing for
// this iteration's bupdate accumulation).
// grid (DD/64 + 1, NS_N2, BSZ). blockIdx.x == DD/64: CtC path + Gf zero.
__global__ void __launch_bounds__(128) numer2ctc16_kernel(const half_t* __restrict__ xh,
                                                          const half_t* __restrict__ cbT,
                                                          float* __restrict__ n2p,
                                                          float* __restrict__ ctcp,
                                                          float* __restrict__ Gf) {
  __shared__ float red[4096];
  const int b = blockIdx.z;
  const int s = blockIdx.y;
  const int t = threadIdx.x;
  const int w = t >> 6;
  const int l = t & 63;
  const int row16 = l & 15;
  const int koff  = (l >> 4) << 3;
  const int nbeg  = s * (NN / NS_N2);

  if (blockIdx.x == DD / 64) {
    // zero this slice's chunk of Gf (consumed+refilled by bupdate next)
    ((float4*)(Gf + (long long)b * 4096 + (s << 9)))[t] = make_float4(0.f, 0.f, 0.f, 0.f);
    const half_t* ap = cbT + ((long long)b * RR + row16) * NN + nbeg + (w << 8) + koff;
    f32x4 acc[4][4];
    #pragma unroll
    for (int i = 0; i < 4; ++i)
      #pragma unroll
      for (int j = 0; j < 4; ++j) acc[i][j] = (f32x4){0.f, 0.f, 0.f, 0.f};
    #pragma unroll
    for (int kt = 0; kt < 8; ++kt) {
      const int ko = kt << 5;
      half8 af[4];
      #pragma unroll
      for (int rs = 0; rs < 4; ++rs) af[rs] = *(const half8*)&ap[(long long)rs * 16 * NN + ko];
      #pragma unroll
      for (int r1 = 0; r1 < 4; ++r1)
        #pragma unroll
        for (int r2 = 0; r2 < 4; ++r2)
          acc[r1][r2] = mfmah(af[r1], af[r2], acc[r1][r2]);
    }
    if (w == 0) {
      #pragma unroll
      for (int r1 = 0; r1 < 4; ++r1)
        #pragma unroll
        for (int r2 = 0; r2 < 4; ++r2)
          #pragma unroll
          for (int j = 0; j < 4; ++j)
            red[((r1 << 4) + ((l >> 4) << 2) + j) * 64 + (r2 << 4) + row16] = acc[r1][r2][j];
    }
    __syncthreads();
    if (w == 1) {
      #pragma unroll
      for (int r1 = 0; r1 < 4; ++r1)
        #pragma unroll
        for (int r2 = 0; r2 < 4; ++r2)
          #pragma unroll
          for (int j = 0; j < 4; ++j)
            red[((r1 << 4) + ((l >> 4) << 2) + j) * 64 + (r2 << 4) + row16] += acc[r1][r2][j];
    }
    __syncthreads();
    float* op = ctcp + ((long long)s * BSZ + b) * 4096;
    for (int i = t; i < 1024; i += 128) ((float4*)op)[i] = ((const float4*)red)[i];
    return;
  }

  const int d0 = blockIdx.x << 6;
  const half_t* ap = xh + ((long long)b * DD + d0 + w * 32 + row16) * NN + nbeg + koff;
  const half_t* cp = cbT + ((long long)b * RR + row16) * NN + nbeg + koff;

  f32x4 acc[2][4];
  #pragma unroll
  for (int ds = 0; ds < 2; ++ds)
    #pragma unroll
    for (int rs = 0; rs < 4; ++rs) acc[ds][rs] = (f32x4){0.f, 0.f, 0.f, 0.f};

  #pragma unroll
  for (int kt = 0; kt < 16; ++kt) {
    const int ko = kt << 5;
    half8 av[2], bf[4];
    #pragma unroll
    for (int ds = 0; ds < 2; ++ds) av[ds] = *(const half8*)&ap[(long long)ds * 16 * NN + ko];
    #pragma unroll
    for (int rs = 0; rs < 4; ++rs) bf[rs] = *(const half8*)&cp[(long long)rs * 16 * NN + ko];
    #pragma unroll
    for (int ds = 0; ds < 2; ++ds)
      #pragma unroll
      for (int rs = 0; rs < 4; ++rs)
        acc[ds][rs] = mfmah(av[ds], bf[rs], acc[ds][rs]);
  }
  float* op = n2p + (((long long)s * BSZ + b) * DD + d0 + w * 32) * RR;
  #pragma unroll
  for (int ds = 0; ds < 2; ++ds)
    #pragma unroll
    for (int rs = 0; rs < 4; ++rs)
      #pragma unroll
      for (int j = 0; j < 4; ++j)
        op[(long long)(ds * 16 + ((l >> 4) << 2) + j) * RR + (rs << 4) + row16] = acc[ds][rs][j];
}

// ================= bases update; emits BbT16, partial new-bases gram into Gf
// (fp32 atomics, zeroed by numer2ctc), and optionally bD16 (last iteration).
__global__ void __launch_bounds__(256) bupdate16_kernel(float* __restrict__ Bw,
                                                        const float* __restrict__ n2p,
                                                        const float* __restrict__ ctcp,
                                                        half_t* __restrict__ BbT,
                                                        float* __restrict__ Gf,
                                                        half_t* __restrict__ bD) {
  __shared__ __align__(16) float ct[4096];
  const int b  = blockIdx.y;
  const int d0 = blockIdx.x << 6;
  const int t  = threadIdx.x;
  #pragma unroll
  for (int i = 0; i < 4; ++i) {
    const int w = t + (i << 8);
    float4 s4 = make_float4(0.f, 0.f, 0.f, 0.f);
    #pragma unroll
    for (int sp = 0; sp < NS_N2; ++sp)
      add4(s4, ((const float4*)(ctcp + ((long long)sp * BSZ + b) * 4096))[w]);
    ((float4*)ct)[w] = s4;
  }
  __syncthreads();
  const int dl = t >> 2;
  const int d  = d0 + dl;
  const int rq = (t & 3) << 4;

  float4 ns[4];
  #pragma unroll
  for (int j = 0; j < 4; ++j) ns[j] = make_float4(0.f, 0.f, 0.f, 0.f);
  for (int s = 0; s < NS_N2; ++s) {
    const float4* p = (const float4*)&n2p[(((long long)s * BSZ + b) * DD + d) * RR + rq];
    #pragma unroll
    for (int j = 0; j < 4; ++j) add4(ns[j], p[j]);
  }
  const float4* brow = (const float4*)&Bw[((long long)b * DD + d) * RR];
  float4 dn[4];
  #pragma unroll
  for (int j = 0; j < 4; ++j) dn[j] = make_float4(0.f, 0.f, 0.f, 0.f);
  for (int q = 0; q < 16; ++q) {
    const float4 b4 = brow[q];
    const float4* c0 = (const float4*)&ct[(4 * q + 0) * 64 + rq];
    const float4* c1 = (const float4*)&ct[(4 * q + 1) * 64 + rq];
    const float4* c2 = (const float4*)&ct[(4 * q + 2) * 64 + rq];
    const float4* c3 = (const float4*)&ct[(4 * q + 3) * 64 + rq];
    #pragma unroll
    for (int j = 0; j < 4; ++j) {
      fma4s(dn[j], c0[j], b4.x); fma4s(dn[j], c1[j], b4.y);
      fma4s(dn[j], c2[j], b4.z); fma4s(dn[j], c3[j], b4.w);
    }
  }
  float4* bp = (float4*)&Bw[((long long)b * DD + d) * RR + rq];
  float4 bo[4];
  #pragma unroll
  for (int j = 0; j < 4; ++j) bo[j] = bp[j];
  __syncthreads();   // all ct / Bw reads complete (block-wide)
  half_t* tile = (half_t*)ct;   // reuse: [r][dlocal] fp16, stride 72 (9216 B)
  float4 ov[4];
  #pragma unroll
  for (int j = 0; j < 4; ++j) {
    ov[j].x = bo[j].x * ns[j].x / (dn[j].x + EPS);
    ov[j].y = bo[j].y * ns[j].y / (dn[j].y + EPS);
    ov[j].z = bo[j].z * ns[j].z / (dn[j].z + EPS);
    ov[j].w = bo[j].w * ns[j].w / (dn[j].w + EPS);
    bp[j] = ov[j];
    tile[(rq + (j << 2) + 0) * 72 + dl] = (half_t)ov[j].x;
    tile[(rq + (j << 2) + 1) * 72 + dl] = (half_t)ov[j].y;
    tile[(rq + (j << 2) + 2) * 72 + dl] = (half_t)ov[j].z;
    tile[(rq + (j << 2) + 3) * 72 + dl] = (half_t)ov[j].w;
  }
  if (bD) {
    half_t* dst = bD + ((long long)b * DD + d) * RR + rq;
    half8 h0, h1;
    h0[0] = (half_t)ov[0].x; h0[1] = (half_t)ov[0].y; h0[2] = (half_t)ov[0].z; h0[3] = (half_t)ov[0].w;
    h0[4] = (half_t)ov[1].x; h0[5] = (half_t)ov[1].y; h0[6] = (half_t)ov[1].z; h0[7] = (half_t)ov[1].w;
    h1[0] = (half_t)ov[2].x; h1[1] = (half_t)ov[2].y; h1[2] = (half_t)ov[2].z; h1[3] = (half_t)ov[2].w;
    h1[4] = (half_t)ov[3].x; h1[5] = (half_t)ov[3].y; h1[6] = (half_t)ov[3].z; h1[7] = (half_t)ov[3].w;
    *(half8*)&dst[0] = h0;
    *(half8*)&dst[8] = h1;
  }
  __syncthreads();   // tile complete
  // ---- partial gram of NEW bases: Gpart[r1][r2] += sum_dl tile[r1][.]*tile[r2][.]
  {
    const int wv = t >> 6;          // r1 quarter
    const int l  = t & 63;
    const int row16 = l & 15;
    const int koff2 = (l >> 4) << 3;
    const half_t* a1 = tile + ((wv << 4) + row16) * 72 + koff2;
    f32x4 g[4];
    #pragma unroll
    for (int rs = 0; rs < 4; ++rs) g[rs] = (f32x4){0.f, 0.f, 0.f, 0.f};
    #pragma unroll
    for (int kt = 0; kt < 2; ++kt) {
      const int ko = kt << 5;
      const half8 av = *(const half8*)&a1[ko];
      #pragma unroll
      for (int rs = 0; rs < 4; ++rs) {
        const half8 bv = *(const half8*)&tile[((rs << 4) + row16) * 72 + koff2 + ko];
        g[rs] = mfmah(av, bv, g[rs]);
      }
    }
    float* gfb = Gf + (long long)b * 4096;
    #pragma unroll
    for (int rs = 0; rs < 4; ++rs)
      #pragma unroll
      for (int j = 0; j < 4; ++j)
        atomicAdd(&gfb[((wv << 4) + ((l >> 4) << 2) + j) * 64 + (rs << 4) + row16], g[rs][j]);
  }
  // ---- BbT emission (transposed fp16)
  const int r = t >> 2, qc = t & 3;
  half_t* dstT = BbT + ((long long)b * RR + r) * DD + d0 + (qc << 4);
  *(half8*)&dstT[0] = *(const half8*)&tile[r * 72 + (qc << 4)];
  *(half8*)&dstT[8] = *(const half8*)&tile[r * 72 + (qc << 4) + 8];
}

// ================= out via fp16 MFMA, 16d x 256n tiles -> 1KB row stores
__global__ void __launch_bounds__(256) out16_kernel(const half_t* __restrict__ bD,
                                                    const half_t* __restrict__ cN,
                                                    float* __restrict__ out) {
  __shared__ float ot[16 * 264];
  const int n0 = blockIdx.x << 8;
  const int d0 = blockIdx.y << 4;
  const int b  = blockIdx.z;
  const int t  = threadIdx.x;
  const int w  = t >> 6;
  const int l  = t & 63;
  const int row16 = l & 15;
  const int koff  = (l >> 4) << 3;

  const half_t* ap = bD + ((long long)b * DD + d0 + row16) * RR + koff;
  const half_t* bp = cN + ((long long)b * NN + n0 + (w << 6) + row16) * RR + koff;

  f32x4 acc[4];
  #pragma unroll
  for (int ns = 0; ns < 4; ++ns) acc[ns] = (f32x4){0.f, 0.f, 0.f, 0.f};

  #pragma unroll
  for (int kt = 0; kt < 2; ++kt) {
    const int ko = kt << 5;
    const half8 av = *(const half8*)&ap[ko];
    #pragma unroll
    for (int ns = 0; ns < 4; ++ns) {
      const half8 bv = *(const half8*)&bp[(long long)ns * 16 * RR + ko];
      acc[ns] = mfmah(av, bv, acc[ns]);
    }
  }
  #pragma unroll
  for (int ns = 0; ns < 4; ++ns)
    #pragma unroll
    for (int j = 0; j < 4; ++j)
      ot[(((l >> 4) << 2) + j) * 264 + (w << 6) + (ns << 4) + row16] = acc[ns][j];
  __syncthreads();
  #pragma unroll
  for (int k = 0; k < 4; ++k) {
    const int idx = t + (k << 8);
    const int row = idx >> 6, c4 = (idx & 63) << 2;
    const float4 v = *(const float4*)&ot[row * 264 + c4];
    *(float4*)&out[((long long)b * DD + d0 + row) * NN + n0 + c4] = v;
  }
}

// ================= fp32 fallback kernels (round-6 path) =================

__global__ void __launch_bounds__(256) gram_kernel(const float* __restrict__ M,
                                                   float* __restrict__ outp,
                                                   int rowsPerWave,
                                                   long long batchStride) {
  __shared__ float red[RR * RR];
  const int lane = threadIdx.x & 63;
  const int wid  = threadIdx.x >> 6;
  const int b    = blockIdx.y;
  const long long rowbase = (long long)(blockIdx.x * 4 + wid) * rowsPerWave;
  const float* Mp = M + (long long)b * batchStride + rowbase * RR;
  float acc[RR];
  #pragma unroll
  for (int k = 0; k < RR; ++k) acc[k] = 0.f;
  #pragma unroll 2
  for (int rr = 0; rr < rowsPerWave; ++rr) {
    const float v = Mp[(long long)rr * RR + lane];
    #pragma unroll
    for (int k = 0; k < RR; ++k) acc[k] = fmaf(__shfl(v, k), v, acc[k]);
  }
  for (int w = 0; w < 4; ++w) {
    if (wid == w) {
      if (w == 0) {
        #pragma unroll
        for (int k = 0; k < RR; ++k) red[k * RR + lane] = acc[k];
      } else {
        #pragma unroll
        for (int k = 0; k < RR; ++k) red[k * RR + lane] += acc[k];
      }
    }
    __syncthreads();
  }
  float* op = outp + ((long long)blockIdx.x * BSZ + b) * (RR * RR);
  for (int i = threadIdx.x; i < RR * RR; i += 256) op[i] = red[i];
}

template <int MODE>
__global__ void __launch_bounds__(128) fused_coef_kernel(const float* __restrict__ X,
                                                         const float* __restrict__ Bw,
                                                         const float* __restrict__ btbp,
                                                         float* __restrict__ coef) {
  __shared__ float lds[8192];
  const int b    = blockIdx.y;
  const int n0   = blockIdx.x << 6;
  const int t    = threadIdx.x;
  const int wid  = t >> 6;
  const int lane = t & 63;
  const int rgrp = t & 7;
  const int ngrp = t >> 3;
  const int nl   = ngrp << 2;
  const int r0   = rgrp << 3;
  const float* Xp = X  + (long long)b * DD * NN + n0;
  const float* Bp = Bw + (long long)b * DD * RR;

  float4 acc[4][2];
  #pragma unroll
  for (int i = 0; i < 4; ++i) { acc[i][0] = make_float4(0,0,0,0); acc[i][1] = make_float4(0,0,0,0); }

  auto stage = [&](int buf, int d0) {
    float* xd = lds + (buf << 11);
    float* bd = lds + 4096 + (buf << 11);
    const int rsub = lane >> 4;
    const int c4   = (lane & 15) << 2;
    #pragma unroll
    for (int j = 0; j < 4; ++j) {
      const int q   = (wid << 2) + j;
      const int row = (q << 2) + rsub;
      gload16(&Xp[(long long)(d0 + row) * NN + c4], xd + (q << 8));
      gload16(&Bp[(long long)(d0 + row) * RR + c4], bd + (q << 8));
    }
  };

  stage(0, 0);
  __syncthreads();
  for (int kt = 0; kt < 16; ++kt) {
    const int cur = kt & 1;
    if (kt + 1 < 16) stage(cur ^ 1, (kt + 1) << 5);
    const float* xs = lds + (cur << 11);
    const float* bs = lds + 4096 + (cur << 11);
    #pragma unroll 8
    for (int dd = 0; dd < 32; ++dd) {
      const float4 xv  = *(const float4*)&xs[(dd << 6) + nl];
      const float4 bv0 = *(const float4*)&bs[(dd << 6) + r0];
      const float4 bv1 = *(const float4*)&bs[(dd << 6) + r0 + 4];
      fma4s(acc[0][0], bv0, xv.x); fma4s(acc[0][1], bv1, xv.x);
      fma4s(acc[1][0], bv0, xv.y); fma4s(acc[1][1], bv1, xv.y);
      fma4s(acc[2][0], bv0, xv.z); fma4s(acc[2][1], bv1, xv.z);
      fma4s(acc[3][0], bv0, xv.w); fma4s(acc[3][1], bv1, xv.w);
    }
    __syncthreads();
  }

  if constexpr (MODE == 0) {
    #pragma unroll
    for (int i = 0; i < 4; ++i) {
      float4 a0 = acc[i][0], a1 = acc[i][1];
      float m = fmaxf(fmaxf(fmaxf(a0.x, a0.y), fmaxf(a0.z, a0.w)),
                      fmaxf(fmaxf(a1.x, a1.y), fmaxf(a1.z, a1.w)));
      m = fmaxf(m, __shfl_xor(m, 1));
      m = fmaxf(m, __shfl_xor(m, 2));
      m = fmaxf(m, __shfl_xor(m, 4));
      a0.x = __expf(a0.x - m); a0.y = __expf(a0.y - m);
      a0.z = __expf(a0.z - m); a0.w = __expf(a0.w - m);
      a1.x = __expf(a1.x - m); a1.y = __expf(a1.y - m);
      a1.z = __expf(a1.z - m); a1.w = __expf(a1.w - m);
      float s = a0.x + a0.y + a0.z + a0.w + a1.x + a1.y + a1.z + a1.w;
      s += __shfl_xor(s, 1); s += __shfl_xor(s, 2); s += __shfl_xor(s, 4);
      const float inv = 1.f / s;
      a0.x *= inv; a0.y *= inv; a0.z *= inv; a0.w *= inv;
      a1.x *= inv; a1.y *= inv; a1.z *= inv; a1.w *= inv;
      float* cp = coef + ((long long)b * NN + n0 + nl + i) * RR + r0;
      *(float4*)&cp[0] = a0;
      *(float4*)&cp[4] = a1;
    }
  } else {
    float4* G4  = (float4*)lds;
    float4* CO4 = (float4*)(lds + 4096);
    #pragma unroll
    for (int j = 0; j < 8; ++j) {
      const int wi = t + (j << 7);
      float4 ssum = make_float4(0,0,0,0);
      #pragma unroll
      for (int sp = 0; sp < NS_B; ++sp)
        add4(ssum, ((const float4*)(btbp + ((long long)sp * BSZ + b) * 4096))[wi]);
      G4[wi] = ssum;
    }
    const float4* cof4 = (const float4*)(coef + ((long long)b * NN + n0) * RR);
    #pragma unroll
    for (int j = 0; j < 8; ++j) {
      const int wi = t + (j << 7);
      const int row = wi >> 4, c4 = wi & 15;
      CO4[(row << 4) + (c4 ^ ((row >> 2) & 7))] = cof4[wi];
    }
    __syncthreads();
    const int g = ngrp & 7;
    float4 dn[4][2];
    #pragma unroll
    for (int i = 0; i < 4; ++i) { dn[i][0] = make_float4(0,0,0,0); dn[i][1] = make_float4(0,0,0,0); }
    #pragma unroll 4
    for (int kq = 0; kq < 16; ++kq) {
      float4 g0[4], g1[4];
      #pragma unroll
      for (int jj = 0; jj < 4; ++jj) {
        g0[jj] = G4[(((kq << 2) + jj) << 4) + (rgrp << 1)];
        g1[jj] = G4[(((kq << 2) + jj) << 4) + (rgrp << 1) + 1];
      }
      #pragma unroll
      for (int i = 0; i < 4; ++i) {
        const float4 cv = CO4[((nl + i) << 4) + (kq ^ g)];
        fma4s(dn[i][0], g0[0], cv.x); fma4s(dn[i][1], g1[0], cv.x);
        fma4s(dn[i][0], g0[1], cv.y); fma4s(dn[i][1], g1[1], cv.y);
        fma4s(dn[i][0], g0[2], cv.z); fma4s(dn[i][1], g1[2], cv.z);
        fma4s(dn[i][0], g0[3], cv.w); fma4s(dn[i][1], g1[3], cv.w);
      }
    }
    #pragma unroll
    for (int i = 0; i < 4; ++i) {
      const int row = nl + i;
      const float4 c0 = CO4[(row << 4) + ((rgrp << 1) ^ g)];
      const float4 c1 = CO4[(row << 4) + (((rgrp << 1) + 1) ^ g)];
      float4 o0, o1;
      o0.x = c0.x * acc[i][0].x / (dn[i][0].x + EPS);
      o0.y = c0.y * acc[i][0].y / (dn[i][0].y + EPS);
      o0.z = c0.z * acc[i][0].z / (dn[i][0].z + EPS);
      o0.w = c0.w * acc[i][0].w / (dn[i][0].w + EPS);
      o1.x = c1.x * acc[i][1].x / (dn[i][1].x + EPS);
      o1.y = c1.y * acc[i][1].y / (dn[i][1].y + EPS);
      o1.z = c1.z * acc[i][1].z / (dn[i][1].z + EPS);
      o1.w = c1.w * acc[i][1].w / (dn[i][1].w + EPS);
      float* cp = coef + ((long long)b * NN + n0 + row) * RR + r0;
      *(float4*)&cp[0] = o0;
      *(float4*)&cp[4] = o1;
    }
  }
}

__global__ void __launch_bounds__(128) numer2_kernel(const float* __restrict__ X,
                                                     const float* __restrict__ coef,
                                                     float* __restrict__ n2p) {
  __shared__ float lds[8192];
  const int b    = blockIdx.z;
  const int s    = blockIdx.y;
  const int d0   = blockIdx.x << 6;
  const int t    = threadIdx.x;
  const int wid  = t >> 6;
  const int lane = t & 63;
  const int rgrp = t & 7;
  const int dgrp = t >> 3;
  const int dl   = dgrp << 2;
  const int r0   = rgrp << 3;
  const int nbeg = s * (NN / NS_N2);
  const float* Xp = X + (long long)b * DD * NN + (long long)d0 * NN;
  const float* Cp = coef + (long long)b * NN * RR;

  float4 acc[4][2];
  #pragma unroll
  for (int i = 0; i < 4; ++i) { acc[i][0] = make_float4(0,0,0,0); acc[i][1] = make_float4(0,0,0,0); }

  auto stage = [&](int buf, int nb) {
    float* xd = lds + (buf << 11);
    float* cd = lds + 4096 + (buf << 11);
    {
      const int rsub = lane >> 3, c4 = lane & 7;
      #pragma unroll
      for (int j = 0; j < 4; ++j) {
        const int q   = (wid << 2) + j;
        const int row = (q << 3) + rsub;
        const int sc  = (c4 ^ ((row >> 2) & 7)) << 2;
        gload16(&Xp[(long long)row * NN + nb + sc], xd + (q << 8));
      }
    }
    {
      const int rsub = lane >> 4, c4 = (lane & 15) << 2;
      #pragma unroll
      for (int j = 0; j < 4; ++j) {
        const int q   = (wid << 2) + j;
        const int row = (q << 2) + rsub;
        gload16(&Cp[(long long)(nb + row) * RR + c4], cd + (q << 8));
      }
    }
  };

  stage(0, nbeg);
  __syncthreads();
  const int g = dgrp & 7;
  for (int kt = 0; kt < (NN / NS_N2) / 32; ++kt) {
    const int cur = kt & 1;
    if (kt + 1 < (NN / NS_N2) / 32) stage(cur ^ 1, nbeg + ((kt + 1) << 5));
    const float* xs = lds + (cur << 11);
    const float* cs = lds + 4096 + (cur << 11);
    #pragma unroll 8
    for (int nn = 0; nn < 32; ++nn) {
      const int col = ((((nn >> 2) ^ g) << 2) + (nn & 3));
      float xe[4];
      #pragma unroll
      for (int i = 0; i < 4; ++i) xe[i] = xs[((dl + i) << 5) + col];
      const float4 cv0 = *(const float4*)&cs[(nn << 6) + r0];
      const float4 cv1 = *(const float4*)&cs[(nn << 6) + r0 + 4];
      #pragma unroll
      for (int i = 0; i < 4; ++i) {
        fma4s(acc[i][0], cv0, xe[i]);
        fma4s(acc[i][1], cv1, xe[i]);
      }
    }
    __syncthreads();
  }
  #pragma unroll
  for (int i = 0; i < 4; ++i) {
    float* op = n2p + (((long long)s * BSZ + b) * DD + d0 + dl + i) * RR + r0;
    *(float4*)&op[0] = acc[i][0];
    *(float4*)&op[4] = acc[i][1];
  }
}

__global__ void __launch_bounds__(256) bupdate_fb_kernel(float* __restrict__ Bw,
                                                         const float* __restrict__ n2p,
                                                         const float* __restrict__ ctcp,
                                                         int ns2) {
  __shared__ float ct[4096];
  const int b  = blockIdx.y;
  const int d0 = blockIdx.x << 6;
  #pragma unroll
  for (int i = 0; i < 4; ++i) {
    const int w = threadIdx.x + (i << 8);
    float4 s = make_float4(0.f, 0.f, 0.f, 0.f);
    for (int sp = 0; sp < NS_C; ++sp)
      add4(s, ((const float4*)(ctcp + ((long long)sp * BSZ + b) * 4096))[w]);
    ((float4*)ct)[w] = s;
  }
  __syncthreads();
  const int d  = d0 + (threadIdx.x >> 2);
  const int rq = (threadIdx.x & 3) << 4;

  float4 ns[4];
  #pragma unroll
  for (int j = 0; j < 4; ++j) ns[j] = make_float4(0.f, 0.f, 0.f, 0.f);
  for (int s = 0; s < ns2; ++s) {
    const float4* p = (const float4*)&n2p[(((long long)s * BSZ + b) * DD + d) * RR + rq];
    #pragma unroll
    for (int j = 0; j < 4; ++j) add4(ns[j], p[j]);
  }
  const float4* brow = (const float4*)&Bw[((long long)b * DD + d) * RR];
  float4 dn[4];
  #pragma unroll
  for (int j = 0; j < 4; ++j) dn[j] = make_float4(0.f, 0.f, 0.f, 0.f);
  for (int q = 0; q < 16; ++q) {
    const float4 b4 = brow[q];
    const float4* c0 = (const float4*)&ct[(4 * q + 0) * 64 + rq];
    const float4* c1 = (const float4*)&ct[(4 * q + 1) * 64 + rq];
    const float4* c2 = (const float4*)&ct[(4 * q + 2) * 64 + rq];
    const float4* c3 = (const float4*)&ct[(4 * q + 3) * 64 + rq];
    #pragma unroll
    for (int j = 0; j < 4; ++j) {
      fma4s(dn[j], c0[j], b4.x); fma4s(dn[j], c1[j], b4.y);
      fma4s(dn[j], c2[j], b4.z); fma4s(dn[j], c3[j], b4.w);
    }
  }
  float4* bp = (float4*)&Bw[((long long)b * DD + d) * RR + rq];
  float4 bo[4];
  #pragma unroll
  for (int j = 0; j < 4; ++j) bo[j] = bp[j];
  __syncthreads();
  #pragma unroll
  for (int j = 0; j < 4; ++j) {
    float4 o;
    o.x = bo[j].x * ns[j].x / (dn[j].x + EPS);
    o.y = bo[j].y * ns[j].y / (dn[j].y + EPS);
    o.z = bo[j].z * ns[j].z / (dn[j].z + EPS);
    o.w = bo[j].w * ns[j].w / (dn[j].w + EPS);
    bp[j] = o;
  }
}

__global__ void __launch_bounds__(256) out_kernel(const float* __restrict__ Bw,
                                                  const float* __restrict__ coef,
                                                  float* __restrict__ out) {
  __shared__ float bt [64 * 68];
  __shared__ float ctl[64 * 68];
  const int n0 = blockIdx.x << 6;
  const int d0 = blockIdx.y << 6;
  const int b  = blockIdx.z;
  const int tx = threadIdx.x & 15;
  const int ty = threadIdx.x >> 4;
  for (int t = threadIdx.x; t < 1024; t += 256) {
    const int row = t >> 4, c4 = (t & 15) << 2;
    const float4 v = *(const float4*)&Bw[((long long)b * DD + d0 + row) * RR + c4];
    bt[(c4 + 0) * 68 + row] = v.x; bt[(c4 + 1) * 68 + row] = v.y;
    bt[(c4 + 2) * 68 + row] = v.z; bt[(c4 + 3) * 68 + row] = v.w;
  }
  for (int t = threadIdx.x; t < 1024; t += 256) {
    const int row = t >> 4, c4 = (t & 15) << 2;
    const float4 v = *(const float4*)&coef[((long long)b * NN + n0 + row) * RR + c4];
    ctl[(c4 + 0) * 68 + row] = v.x; ctl[(c4 + 1) * 68 + row] = v.y;
    ctl[(c4 + 2) * 68 + row] = v.z; ctl[(c4 + 3) * 68 + row] = v.w;
  }
  __syncthreads();
  float4 ai[4];
  #pragma unroll
  for (int i = 0; i < 4; ++i) ai[i] = make_float4(0.f, 0.f, 0.f, 0.f);
  #pragma unroll 8
  for (int r = 0; r < 64; ++r) {
    const float4 bv = *(const float4*)&bt [r * 68 + (ty << 2)];
    const float4 cv = *(const float4*)&ctl[r * 68 + (tx << 2)];
    fma4s(ai[0], cv, bv.x); fma4s(ai[1], cv, bv.y);
    fma4s(ai[2], cv, bv.z); fma4s(ai[3], cv, bv.w);
  }
  #pragma unroll
  for (int i = 0; i < 4; ++i)
    *(float4*)&out[((long long)b * DD + d0 + (ty << 2) + i) * NN + n0 + (tx << 2)] = ai[i];
}

extern "C" void kernel_launch(void* const* d_in, const int* in_sizes, int n_in,
                              void* d_out, int out_size, void* d_ws, size_t ws_size,
                              hipStream_t stream) {
  const float* x        = (const float*)d_in[0];
  const float* bases_in = (const float*)d_in[1];
  float* out = (float*)d_out;
  float* ws  = (float*)d_ws;

  float* coef    = ws;                                   // 4M f32
  float* bases_w = coef + (long long)BSZ * NN * RR;      // 0.5M
  float* btbp    = bases_w + (long long)BSZ * DD * RR;   // 0.5M (fallback; fp16: bD16)
  float* ctcp    = btbp + (long long)NS_B * BSZ * 4096;  // 2M
  float* n2p     = ctcp + (long long)NS_C * BSZ * 4096;  // 4M
  float* Gf      = n2p + (long long)NS_N2 * BSZ * DD * RR;   // 64K f32 (fp16 path G)
  half_t* xT16   = (half_t*)(Gf + (long long)BSZ * 4096);    // 33.5M halfs
  half_t* xd16   = xT16 + (long long)BSZ * NN * DD;          // 33.5M halfs
  half_t* BbT16  = xd16 + (long long)BSZ * NN * DD;          // 0.5M halfs
  half_t* cbT16  = BbT16 + (long long)BSZ * RR * DD;         // 4M halfs
  half_t* Gh16   = cbT16 + (long long)BSZ * RR * NN;         // 64K halfs (layout keep)
  const long long need = (long long)((char*)(Gh16 + (long long)BSZ * 4096) - (char*)d_ws);

  // fp16-path aliases: cN16 in n2p (dead after loop); bD16 in btbp
  half_t* cN16 = (half_t*)n2p;
  half_t* bD16 = (half_t*)btbp;

  const dim3 blk256(256);
  const dim3 blk128(128);

  hipMemcpyAsync(bases_w, bases_in, sizeof(float) * BSZ * DD * RR,
                 hipMemcpyDeviceToDevice, stream);

  if ((long long)ws_size >= need) {
    // ---------- fp16-MFMA path (all loop operands L3-resident) ----------
    xcvt16_kernel<<<dim3(NN / 64, DD / 64, BSZ), blk256, 0, stream>>>(x, xd16, xT16);
    tcvt16_kernel<<<dim3(1, DD / 64, BSZ), blk256, 0, stream>>>(bases_w, BbT16, DD, RR);
    btb16_kernel<<<dim3(BSZ), blk256, 0, stream>>>(BbT16, Gf);
    fused16_kernel<0><<<dim3(NN / 32, BSZ), blk128, 0, stream>>>(
        xT16, BbT16, nullptr, coef, nullptr, nullptr);

    for (int it = 0; it < STEPS; ++it) {
      fused16_kernel<1><<<dim3(NN / 32, BSZ), blk128, 0, stream>>>(
          xT16, BbT16, Gf, coef, cbT16, nullptr);
      numer2ctc16_kernel<<<dim3(DD / 64 + 1, NS_N2, BSZ), blk128, 0, stream>>>(
          xd16, cbT16, n2p, ctcp, Gf);
      bupdate16_kernel<<<dim3(DD / 64, BSZ), blk256, 0, stream>>>(
          bases_w, n2p, ctcp, BbT16, Gf, (it == STEPS - 1) ? bD16 : nullptr);
    }
    // compute_coef: final update (G of final bases accumulated by last bupdate)
    fused16_kernel<2><<<dim3(NN / 32, BSZ), blk128, 0, stream>>>(
        xT16, BbT16, Gf, coef, nullptr, cN16);
    out16_kernel<<<dim3(NN / 256, DD / 16, BSZ), blk256, 0, stream>>>(bD16, cN16, out);
  } else {
    // ---------- fp32 fallback (round-6 path) ----------
    fused_coef_kernel<0><<<dim3(NN / 64, BSZ), blk128, 0, stream>>>(x, bases_w, nullptr, coef);
    for (int it = 0; it < STEPS; ++it) {
      gram_kernel<<<dim3(NS_B, BSZ), blk256, 0, stream>>>(bases_w, btbp, DD / (NS_B * 4),
                                                          (long long)DD * RR);
      fused_coef_kernel<1><<<dim3(NN / 64, BSZ), blk128, 0, stream>>>(x, bases_w, btbp, coef);
      gram_kernel<<<dim3(NS_C, BSZ), blk256, 0, stream>>>(coef, ctcp, NN / (NS_C * 4),
                                                          (long long)NN * RR);
      numer2_kernel<<<dim3(DD / 64, NS_N2, BSZ), blk128, 0, stream>>>(x, coef, n2p);
      bupdate_fb_kernel<<<dim3(DD / 64, BSZ), blk256, 0, stream>>>(bases_w, n2p, ctcp, NS_N2);
    }
    gram_kernel<<<dim3(NS_B, BSZ), blk256, 0, stream>>>(bases_w, btbp, DD / (NS_B * 4),
                                                        (long long)DD * RR);
    fused_coef_kernel<1><<<dim3(NN / 64, BSZ), blk128, 0, stream>>>(x, bases_w, btbp, coef);
    out_kernel<<<dim3(NN / 64, DD / 64, BSZ), blk256, 0, stream>>>(bases_w, coef, out);
  }
}